// Round 3
// baseline (2291.207 us; speedup 1.0000x reference)
//
#include <hip/hip_runtime.h>
#include <hip/hip_bf16.h>
#include <stdint.h>

#define NODES 50000
#define RELS  4
#define EDGES 1600000
#define FEAT  256
#define NCLS  16
#define MPAD  50048                 // 391 * 128
#define RPS   50016                 // row_ptr per-relation stride
#define SCHUNK 1024                 // scan elements per block
#define NSBLK  49                   // ceil(50000/1024)
#define NCHUNK 64                   // edge chunks per relation
#define CHUNKE 25000                // EDGES / NCHUNK
#define NB     782                  // node buckets of 64 rows (781*64+16)
#define FCH    8                    // feature chunks (32 feats = 64B slice each)
#define FCW    32                   // feature chunk width

typedef __attribute__((ext_vector_type(8))) short short8;
typedef __attribute__((ext_vector_type(8))) unsigned short u16x8;
typedef __attribute__((ext_vector_type(4))) float f32x4;

static __device__ __forceinline__ float bf2f(unsigned short u) {
    return __uint_as_float(((unsigned int)u) << 16);
}
static __device__ __forceinline__ unsigned short f2bf(float f) {
    unsigned int x = __float_as_uint(f);
    unsigned int r = x + 0x7fffu + ((x >> 16) & 1u);
    return (unsigned short)(r >> 16);
}

// ============ CSR build (row side): bucket radix sort, zero global atomics ============

__global__ __launch_bounds__(256)
void k_bhist(const int* __restrict__ edges, int arr_off, unsigned* __restrict__ part) {
    int chunk = blockIdx.x, rel = blockIdx.y, t = threadIdx.x;
    const int* arr = edges + (size_t)rel * 2 * EDGES + arr_off + (size_t)chunk * CHUNKE;
    __shared__ unsigned h[NB];
    for (int i = t; i < NB; i += 256) h[i] = 0;
    __syncthreads();
    for (int e = t; e < CHUNKE; e += 256) atomicAdd(&h[((unsigned)arr[e]) >> 6], 1u);
    __syncthreads();
    unsigned* po = part + ((size_t)rel * NCHUNK + chunk) * NB;
    for (int i = t; i < NB; i += 256) po[i] = h[i];
}

__global__ __launch_bounds__(256)
void k_bscan(const unsigned* __restrict__ part, unsigned* __restrict__ off,
             unsigned* __restrict__ bbase) {
    int rel = blockIdx.x, t = threadIdx.x;
    const int BPT = 4;                       // 256*4 >= NB
    int b0 = t * BPT;
    unsigned s = 0;
#pragma unroll
    for (int j = 0; j < BPT; ++j) {
        int b = b0 + j;
        unsigned x = 0;
        if (b < NB)
            for (int c = 0; c < NCHUNK; ++c)
                x += part[((size_t)rel * NCHUNK + c) * NB + b];
        s += x;
    }
    __shared__ unsigned sh[256];
    sh[t] = s;
    __syncthreads();
    for (int o = 1; o < 256; o <<= 1) {
        unsigned u = (t >= o) ? sh[t - o] : 0;
        __syncthreads();
        sh[t] += u;
        __syncthreads();
    }
    unsigned base = sh[t] - s;
#pragma unroll
    for (int j = 0; j < BPT; ++j) {
        int b = b0 + j;
        if (b < NB) {
            bbase[rel * (NB + 1) + b] = base;
            unsigned acc = base;
            for (int c = 0; c < NCHUNK; ++c) {
                size_t o2 = ((size_t)rel * NCHUNK + c) * NB + b;
                off[o2] = acc;
                acc += part[o2];
            }
            base = acc;
        }
    }
    if (t == 255) bbase[rel * (NB + 1) + NB] = sh[255];
}

__global__ __launch_bounds__(256)
void k_scatR(const int* __restrict__ edges, const unsigned* __restrict__ off,
             int2* __restrict__ ebuf) {
    int chunk = blockIdx.x, rel = blockIdx.y, t = threadIdx.x;
    const int* rows = edges + (size_t)rel * 2 * EDGES + (size_t)chunk * CHUNKE;
    const int* cols = rows + EDGES;
    __shared__ unsigned cur[NB];
    const unsigned* po = off + ((size_t)rel * NCHUNK + chunk) * NB;
    for (int i = t; i < NB; i += 256) cur[i] = po[i];
    __syncthreads();
    int2* eb = ebuf + (size_t)rel * EDGES;
    for (int e = t; e < CHUNKE; e += 256) {
        int r = rows[e], c = cols[e];
        unsigned pos = atomicAdd(&cur[((unsigned)r) >> 6], 1u);
        eb[pos] = make_int2(r, c);
    }
}

__global__ __launch_bounds__(256)
void k_countR(const int2* __restrict__ ebuf, const unsigned* __restrict__ bbase,
              int* __restrict__ deg_row) {
    int b = blockIdx.x, rel = blockIdx.y, t = threadIdx.x;
    unsigned s = bbase[rel * (NB + 1) + b], e = bbase[rel * (NB + 1) + b + 1];
    __shared__ unsigned cnt[64];
    if (t < 64) cnt[t] = 0;
    __syncthreads();
    const int2* eb = ebuf + (size_t)rel * EDGES;
    for (unsigned i = s + t; i < e; i += 256) atomicAdd(&cnt[eb[i].x & 63], 1u);
    __syncthreads();
    int base = b * 64;
    if (t < 64 && base + t < NODES) deg_row[(size_t)rel * NODES + base + t] = (int)cnt[t];
}

// col degrees: direct global atomics into L2-resident 800KB table
__global__ void k_zero(int* __restrict__ p, int count) {
    int i = blockIdx.x * blockDim.x + threadIdx.x;
    if (i < count) p[i] = 0;
}

__global__ __launch_bounds__(256)
void k_dcol(const int* __restrict__ edges, int* __restrict__ deg_col) {
    int rel = blockIdx.y;
    const int* cols = edges + (size_t)rel * 2 * EDGES + EDGES;
    int i = blockIdx.x * 256 + threadIdx.x;          // grid.x*256 == EDGES
    atomicAdd(deg_col + (size_t)rel * NODES + cols[i], 1);
}

__global__ void k_dinv(const int* __restrict__ deg_row, const int* __restrict__ deg_col,
                       float* dinv_row, float* dinv_col) {
    int idx = blockIdx.x * blockDim.x + threadIdx.x;
    if (idx >= RELS * NODES) return;
    int dr = deg_row[idx]; if (dr < 1) dr = 1;
    int dc = deg_col[idx]; if (dc < 1) dc = 1;
    dinv_row[idx] = rsqrtf((float)dr);
    dinv_col[idx] = rsqrtf((float)dc);
}

// -------- parallel exclusive scan of deg_row -> row_ptr --------
__global__ __launch_bounds__(256)
void k_scanA(const int* __restrict__ deg, int* __restrict__ tmp, int* __restrict__ btot) {
    int r = blockIdx.y, blk = blockIdx.x, t = threadIdx.x;
    int i0 = blk * SCHUNK + t * 4;
    const int* d = deg + (size_t)r * NODES;
    int4 v = make_int4(0, 0, 0, 0);
    if (i0 + 3 < NODES) v = *(const int4*)(d + i0);
    else if (i0 < NODES) {
        v.x = d[i0];
        if (i0 + 1 < NODES) v.y = d[i0 + 1];
        if (i0 + 2 < NODES) v.z = d[i0 + 2];
    }
    int s = v.x + v.y + v.z + v.w;
    __shared__ int sh[256];
    sh[t] = s;
    __syncthreads();
    for (int off = 1; off < 256; off <<= 1) {
        int u = (t >= off) ? sh[t - off] : 0;
        __syncthreads();
        sh[t] += u;
        __syncthreads();
    }
    int excl = sh[t] - s;
    int4 o;
    o.x = excl; o.y = excl + v.x; o.z = o.y + v.y; o.w = o.z + v.z;
    int* tp = tmp + (size_t)r * NODES;
    if (i0 + 3 < NODES) *(int4*)(tp + i0) = o;
    else if (i0 < NODES) {
        tp[i0] = o.x;
        if (i0 + 1 < NODES) tp[i0 + 1] = o.y;
        if (i0 + 2 < NODES) tp[i0 + 2] = o.z;
    }
    if (t == 255) btot[r * 64 + blk] = sh[255];
}

__global__ void k_scanB(int* __restrict__ btot, int* __restrict__ row_ptr) {
    int r = blockIdx.x;
    if (threadIdx.x != 0) return;
    int acc = 0;
    for (int b = 0; b < NSBLK; ++b) {
        int v = btot[r * 64 + b];
        btot[r * 64 + b] = acc;
        acc += v;
    }
    row_ptr[r * RPS + NODES] = acc;
}

__global__ __launch_bounds__(256)
void k_scanC(const int* __restrict__ tmp, const int* __restrict__ btot,
             int* __restrict__ row_ptr) {
    int r = blockIdx.y, blk = blockIdx.x, t = threadIdx.x;
    int i0 = blk * SCHUNK + t * 4;
    int off = btot[r * 64 + blk];
    const int* tp = tmp + (size_t)r * NODES;
    int* rp = row_ptr + (size_t)r * RPS;
    if (i0 + 3 < NODES) {
        int4 v = *(const int4*)(tp + i0);
        rp[i0] = v.x + off; rp[i0 + 1] = v.y + off;
        rp[i0 + 2] = v.z + off; rp[i0 + 3] = v.w + off;
    } else if (i0 < NODES) {
        for (int j = 0; j < 4 && i0 + j < NODES; ++j)
            rp[i0 + j] = tp[i0 + j] + off;
    }
}

__global__ __launch_bounds__(256)
void k_place(const int2* __restrict__ ebuf, const unsigned* __restrict__ bbase,
             const int* __restrict__ row_ptr, int* __restrict__ csr_col) {
    int b = blockIdx.x, rel = blockIdx.y, t = threadIdx.x;
    unsigned s = bbase[rel * (NB + 1) + b], e = bbase[rel * (NB + 1) + b + 1];
    __shared__ int cur[64];
    int base = b * 64;
    const int* rp = row_ptr + (size_t)rel * RPS;
    if (t < 64) cur[t] = (base + t < NODES) ? rp[base + t] : 0;
    __syncthreads();
    const int2* eb = ebuf + (size_t)rel * EDGES;
    int* cc = csr_col + (size_t)rel * EDGES;
    for (unsigned i = s + t; i < e; i += 256) {
        int2 ec = eb[i];
        int pos = atomicAdd(&cur[ec.x - base], 1);
        cc[pos] = ec.y;
    }
}

// ---------------- conversions ----------------

__global__ void k_wt(const float* __restrict__ W, unsigned short* __restrict__ Wt) {
    int idx = blockIdx.x * blockDim.x + threadIdx.x;
    if (idx >= RELS * FEAT * FEAT) return;
    int r = idx >> 16;
    int rem = idx & 65535;
    int n = rem >> 8;
    int k = rem & 255;
    Wt[idx] = f2bf(W[(size_t)r * FEAT * FEAT + (size_t)k * FEAT + n]);
}

// X fp32 [NODES][256] -> chunk-major bf16 [FCH][NODES][32] in one pass
__global__ __launch_bounds__(256)
void k_chunkx(const float* __restrict__ X, unsigned short* __restrict__ dst) {
    int gid = blockIdx.x * 256 + threadIdx.x;        // over NODES*32 groups of 8 feats
    if (gid >= NODES * 32) return;
    int node = gid >> 5, sub = gid & 31;
    int chunk = sub >> 2, fl = sub & 3;
    const float* s = X + (size_t)node * FEAT + sub * 8;
    float4 a = *(const float4*)s;
    float4 b = *(const float4*)(s + 4);
    u16x8 v;
    v[0] = f2bf(a.x); v[1] = f2bf(a.y); v[2] = f2bf(a.z); v[3] = f2bf(a.w);
    v[4] = f2bf(b.x); v[5] = f2bf(b.y); v[6] = f2bf(b.z); v[7] = f2bf(b.w);
    *(u16x8*)(dst + ((size_t)chunk * NODES + node) * FCW + fl * 8) = v;
}

// ---------------- SPMM: chunked gather, serial 4-lane row groups ----------------
// Wave = 16 groups x 4 lanes. Each group owns ONE row for one feature chunk and
// iterates its edges serially (2 in flight); the 4 lanes partition the 32-feat
// chunk (8 feats / 16B each). No cross-lane reduction, prologue ~2 loads/row.
// chunk = slowest grid dim -> all CUs sweep one 3.2MB L2-resident slice at a time.
// rel_fixed<0: fused over rels, agg slice = agg + rel*MPAD*FEAT.

__global__ __launch_bounds__(256)
void k_spmmc(const unsigned short* __restrict__ featc, const int* __restrict__ row_ptr,
             const int* __restrict__ csr_col, const float* __restrict__ dinv_row,
             const float* __restrict__ dinv_col, unsigned short* __restrict__ agg,
             int rel_fixed) {
    int rel, chunk;
    unsigned short* aggp;
    if (rel_fixed < 0) {
        rel = blockIdx.y; chunk = blockIdx.z;
        aggp = agg + (size_t)rel * MPAD * FEAT;
    } else {
        rel = rel_fixed; chunk = blockIdx.y;
        aggp = agg;
    }
    int t = threadIdx.x;
    int row = blockIdx.x * 64 + (t >> 2);
    int fl  = t & 3;
    if (row >= NODES) return;

    int j   = row_ptr[rel * RPS + row];
    int end = row_ptr[rel * RPS + row + 1];
    const int* cols = csr_col + (size_t)rel * EDGES;
    const float* dc = dinv_col + rel * NODES;
    const unsigned short* ft = featc + (size_t)chunk * NODES * FCW + fl * 8;

    float acc[8] = {0.f, 0.f, 0.f, 0.f, 0.f, 0.f, 0.f, 0.f};
    for (; j + 1 < end; j += 2) {
        int c0 = cols[j];
        int c1 = cols[j + 1];
        float w0 = dc[c0];
        float w1 = dc[c1];
        u16x8 u0 = *(const u16x8*)(ft + (size_t)c0 * FCW);
        u16x8 u1 = *(const u16x8*)(ft + (size_t)c1 * FCW);
#pragma unroll
        for (int i = 0; i < 8; ++i) acc[i] += w0 * bf2f(u0[i]);
#pragma unroll
        for (int i = 0; i < 8; ++i) acc[i] += w1 * bf2f(u1[i]);
    }
    if (j < end) {
        int c0 = cols[j];
        float w0 = dc[c0];
        u16x8 u0 = *(const u16x8*)(ft + (size_t)c0 * FCW);
#pragma unroll
        for (int i = 0; i < 8; ++i) acc[i] += w0 * bf2f(u0[i]);
    }
    float dr = dinv_row[rel * NODES + row];
    u16x8 o;
#pragma unroll
    for (int i = 0; i < 8; ++i) o[i] = f2bf(acc[i] * dr);
    *(u16x8*)(aggp + (size_t)row * FEAT + chunk * FCW + fl * 8) = o;
}

// ---------------- MFMA GEMM (128x128 tile, BK=64, XOR-swizzled LDS) ----------------
// C/D layout: col = lane&15, row = quad*4 + reg.

__global__ __launch_bounds__(256)
void k_gemm1(const unsigned short* __restrict__ Abase, const unsigned short* __restrict__ Wt,
             unsigned short* __restrict__ h1c) {
    __shared__ __align__(16) unsigned short As[128 * 64];
    __shared__ __align__(16) unsigned short Bs[128 * 64];
    int tid = threadIdx.x;
    int wave = tid >> 6, lane = tid & 63;
    int quad = lane >> 4, l16 = lane & 15;
    int wm = (wave & 1) * 64, wn = (wave >> 1) * 64;
    int row0 = blockIdx.x * 128, n0 = blockIdx.y * 128;

    f32x4 hacc[4][4];
#pragma unroll
    for (int mi = 0; mi < 4; ++mi)
#pragma unroll
        for (int ni = 0; ni < 4; ++ni)
            hacc[mi][ni] = (f32x4){0.f, 0.f, 0.f, 0.f};

    for (int r = 0; r < RELS; ++r) {
        const unsigned short* A  = Abase + (size_t)r * MPAD * FEAT;
        const unsigned short* Bt = Wt + (size_t)r * FEAT * FEAT;
        f32x4 acc[4][4];
#pragma unroll
        for (int mi = 0; mi < 4; ++mi)
#pragma unroll
            for (int ni = 0; ni < 4; ++ni)
                acc[mi][ni] = (f32x4){0.f, 0.f, 0.f, 0.f};

        for (int k0 = 0; k0 < FEAT; k0 += 64) {
#pragma unroll
            for (int issue = 0; issue < 4; ++issue) {
                int flat = issue * 256 + tid;
                int row = flat >> 3;
                int gr = flat & 7;
                int sg = gr ^ (row & 7);
                *(uint4*)&As[flat * 8] = *(const uint4*)(A + (size_t)(row0 + row) * FEAT + k0 + sg * 8);
                *(uint4*)&Bs[flat * 8] = *(const uint4*)(Bt + (size_t)(n0 + row) * FEAT + k0 + sg * 8);
            }
            __syncthreads();
#pragma unroll
            for (int ks = 0; ks < 2; ++ks) {
                int g = ks * 4 + quad;
                short8 af[4], bfr[4];
#pragma unroll
                for (int mi = 0; mi < 4; ++mi) {
                    int m = wm + mi * 16 + l16;
                    af[mi] = *(const short8*)&As[m * 64 + ((g ^ (m & 7)) << 3)];
                }
#pragma unroll
                for (int ni = 0; ni < 4; ++ni) {
                    int n = wn + ni * 16 + l16;
                    bfr[ni] = *(const short8*)&Bs[n * 64 + ((g ^ (n & 7)) << 3)];
                }
#pragma unroll
                for (int mi = 0; mi < 4; ++mi)
#pragma unroll
                    for (int ni = 0; ni < 4; ++ni)
                        acc[mi][ni] = __builtin_amdgcn_mfma_f32_16x16x32_bf16(af[mi], bfr[ni], acc[mi][ni], 0, 0, 0);
            }
            __syncthreads();
        }
#pragma unroll
        for (int mi = 0; mi < 4; ++mi)
#pragma unroll
            for (int ni = 0; ni < 4; ++ni)
#pragma unroll
                for (int i = 0; i < 4; ++i) {
                    float v = acc[mi][ni][i];
                    hacc[mi][ni][i] += 0.25f * (v > 0.f ? v : 0.f);
                }
    }

    // write chunk-major h1c [FCH][NODES][32] directly (layer-2 gather source)
#pragma unroll
    for (int mi = 0; mi < 4; ++mi)
#pragma unroll
        for (int ni = 0; ni < 4; ++ni) {
            int col = n0 + wn + ni * 16 + l16;
            int ch = col >> 5, cf = col & 31;
#pragma unroll
            for (int i = 0; i < 4; ++i) {
                int row = row0 + wm + mi * 16 + quad * 4 + i;
                if (row < NODES)
                    h1c[((size_t)ch * NODES + row) * FCW + cf] = f2bf(hacc[mi][ni][i]);
            }
        }
}

__global__ __launch_bounds__(256)
void k_gemm2(const unsigned short* __restrict__ A, const unsigned short* __restrict__ Bt,
             unsigned short* __restrict__ H2) {
    __shared__ __align__(16) unsigned short As[128 * 64];
    __shared__ __align__(16) unsigned short Bs[128 * 64];
    int tid = threadIdx.x;
    int wave = tid >> 6, lane = tid & 63;
    int quad = lane >> 4, l16 = lane & 15;
    int wm = (wave & 1) * 64, wn = (wave >> 1) * 64;
    int row0 = blockIdx.x * 128, n0 = blockIdx.y * 128;

    f32x4 acc[4][4];
#pragma unroll
    for (int mi = 0; mi < 4; ++mi)
#pragma unroll
        for (int ni = 0; ni < 4; ++ni)
            acc[mi][ni] = (f32x4){0.f, 0.f, 0.f, 0.f};

    for (int k0 = 0; k0 < FEAT; k0 += 64) {
#pragma unroll
        for (int issue = 0; issue < 4; ++issue) {
            int flat = issue * 256 + tid;
            int row = flat >> 3;
            int gr = flat & 7;
            int sg = gr ^ (row & 7);
            *(uint4*)&As[flat * 8] = *(const uint4*)(A + (size_t)(row0 + row) * FEAT + k0 + sg * 8);
            *(uint4*)&Bs[flat * 8] = *(const uint4*)(Bt + (size_t)(n0 + row) * FEAT + k0 + sg * 8);
        }
        __syncthreads();
#pragma unroll
        for (int ks = 0; ks < 2; ++ks) {
            int g = ks * 4 + quad;
            short8 af[4], bfr[4];
#pragma unroll
            for (int mi = 0; mi < 4; ++mi) {
                int m = wm + mi * 16 + l16;
                af[mi] = *(const short8*)&As[m * 64 + ((g ^ (m & 7)) << 3)];
            }
#pragma unroll
            for (int ni = 0; ni < 4; ++ni) {
                int n = wn + ni * 16 + l16;
                bfr[ni] = *(const short8*)&Bs[n * 64 + ((g ^ (n & 7)) << 3)];
            }
#pragma unroll
            for (int mi = 0; mi < 4; ++mi)
#pragma unroll
                for (int ni = 0; ni < 4; ++ni)
                    acc[mi][ni] = __builtin_amdgcn_mfma_f32_16x16x32_bf16(af[mi], bfr[ni], acc[mi][ni], 0, 0, 0);
        }
        __syncthreads();
    }

#pragma unroll
    for (int mi = 0; mi < 4; ++mi)
#pragma unroll
        for (int ni = 0; ni < 4; ++ni) {
            int col = n0 + wn + ni * 16 + l16;
#pragma unroll
            for (int i = 0; i < 4; ++i) {
                int row = row0 + wm + mi * 16 + quad * 4 + i;
                if (row < NODES) {
                    float v = acc[mi][ni][i];
                    H2[(size_t)row * FEAT + col] = f2bf(v > 0.f ? v : 0.f);
                }
            }
        }
}

// ---------------- fused attention scores + softmax + combine + output GEMV ----------------
// H2 slices are MPAD*FEAT apart (they live in agg slices S0..S3).

__global__ __launch_bounds__(256)
void k_attn_out(const unsigned short* __restrict__ H2bf, const float* __restrict__ att_q,
                const float* __restrict__ tau_p, const float* __restrict__ W_out,
                const float* __restrict__ b_out, float* __restrict__ alpha_out,
                float* __restrict__ logits) {
    __shared__ float red[4][64 * 17];
    int tid = threadIdx.x;
    int wid = tid >> 6;
    int lane = tid & 63;
    int gwave = blockIdx.x * 4 + wid;
    int nwaves = gridDim.x * 4;

    float4 q = *(const float4*)(att_q + lane * 4);
    float tau = fminf(fmaxf(tau_p[0], 0.5f), 5.0f);
    float itau = 1.0f / tau;
    f32x4 Wr[4][4];
#pragma unroll
    for (int j = 0; j < 4; ++j)
#pragma unroll
        for (int c4 = 0; c4 < 4; ++c4) {
            float4 w = *(const float4*)(W_out + (size_t)(lane * 4 + j) * NCLS + c4 * 4);
            Wr[j][c4] = (f32x4){w.x, w.y, w.z, w.w};
        }
    float bc = b_out[lane & 15];
    float* myred = &red[wid][0];
    int cls = lane & 15;
    int rb = (lane >> 4) * 16;

    int n = gwave;
    if (n >= NODES) return;
    ushort4 u[RELS];
#pragma unroll
    for (int r = 0; r < RELS; ++r)
        u[r] = *(const ushort4*)(H2bf + ((size_t)r * MPAD + n) * FEAT + lane * 4);

    while (n < NODES) {
        int nn = n + nwaves;
        int nc = (nn < NODES) ? nn : n;
        ushort4 un[RELS];
#pragma unroll
        for (int r = 0; r < RELS; ++r)
            un[r] = *(const ushort4*)(H2bf + ((size_t)r * MPAD + nc) * FEAT + lane * 4);

        float h[RELS][4];
#pragma unroll
        for (int r = 0; r < RELS; ++r) {
            h[r][0] = bf2f(u[r].x); h[r][1] = bf2f(u[r].y);
            h[r][2] = bf2f(u[r].z); h[r][3] = bf2f(u[r].w);
        }
        float s[RELS];
#pragma unroll
        for (int r = 0; r < RELS; ++r)
            s[r] = h[r][0] * q.x + h[r][1] * q.y + h[r][2] * q.z + h[r][3] * q.w;
#pragma unroll
        for (int off = 1; off < 64; off <<= 1) {
#pragma unroll
            for (int r = 0; r < RELS; ++r) s[r] += __shfl_xor(s[r], off, 64);
        }
        float m = fmaxf(fmaxf(s[0], s[1]), fmaxf(s[2], s[3]));
        float e[RELS];
        float esum = 0.f;
#pragma unroll
        for (int r = 0; r < RELS; ++r) { e[r] = expf((s[r] - m) * itau); esum += e[r]; }
        float inv = 1.0f / esum;
        float a[RELS];
#pragma unroll
        for (int r = 0; r < RELS; ++r) a[r] = e[r] * inv;
        if (lane == 0)
            *(float4*)(alpha_out + (size_t)n * 4) = make_float4(a[0], a[1], a[2], a[3]);

        float w0 = 0.25f + a[0], w1 = 0.25f + a[1], w2 = 0.25f + a[2], w3 = 0.25f + a[3];
        float h2[4];
#pragma unroll
        for (int j = 0; j < 4; ++j)
            h2[j] = w0 * h[0][j] + w1 * h[1][j] + w2 * h[2][j] + w3 * h[3][j];

        f32x4 acc[4];
#pragma unroll
        for (int c4 = 0; c4 < 4; ++c4)
            acc[c4] = h2[0] * Wr[0][c4] + h2[1] * Wr[1][c4]
                    + h2[2] * Wr[2][c4] + h2[3] * Wr[3][c4];

#pragma unroll
        for (int c4 = 0; c4 < 4; ++c4)
#pragma unroll
            for (int i = 0; i < 4; ++i)
                myred[lane * 17 + c4 * 4 + i] = acc[c4][i];
        asm volatile("s_waitcnt lgkmcnt(0)" ::: "memory");
        float t = 0.f;
#pragma unroll
        for (int k = 0; k < 16; ++k) t += myred[(rb + k) * 17 + cls];
        t += __shfl_xor(t, 16, 64);
        t += __shfl_xor(t, 32, 64);
        if (lane < 16) logits[(size_t)n * NCLS + lane] = t + bc;
        asm volatile("" ::: "memory");

#pragma unroll
        for (int r = 0; r < RELS; ++r) u[r] = un[r];
        n = nn;
    }
}

// ---------------- launcher ----------------

static inline int cdiv(int a, int b) { return (a + b - 1) / b; }

extern "C" void kernel_launch(void* const* d_in, const int* in_sizes, int n_in,
                              void* d_out, int out_size, void* d_ws, size_t ws_size,
                              hipStream_t stream) {
    const float* X     = (const float*)d_in[0];
    const int*   edges = (const int*)d_in[1];
    const float* W1    = (const float*)d_in[2];
    const float* W2    = (const float*)d_in[3];
    const float* att_q = (const float*)d_in[4];
    const float* tau   = (const float*)d_in[5];
    const float* W_out = (const float*)d_in[6];
    const float* b_out = (const float*)d_in[7];

    float* logits = (float*)d_out;
    float* alpha  = logits + (size_t)NODES * NCLS;

    char* p = (char*)d_ws;
    auto carve = [&](size_t bytes) -> char* {
        char* q = p;
        p += (bytes + 255) & ~(size_t)255;
        return q;
    };
    int*   deg_row  = (int*)carve((size_t)RELS * NODES * 4);
    int*   deg_col  = (int*)carve((size_t)RELS * NODES * 4);
    float* dinv_row = (float*)carve((size_t)RELS * NODES * 4);
    float* dinv_col = (float*)carve((size_t)RELS * NODES * 4);
    int*   row_ptr  = (int*)carve((size_t)RELS * RPS * 4 + 256);
    int*   tmp      = (int*)carve((size_t)RELS * NODES * 4);
    int*   btot     = (int*)carve((size_t)RELS * 64 * 4);
    int*   csr_col  = (int*)carve((size_t)RELS * EDGES * 4);
    unsigned short* Xc   = (unsigned short*)carve((size_t)NODES * FEAT * 2);  // chunked X
    unsigned short* h1c  = (unsigned short*)carve((size_t)NODES * FEAT * 2);  // chunked h1
    unsigned short* W1t  = (unsigned short*)carve((size_t)RELS * FEAT * FEAT * 2);
    unsigned short* W2t  = (unsigned short*)carve((size_t)RELS * FEAT * FEAT * 2);
    // BIG region: 5 slices of MPAD*FEAT bf16, phase-aliased:
    //   CSR phase:  ebuf(51.2M) | partR/offR(3.2M) | bbR
    //   layer 1:    agg[r] = S_r (r=0..3)
    //   layer 2:    agg[r] = S_{r+1}; gemm2_r reads S_{r+1}, writes H2_r = S_r
    //   attn:       H2 slices contiguous at BIG, stride MPAD*FEAT
    const size_t AGGSE = (size_t)MPAD * FEAT;        // elements per slice
    char* BIG = carve(5 * AGGSE * 2);
    int2*     ebuf = (int2*)BIG;
    char*     q = BIG + (size_t)RELS * EDGES * 8;
    unsigned* partR = (unsigned*)q;               q += (size_t)RELS * NCHUNK * NB * 4;
    unsigned* offR  = (unsigned*)q;               q += (size_t)RELS * NCHUNK * NB * 4;
    unsigned* bbR   = (unsigned*)q;
    unsigned short* aggbf = (unsigned short*)BIG;
    unsigned short* H2bf  = (unsigned short*)BIG;   // S0..S3 after layer 2

    // CSR build: row side via bucket sort; col degrees via direct L2 atomics
    {
        dim3 hg(NCHUNK, RELS);
        dim3 bg(NB, RELS);
        k_zero<<<cdiv(RELS * NODES, 256), 256, 0, stream>>>(deg_col, RELS * NODES);
        k_bhist<<<hg, 256, 0, stream>>>(edges, 0, partR);
        k_bscan<<<RELS, 256, 0, stream>>>(partR, offR, bbR);
        k_scatR<<<hg, 256, 0, stream>>>(edges, offR, ebuf);
        k_countR<<<bg, 256, 0, stream>>>(ebuf, bbR, deg_row);
        k_dcol<<<dim3(EDGES / 256, RELS), 256, 0, stream>>>(edges, deg_col);
        k_dinv<<<cdiv(RELS * NODES, 256), 256, 0, stream>>>(deg_row, deg_col, dinv_row, dinv_col);
        dim3 sg(NSBLK, RELS);
        k_scanA<<<sg, 256, 0, stream>>>(deg_row, tmp, btot);
        k_scanB<<<RELS, 64, 0, stream>>>(btot, row_ptr);
        k_scanC<<<sg, 256, 0, stream>>>(tmp, btot, row_ptr);
        k_place<<<bg, 256, 0, stream>>>(ebuf, bbR, row_ptr, csr_col);
    }

    // conversions
    k_wt<<<cdiv(RELS * FEAT * FEAT, 256), 256, 0, stream>>>(W1, W1t);
    k_wt<<<cdiv(RELS * FEAT * FEAT, 256), 256, 0, stream>>>(W2, W2t);
    k_chunkx<<<cdiv(NODES * 32, 256), 256, 0, stream>>>(X, Xc);

    dim3 gemm_grid(MPAD / 128, FEAT / 128);
    dim3 sgrid(NB, RELS, FCH);   // chunk (z) slowest -> slice-sequential sweep

    // Layer 1: fused SPMM (all rels x chunks) into S0..S3, then fused GEMM -> h1c
    k_spmmc<<<sgrid, 256, 0, stream>>>(Xc, row_ptr, csr_col, dinv_row, dinv_col,
                                       aggbf, -1);
    k_gemm1<<<gemm_grid, 256, 0, stream>>>(aggbf, W1t, h1c);

    // Layer 2: fused SPMM into S1..S4; gemm2_r: S_{r+1} -> H2_r = S_r
    k_spmmc<<<sgrid, 256, 0, stream>>>(h1c, row_ptr, csr_col, dinv_row, dinv_col,
                                       aggbf + AGGSE, -1);
    for (int r = 0; r < RELS; ++r)
        k_gemm2<<<gemm_grid, 256, 0, stream>>>(aggbf + (size_t)(r + 1) * AGGSE,
                                               W2t + (size_t)r * FEAT * FEAT,
                                               aggbf + (size_t)r * AGGSE);

    // fused attention + output (single pass over H2)
    k_attn_out<<<1024, 256, 0, stream>>>(H2bf, att_q, tau, W_out, b_out, alpha, logits);
}

// Round 4
// 1725.934 us; speedup vs baseline: 1.3275x; 1.3275x over previous
//
#include <hip/hip_runtime.h>
#include <hip/hip_bf16.h>
#include <stdint.h>

#define NODES 50000
#define RELS  4
#define EDGES 1600000
#define FEAT  256
#define NCLS  16
#define MPAD  50048                 // 391 * 128
#define RPS   50016                 // row_ptr per-relation stride
#define SCHUNK 1024                 // scan elements per block
#define NSBLK  49                   // ceil(50000/1024)
#define NCHUNK 64                   // edge chunks per relation
#define CHUNKE 25000                // EDGES / NCHUNK
#define NB     782                  // node buckets of 64 rows (781*64+16)

typedef __attribute__((ext_vector_type(8))) short short8;
typedef __attribute__((ext_vector_type(8))) unsigned short u16x8;
typedef __attribute__((ext_vector_type(4))) float f32x4;

static __device__ __forceinline__ float bf2f(unsigned short u) {
    return __uint_as_float(((unsigned int)u) << 16);
}
static __device__ __forceinline__ unsigned short f2bf(float f) {
    unsigned int x = __float_as_uint(f);
    unsigned int r = x + 0x7fffu + ((x >> 16) & 1u);
    return (unsigned short)(r >> 16);
}

// ============ CSR build (row side): bucket radix sort, zero global atomics ============

__global__ __launch_bounds__(256)
void k_bhist(const int* __restrict__ edges, int arr_off, unsigned* __restrict__ part) {
    int chunk = blockIdx.x, rel = blockIdx.y, t = threadIdx.x;
    const int* arr = edges + (size_t)rel * 2 * EDGES + arr_off + (size_t)chunk * CHUNKE;
    __shared__ unsigned h[NB];
    for (int i = t; i < NB; i += 256) h[i] = 0;
    __syncthreads();
    for (int e = t; e < CHUNKE; e += 256) atomicAdd(&h[((unsigned)arr[e]) >> 6], 1u);
    __syncthreads();
    unsigned* po = part + ((size_t)rel * NCHUNK + chunk) * NB;
    for (int i = t; i < NB; i += 256) po[i] = h[i];
}

__global__ __launch_bounds__(256)
void k_bscan(const unsigned* __restrict__ part, unsigned* __restrict__ off,
             unsigned* __restrict__ bbase) {
    int rel = blockIdx.x, t = threadIdx.x;
    const int BPT = 4;                       // 256*4 >= NB
    int b0 = t * BPT;
    unsigned s = 0;
#pragma unroll
    for (int j = 0; j < BPT; ++j) {
        int b = b0 + j;
        unsigned x = 0;
        if (b < NB)
            for (int c = 0; c < NCHUNK; ++c)
                x += part[((size_t)rel * NCHUNK + c) * NB + b];
        s += x;
    }
    __shared__ unsigned sh[256];
    sh[t] = s;
    __syncthreads();
    for (int o = 1; o < 256; o <<= 1) {
        unsigned u = (t >= o) ? sh[t - o] : 0;
        __syncthreads();
        sh[t] += u;
        __syncthreads();
    }
    unsigned base = sh[t] - s;
#pragma unroll
    for (int j = 0; j < BPT; ++j) {
        int b = b0 + j;
        if (b < NB) {
            bbase[rel * (NB + 1) + b] = base;
            unsigned acc = base;
            for (int c = 0; c < NCHUNK; ++c) {
                size_t o2 = ((size_t)rel * NCHUNK + c) * NB + b;
                off[o2] = acc;
                acc += part[o2];
            }
            base = acc;
        }
    }
    if (t == 255) bbase[rel * (NB + 1) + NB] = sh[255];
}

__global__ __launch_bounds__(256)
void k_scatR(const int* __restrict__ edges, const unsigned* __restrict__ off,
             int2* __restrict__ ebuf) {
    int chunk = blockIdx.x, rel = blockIdx.y, t = threadIdx.x;
    const int* rows = edges + (size_t)rel * 2 * EDGES + (size_t)chunk * CHUNKE;
    const int* cols = rows + EDGES;
    __shared__ unsigned cur[NB];
    const unsigned* po = off + ((size_t)rel * NCHUNK + chunk) * NB;
    for (int i = t; i < NB; i += 256) cur[i] = po[i];
    __syncthreads();
    int2* eb = ebuf + (size_t)rel * EDGES;
    for (int e = t; e < CHUNKE; e += 256) {
        int r = rows[e], c = cols[e];
        unsigned pos = atomicAdd(&cur[((unsigned)r) >> 6], 1u);
        eb[pos] = make_int2(r, c);
    }
}

__global__ __launch_bounds__(256)
void k_countR(const int2* __restrict__ ebuf, const unsigned* __restrict__ bbase,
              int* __restrict__ deg_row) {
    int b = blockIdx.x, rel = blockIdx.y, t = threadIdx.x;
    unsigned s = bbase[rel * (NB + 1) + b], e = bbase[rel * (NB + 1) + b + 1];
    __shared__ unsigned cnt[64];
    if (t < 64) cnt[t] = 0;
    __syncthreads();
    const int2* eb = ebuf + (size_t)rel * EDGES;
    for (unsigned i = s + t; i < e; i += 256) atomicAdd(&cnt[eb[i].x & 63], 1u);
    __syncthreads();
    int base = b * 64;
    if (t < 64 && base + t < NODES) deg_row[(size_t)rel * NODES + base + t] = (int)cnt[t];
}

// col degrees: direct global atomics into L2-resident 800KB table
__global__ void k_zero(int* __restrict__ p, int count) {
    int i = blockIdx.x * blockDim.x + threadIdx.x;
    if (i < count) p[i] = 0;
}

__global__ __launch_bounds__(256)
void k_dcol(const int* __restrict__ edges, int* __restrict__ deg_col) {
    int rel = blockIdx.y;
    const int* cols = edges + (size_t)rel * 2 * EDGES + EDGES;
    int i = blockIdx.x * 256 + threadIdx.x;          // grid.x*256 == EDGES
    atomicAdd(deg_col + (size_t)rel * NODES + cols[i], 1);
}

__global__ void k_dinv(const int* __restrict__ deg_row, const int* __restrict__ deg_col,
                       float* dinv_row, float* dinv_col) {
    int idx = blockIdx.x * blockDim.x + threadIdx.x;
    if (idx >= RELS * NODES) return;
    int dr = deg_row[idx]; if (dr < 1) dr = 1;
    int dc = deg_col[idx]; if (dc < 1) dc = 1;
    dinv_row[idx] = rsqrtf((float)dr);
    dinv_col[idx] = rsqrtf((float)dc);
}

// -------- parallel exclusive scan of deg_row -> row_ptr --------
__global__ __launch_bounds__(256)
void k_scanA(const int* __restrict__ deg, int* __restrict__ tmp, int* __restrict__ btot) {
    int r = blockIdx.y, blk = blockIdx.x, t = threadIdx.x;
    int i0 = blk * SCHUNK + t * 4;
    const int* d = deg + (size_t)r * NODES;
    int4 v = make_int4(0, 0, 0, 0);
    if (i0 + 3 < NODES) v = *(const int4*)(d + i0);
    else if (i0 < NODES) {
        v.x = d[i0];
        if (i0 + 1 < NODES) v.y = d[i0 + 1];
        if (i0 + 2 < NODES) v.z = d[i0 + 2];
    }
    int s = v.x + v.y + v.z + v.w;
    __shared__ int sh[256];
    sh[t] = s;
    __syncthreads();
    for (int off = 1; off < 256; off <<= 1) {
        int u = (t >= off) ? sh[t - off] : 0;
        __syncthreads();
        sh[t] += u;
        __syncthreads();
    }
    int excl = sh[t] - s;
    int4 o;
    o.x = excl; o.y = excl + v.x; o.z = o.y + v.y; o.w = o.z + v.z;
    int* tp = tmp + (size_t)r * NODES;
    if (i0 + 3 < NODES) *(int4*)(tp + i0) = o;
    else if (i0 < NODES) {
        tp[i0] = o.x;
        if (i0 + 1 < NODES) tp[i0 + 1] = o.y;
        if (i0 + 2 < NODES) tp[i0 + 2] = o.z;
    }
    if (t == 255) btot[r * 64 + blk] = sh[255];
}

__global__ void k_scanB(int* __restrict__ btot, int* __restrict__ row_ptr) {
    int r = blockIdx.x;
    if (threadIdx.x != 0) return;
    int acc = 0;
    for (int b = 0; b < NSBLK; ++b) {
        int v = btot[r * 64 + b];
        btot[r * 64 + b] = acc;
        acc += v;
    }
    row_ptr[r * RPS + NODES] = acc;
}

__global__ __launch_bounds__(256)
void k_scanC(const int* __restrict__ tmp, const int* __restrict__ btot,
             int* __restrict__ row_ptr) {
    int r = blockIdx.y, blk = blockIdx.x, t = threadIdx.x;
    int i0 = blk * SCHUNK + t * 4;
    int off = btot[r * 64 + blk];
    const int* tp = tmp + (size_t)r * NODES;
    int* rp = row_ptr + (size_t)r * RPS;
    if (i0 + 3 < NODES) {
        int4 v = *(const int4*)(tp + i0);
        rp[i0] = v.x + off; rp[i0 + 1] = v.y + off;
        rp[i0 + 2] = v.z + off; rp[i0 + 3] = v.w + off;
    } else if (i0 < NODES) {
        for (int j = 0; j < 4 && i0 + j < NODES; ++j)
            rp[i0 + j] = tp[i0 + j] + off;
    }
}

__global__ __launch_bounds__(256)
void k_place(const int2* __restrict__ ebuf, const unsigned* __restrict__ bbase,
             const int* __restrict__ row_ptr, int* __restrict__ csr_col) {
    int b = blockIdx.x, rel = blockIdx.y, t = threadIdx.x;
    unsigned s = bbase[rel * (NB + 1) + b], e = bbase[rel * (NB + 1) + b + 1];
    __shared__ int cur[64];
    int base = b * 64;
    const int* rp = row_ptr + (size_t)rel * RPS;
    if (t < 64) cur[t] = (base + t < NODES) ? rp[base + t] : 0;
    __syncthreads();
    const int2* eb = ebuf + (size_t)rel * EDGES;
    int* cc = csr_col + (size_t)rel * EDGES;
    for (unsigned i = s + t; i < e; i += 256) {
        int2 ec = eb[i];
        int pos = atomicAdd(&cur[ec.x - base], 1);
        cc[pos] = ec.y;
    }
}

// ---------------- conversions ----------------

// 8 floats per thread -> u16x8 store
__global__ __launch_bounds__(256)
void k_f2bf8(const float* __restrict__ src, unsigned short* __restrict__ dst, int count8) {
    int i = blockIdx.x * 256 + threadIdx.x;
    if (i >= count8) return;
    const float* s = src + (size_t)i * 8;
    float4 a = *(const float4*)s;
    float4 b = *(const float4*)(s + 4);
    u16x8 v;
    v[0] = f2bf(a.x); v[1] = f2bf(a.y); v[2] = f2bf(a.z); v[3] = f2bf(a.w);
    v[4] = f2bf(b.x); v[5] = f2bf(b.y); v[6] = f2bf(b.z); v[7] = f2bf(b.w);
    *(u16x8*)(dst + (size_t)i * 8) = v;
}

__global__ void k_wt(const float* __restrict__ W, unsigned short* __restrict__ Wt) {
    int idx = blockIdx.x * blockDim.x + threadIdx.x;
    if (idx >= RELS * FEAT * FEAT) return;
    int r = idx >> 16;
    int rem = idx & 65535;
    int n = rem >> 8;
    int k = rem & 255;
    Wt[idx] = f2bf(W[(size_t)r * FEAT * FEAT + (size_t)k * FEAT + n]);
}

// ---------------- SPMM: wave per row, contiguous half-split, 4 edges in flight ----------------
// Each half-wave (32 lanes x 16B = full 512B feature row) owns a contiguous half of
// the row's edge list and keeps 4 gathered rows in flight (8/wave). Non-temporal
// cols stream + agg store keep the feature table hot in L2.

__global__ __launch_bounds__(256)
void k_spmm(const unsigned short* __restrict__ feat, const int* __restrict__ row_ptr,
            const int* __restrict__ csr_col, const float* __restrict__ dinv_row,
            const float* __restrict__ dinv_col, unsigned short* __restrict__ aggbf, int rel) {
    int wave = (blockIdx.x * blockDim.x + threadIdx.x) >> 6;
    int lane = threadIdx.x & 63;
    if (wave >= NODES) return;
    int row = wave;
    int half = lane >> 5;
    int l32  = lane & 31;
    int start = row_ptr[rel * RPS + row];
    int end   = row_ptr[rel * RPS + row + 1];
    int deg = end - start;
    int hs = (deg + 1) >> 1;                     // half 0 gets ceil(deg/2)
    int jb = start + half * hs;
    int je = (half == 0) ? (start + hs) : end;
    const int* cols = csr_col + (size_t)rel * EDGES;
    const float* dc = dinv_col + rel * NODES;
    const unsigned short* fb = feat + l32 * 8;
    float acc[8] = {0.f, 0.f, 0.f, 0.f, 0.f, 0.f, 0.f, 0.f};
    int j = jb;
    for (; j + 3 < je; j += 4) {
        int c0 = __builtin_nontemporal_load(cols + j);
        int c1 = __builtin_nontemporal_load(cols + j + 1);
        int c2 = __builtin_nontemporal_load(cols + j + 2);
        int c3 = __builtin_nontemporal_load(cols + j + 3);
        float w0 = dc[c0], w1 = dc[c1], w2 = dc[c2], w3 = dc[c3];
        u16x8 u0 = *(const u16x8*)(fb + (size_t)c0 * FEAT);
        u16x8 u1 = *(const u16x8*)(fb + (size_t)c1 * FEAT);
        u16x8 u2 = *(const u16x8*)(fb + (size_t)c2 * FEAT);
        u16x8 u3 = *(const u16x8*)(fb + (size_t)c3 * FEAT);
#pragma unroll
        for (int i = 0; i < 8; ++i) acc[i] += w0 * bf2f(u0[i]);
#pragma unroll
        for (int i = 0; i < 8; ++i) acc[i] += w1 * bf2f(u1[i]);
#pragma unroll
        for (int i = 0; i < 8; ++i) acc[i] += w2 * bf2f(u2[i]);
#pragma unroll
        for (int i = 0; i < 8; ++i) acc[i] += w3 * bf2f(u3[i]);
    }
    for (; j < je; ++j) {
        int c0 = __builtin_nontemporal_load(cols + j);
        float w0 = dc[c0];
        u16x8 u0 = *(const u16x8*)(fb + (size_t)c0 * FEAT);
#pragma unroll
        for (int i = 0; i < 8; ++i) acc[i] += w0 * bf2f(u0[i]);
    }
#pragma unroll
    for (int i = 0; i < 8; ++i) acc[i] += __shfl_down(acc[i], 32, 64);
    if (half == 0) {
        float dr = dinv_row[rel * NODES + row];
        u16x8 o;
#pragma unroll
        for (int i = 0; i < 8; ++i) o[i] = f2bf(acc[i] * dr);
        __builtin_nontemporal_store(o, (u16x8*)(aggbf + (size_t)row * FEAT + l32 * 8));
    }
}

// ---------------- MFMA GEMM (128x128 tile, BK=64, XOR-swizzled LDS) ----------------
// C/D layout: col = lane&15, row = quad*4 + reg.

__global__ __launch_bounds__(256)
void k_gemm1(const unsigned short* __restrict__ Abase, const unsigned short* __restrict__ Wt,
             unsigned short* __restrict__ h1bf) {
    __shared__ __align__(16) unsigned short As[128 * 64];
    __shared__ __align__(16) unsigned short Bs[128 * 64];
    int tid = threadIdx.x;
    int wave = tid >> 6, lane = tid & 63;
    int quad = lane >> 4, l16 = lane & 15;
    int wm = (wave & 1) * 64, wn = (wave >> 1) * 64;
    int row0 = blockIdx.x * 128, n0 = blockIdx.y * 128;

    f32x4 hacc[4][4];
#pragma unroll
    for (int mi = 0; mi < 4; ++mi)
#pragma unroll
        for (int ni = 0; ni < 4; ++ni)
            hacc[mi][ni] = (f32x4){0.f, 0.f, 0.f, 0.f};

    for (int r = 0; r < RELS; ++r) {
        const unsigned short* A  = Abase + (size_t)r * MPAD * FEAT;
        const unsigned short* Bt = Wt + (size_t)r * FEAT * FEAT;
        f32x4 acc[4][4];
#pragma unroll
        for (int mi = 0; mi < 4; ++mi)
#pragma unroll
            for (int ni = 0; ni < 4; ++ni)
                acc[mi][ni] = (f32x4){0.f, 0.f, 0.f, 0.f};

        for (int k0 = 0; k0 < FEAT; k0 += 64) {
#pragma unroll
            for (int issue = 0; issue < 4; ++issue) {
                int flat = issue * 256 + tid;
                int row = flat >> 3;
                int gr = flat & 7;
                int sg = gr ^ (row & 7);
                *(uint4*)&As[flat * 8] = *(const uint4*)(A + (size_t)(row0 + row) * FEAT + k0 + sg * 8);
                *(uint4*)&Bs[flat * 8] = *(const uint4*)(Bt + (size_t)(n0 + row) * FEAT + k0 + sg * 8);
            }
            __syncthreads();
#pragma unroll
            for (int ks = 0; ks < 2; ++ks) {
                int g = ks * 4 + quad;
                short8 af[4], bfr[4];
#pragma unroll
                for (int mi = 0; mi < 4; ++mi) {
                    int m = wm + mi * 16 + l16;
                    af[mi] = *(const short8*)&As[m * 64 + ((g ^ (m & 7)) << 3)];
                }
#pragma unroll
                for (int ni = 0; ni < 4; ++ni) {
                    int n = wn + ni * 16 + l16;
                    bfr[ni] = *(const short8*)&Bs[n * 64 + ((g ^ (n & 7)) << 3)];
                }
#pragma unroll
                for (int mi = 0; mi < 4; ++mi)
#pragma unroll
                    for (int ni = 0; ni < 4; ++ni)
                        acc[mi][ni] = __builtin_amdgcn_mfma_f32_16x16x32_bf16(af[mi], bfr[ni], acc[mi][ni], 0, 0, 0);
            }
            __syncthreads();
        }
#pragma unroll
        for (int mi = 0; mi < 4; ++mi)
#pragma unroll
            for (int ni = 0; ni < 4; ++ni)
#pragma unroll
                for (int i = 0; i < 4; ++i) {
                    float v = acc[mi][ni][i];
                    hacc[mi][ni][i] += 0.25f * (v > 0.f ? v : 0.f);
                }
    }

#pragma unroll
    for (int mi = 0; mi < 4; ++mi)
#pragma unroll
        for (int ni = 0; ni < 4; ++ni) {
            int col = n0 + wn + ni * 16 + l16;
#pragma unroll
            for (int i = 0; i < 4; ++i) {
                int row = row0 + wm + mi * 16 + quad * 4 + i;
                if (row < NODES) h1bf[(size_t)row * FEAT + col] = f2bf(hacc[mi][ni][i]);
            }
        }
}

__global__ __launch_bounds__(256)
void k_gemm2(const unsigned short* __restrict__ A, const unsigned short* __restrict__ Bt,
             unsigned short* __restrict__ H2) {
    __shared__ __align__(16) unsigned short As[128 * 64];
    __shared__ __align__(16) unsigned short Bs[128 * 64];
    int tid = threadIdx.x;
    int wave = tid >> 6, lane = tid & 63;
    int quad = lane >> 4, l16 = lane & 15;
    int wm = (wave & 1) * 64, wn = (wave >> 1) * 64;
    int row0 = blockIdx.x * 128, n0 = blockIdx.y * 128;

    f32x4 acc[4][4];
#pragma unroll
    for (int mi = 0; mi < 4; ++mi)
#pragma unroll
        for (int ni = 0; ni < 4; ++ni)
            acc[mi][ni] = (f32x4){0.f, 0.f, 0.f, 0.f};

    for (int k0 = 0; k0 < FEAT; k0 += 64) {
#pragma unroll
        for (int issue = 0; issue < 4; ++issue) {
            int flat = issue * 256 + tid;
            int row = flat >> 3;
            int gr = flat & 7;
            int sg = gr ^ (row & 7);
            *(uint4*)&As[flat * 8] = *(const uint4*)(A + (size_t)(row0 + row) * FEAT + k0 + sg * 8);
            *(uint4*)&Bs[flat * 8] = *(const uint4*)(Bt + (size_t)(n0 + row) * FEAT + k0 + sg * 8);
        }
        __syncthreads();
#pragma unroll
        for (int ks = 0; ks < 2; ++ks) {
            int g = ks * 4 + quad;
            short8 af[4], bfr[4];
#pragma unroll
            for (int mi = 0; mi < 4; ++mi) {
                int m = wm + mi * 16 + l16;
                af[mi] = *(const short8*)&As[m * 64 + ((g ^ (m & 7)) << 3)];
            }
#pragma unroll
            for (int ni = 0; ni < 4; ++ni) {
                int n = wn + ni * 16 + l16;
                bfr[ni] = *(const short8*)&Bs[n * 64 + ((g ^ (n & 7)) << 3)];
            }
#pragma unroll
            for (int mi = 0; mi < 4; ++mi)
#pragma unroll
                for (int ni = 0; ni < 4; ++ni)
                    acc[mi][ni] = __builtin_amdgcn_mfma_f32_16x16x32_bf16(af[mi], bfr[ni], acc[mi][ni], 0, 0, 0);
        }
        __syncthreads();
    }

#pragma unroll
    for (int mi = 0; mi < 4; ++mi)
#pragma unroll
        for (int ni = 0; ni < 4; ++ni) {
            int col = n0 + wn + ni * 16 + l16;
#pragma unroll
            for (int i = 0; i < 4; ++i) {
                int row = row0 + wm + mi * 16 + quad * 4 + i;
                if (row < NODES) {
                    float v = acc[mi][ni][i];
                    H2[(size_t)row * FEAT + col] = f2bf(v > 0.f ? v : 0.f);
                }
            }
        }
}

// ---------------- fused attention scores + softmax + combine + output GEMV ----------------
// H2 slices are MPAD*FEAT apart (they live in agg slices S0..S3).

__global__ __launch_bounds__(256)
void k_attn_out(const unsigned short* __restrict__ H2bf, const float* __restrict__ att_q,
                const float* __restrict__ tau_p, const float* __restrict__ W_out,
                const float* __restrict__ b_out, float* __restrict__ alpha_out,
                float* __restrict__ logits) {
    __shared__ float red[4][64 * 17];
    int tid = threadIdx.x;
    int wid = tid >> 6;
    int lane = tid & 63;
    int gwave = blockIdx.x * 4 + wid;
    int nwaves = gridDim.x * 4;

    float4 q = *(const float4*)(att_q + lane * 4);
    float tau = fminf(fmaxf(tau_p[0], 0.5f), 5.0f);
    float itau = 1.0f / tau;
    f32x4 Wr[4][4];
#pragma unroll
    for (int j = 0; j < 4; ++j)
#pragma unroll
        for (int c4 = 0; c4 < 4; ++c4) {
            float4 w = *(const float4*)(W_out + (size_t)(lane * 4 + j) * NCLS + c4 * 4);
            Wr[j][c4] = (f32x4){w.x, w.y, w.z, w.w};
        }
    float bc = b_out[lane & 15];
    float* myred = &red[wid][0];
    int cls = lane & 15;
    int rb = (lane >> 4) * 16;

    int n = gwave;
    if (n >= NODES) return;
    ushort4 u[RELS];
#pragma unroll
    for (int r = 0; r < RELS; ++r)
        u[r] = *(const ushort4*)(H2bf + ((size_t)r * MPAD + n) * FEAT + lane * 4);

    while (n < NODES) {
        int nn = n + nwaves;
        int nc = (nn < NODES) ? nn : n;
        ushort4 un[RELS];
#pragma unroll
        for (int r = 0; r < RELS; ++r)
            un[r] = *(const ushort4*)(H2bf + ((size_t)r * MPAD + nc) * FEAT + lane * 4);

        float h[RELS][4];
#pragma unroll
        for (int r = 0; r < RELS; ++r) {
            h[r][0] = bf2f(u[r].x); h[r][1] = bf2f(u[r].y);
            h[r][2] = bf2f(u[r].z); h[r][3] = bf2f(u[r].w);
        }
        float s[RELS];
#pragma unroll
        for (int r = 0; r < RELS; ++r)
            s[r] = h[r][0] * q.x + h[r][1] * q.y + h[r][2] * q.z + h[r][3] * q.w;
#pragma unroll
        for (int off = 1; off < 64; off <<= 1) {
#pragma unroll
            for (int r = 0; r < RELS; ++r) s[r] += __shfl_xor(s[r], off, 64);
        }
        float m = fmaxf(fmaxf(s[0], s[1]), fmaxf(s[2], s[3]));
        float e[RELS];
        float esum = 0.f;
#pragma unroll
        for (int r = 0; r < RELS; ++r) { e[r] = expf((s[r] - m) * itau); esum += e[r]; }
        float inv = 1.0f / esum;
        float a[RELS];
#pragma unroll
        for (int r = 0; r < RELS; ++r) a[r] = e[r] * inv;
        if (lane == 0)
            *(float4*)(alpha_out + (size_t)n * 4) = make_float4(a[0], a[1], a[2], a[3]);

        float w0 = 0.25f + a[0], w1 = 0.25f + a[1], w2 = 0.25f + a[2], w3 = 0.25f + a[3];
        float h2[4];
#pragma unroll
        for (int j = 0; j < 4; ++j)
            h2[j] = w0 * h[0][j] + w1 * h[1][j] + w2 * h[2][j] + w3 * h[3][j];

        f32x4 acc[4];
#pragma unroll
        for (int c4 = 0; c4 < 4; ++c4)
            acc[c4] = h2[0] * Wr[0][c4] + h2[1] * Wr[1][c4]
                    + h2[2] * Wr[2][c4] + h2[3] * Wr[3][c4];

#pragma unroll
        for (int c4 = 0; c4 < 4; ++c4)
#pragma unroll
            for (int i = 0; i < 4; ++i)
                myred[lane * 17 + c4 * 4 + i] = acc[c4][i];
        asm volatile("s_waitcnt lgkmcnt(0)" ::: "memory");
        float t = 0.f;
#pragma unroll
        for (int k = 0; k < 16; ++k) t += myred[(rb + k) * 17 + cls];
        t += __shfl_xor(t, 16, 64);
        t += __shfl_xor(t, 32, 64);
        if (lane < 16) logits[(size_t)n * NCLS + lane] = t + bc;
        asm volatile("" ::: "memory");

#pragma unroll
        for (int r = 0; r < RELS; ++r) u[r] = un[r];
        n = nn;
    }
}

// ---------------- launcher ----------------

static inline int cdiv(int a, int b) { return (a + b - 1) / b; }

extern "C" void kernel_launch(void* const* d_in, const int* in_sizes, int n_in,
                              void* d_out, int out_size, void* d_ws, size_t ws_size,
                              hipStream_t stream) {
    const float* X     = (const float*)d_in[0];
    const int*   edges = (const int*)d_in[1];
    const float* W1    = (const float*)d_in[2];
    const float* W2    = (const float*)d_in[3];
    const float* att_q = (const float*)d_in[4];
    const float* tau   = (const float*)d_in[5];
    const float* W_out = (const float*)d_in[6];
    const float* b_out = (const float*)d_in[7];

    float* logits = (float*)d_out;
    float* alpha  = logits + (size_t)NODES * NCLS;

    char* p = (char*)d_ws;
    auto carve = [&](size_t bytes) -> char* {
        char* q = p;
        p += (bytes + 255) & ~(size_t)255;
        return q;
    };
    int*   deg_row  = (int*)carve((size_t)RELS * NODES * 4);
    int*   deg_col  = (int*)carve((size_t)RELS * NODES * 4);
    float* dinv_row = (float*)carve((size_t)RELS * NODES * 4);
    float* dinv_col = (float*)carve((size_t)RELS * NODES * 4);
    int*   row_ptr  = (int*)carve((size_t)RELS * RPS * 4 + 256);
    int*   tmp      = (int*)carve((size_t)RELS * NODES * 4);
    int*   btot     = (int*)carve((size_t)RELS * 64 * 4);
    int*   csr_col  = (int*)carve((size_t)RELS * EDGES * 4);
    unsigned short* Xbf  = (unsigned short*)carve((size_t)NODES * FEAT * 2);
    unsigned short* h1bf = (unsigned short*)carve((size_t)NODES * FEAT * 2);
    unsigned short* W1t  = (unsigned short*)carve((size_t)RELS * FEAT * FEAT * 2);
    unsigned short* W2t  = (unsigned short*)carve((size_t)RELS * FEAT * FEAT * 2);
    // BIG region: 5 slices of MPAD*FEAT bf16, phase-aliased:
    //   CSR phase:  ebuf(51.2M) | partR/offR(3.2M) | bbR
    //   layer 1:    agg[r] = S_r (r=0..3)
    //   layer 2:    spmm_r -> S_{r+1}; gemm2_r: S_{r+1} -> H2_r = S_r
    //   attn:       H2 slices contiguous at BIG, stride MPAD*FEAT
    const size_t AGGSE = (size_t)MPAD * FEAT;        // elements per slice
    char* BIG = carve(5 * AGGSE * 2);
    int2*     ebuf = (int2*)BIG;
    char*     q = BIG + (size_t)RELS * EDGES * 8;
    unsigned* partR = (unsigned*)q;               q += (size_t)RELS * NCHUNK * NB * 4;
    unsigned* offR  = (unsigned*)q;               q += (size_t)RELS * NCHUNK * NB * 4;
    unsigned* bbR   = (unsigned*)q;
    unsigned short* aggbf = (unsigned short*)BIG;
    unsigned short* H2bf  = (unsigned short*)BIG;   // S0..S3 after layer 2

    // CSR build: row side via bucket sort; col degrees via direct L2 atomics
    {
        dim3 hg(NCHUNK, RELS);
        dim3 bg(NB, RELS);
        k_zero<<<cdiv(RELS * NODES, 256), 256, 0, stream>>>(deg_col, RELS * NODES);
        k_bhist<<<hg, 256, 0, stream>>>(edges, 0, partR);
        k_bscan<<<RELS, 256, 0, stream>>>(partR, offR, bbR);
        k_scatR<<<hg, 256, 0, stream>>>(edges, offR, ebuf);
        k_countR<<<bg, 256, 0, stream>>>(ebuf, bbR, deg_row);
        k_dcol<<<dim3(EDGES / 256, RELS), 256, 0, stream>>>(edges, deg_col);
        k_dinv<<<cdiv(RELS * NODES, 256), 256, 0, stream>>>(deg_row, deg_col, dinv_row, dinv_col);
        dim3 sg(NSBLK, RELS);
        k_scanA<<<sg, 256, 0, stream>>>(deg_row, tmp, btot);
        k_scanB<<<RELS, 64, 0, stream>>>(btot, row_ptr);
        k_scanC<<<sg, 256, 0, stream>>>(tmp, btot, row_ptr);
        k_place<<<bg, 256, 0, stream>>>(ebuf, bbR, row_ptr, csr_col);
    }

    // conversions
    k_wt<<<cdiv(RELS * FEAT * FEAT, 256), 256, 0, stream>>>(W1, W1t);
    k_wt<<<cdiv(RELS * FEAT * FEAT, 256), 256, 0, stream>>>(W2, W2t);
    k_f2bf8<<<cdiv(NODES * FEAT / 8, 256), 256, 0, stream>>>(X, Xbf, NODES * FEAT / 8);

    dim3 gemm_grid(MPAD / 128, FEAT / 128);

    // Layer 1: 4 SPMMs into S0..S3, then one fused GEMM -> h1bf
    for (int r = 0; r < RELS; ++r)
        k_spmm<<<cdiv(NODES * 64, 256), 256, 0, stream>>>(Xbf, row_ptr, csr_col,
                                                          dinv_row, dinv_col,
                                                          aggbf + (size_t)r * AGGSE, r);
    k_gemm1<<<gemm_grid, 256, 0, stream>>>(aggbf, W1t, h1bf);

    // Layer 2: per relation, SPMM -> S_{r+1}, then GEMM: S_{r+1} -> H2_r = S_r
    for (int r = 0; r < RELS; ++r) {
        k_spmm<<<cdiv(NODES * 64, 256), 256, 0, stream>>>(h1bf, row_ptr, csr_col,
                                                          dinv_row, dinv_col,
                                                          aggbf + (size_t)(r + 1) * AGGSE, r);
        k_gemm2<<<gemm_grid, 256, 0, stream>>>(aggbf + (size_t)(r + 1) * AGGSE,
                                               W2t + (size_t)r * FEAT * FEAT,
                                               aggbf + (size_t)r * AGGSE);
    }

    // fused attention + output (single pass over H2)
    k_attn_out<<<1024, 256, 0, stream>>>(H2bf, att_q, tau, W_out, b_out, alpha, logits);
}

// Round 5
// 1475.718 us; speedup vs baseline: 1.5526x; 1.1696x over previous
//
#include <hip/hip_runtime.h>
#include <hip/hip_bf16.h>
#include <stdint.h>

#define NODES 50000
#define RELS  4
#define EDGES 1600000
#define FEAT  256
#define NCLS  16
#define MPAD  50048                 // 391 * 128
#define RPS   50016                 // row_ptr per-relation stride
#define SCHUNK 1024                 // scan elements per block
#define NSBLK  49                   // ceil(50000/1024)
#define NCHUNK 64                   // edge chunks per relation
#define CHUNKE 25000                // EDGES / NCHUNK
#define NB     782                  // node buckets of 64 rows (781*64+16)

typedef __attribute__((ext_vector_type(8))) short short8;
typedef __attribute__((ext_vector_type(8))) unsigned short u16x8;
typedef __attribute__((ext_vector_type(4))) float f32x4;

static __device__ __forceinline__ float bf2f(unsigned short u) {
    return __uint_as_float(((unsigned int)u) << 16);
}
static __device__ __forceinline__ unsigned short f2bf(float f) {
    unsigned int x = __float_as_uint(f);
    unsigned int r = x + 0x7fffu + ((x >> 16) & 1u);
    return (unsigned short)(r >> 16);
}

// ============ CSR build: bucket radix sort, zero global atomics ============

// per-(rel,chunk) LDS histogram of value>>6 -> part[rel][chunk][NB]
__global__ __launch_bounds__(256)
void k_bhist(const int* __restrict__ edges, int arr_off, unsigned* __restrict__ part) {
    int chunk = blockIdx.x, rel = blockIdx.y, t = threadIdx.x;
    const int* arr = edges + (size_t)rel * 2 * EDGES + arr_off + (size_t)chunk * CHUNKE;
    __shared__ unsigned h[NB];
    for (int i = t; i < NB; i += 256) h[i] = 0;
    __syncthreads();
    for (int e = t; e < CHUNKE; e += 256) atomicAdd(&h[((unsigned)arr[e]) >> 6], 1u);
    __syncthreads();
    unsigned* po = part + ((size_t)rel * NCHUNK + chunk) * NB;
    for (int i = t; i < NB; i += 256) po[i] = h[i];
}

// per relation: bucket bases (exclusive scan of totals) + per-(chunk,bucket) offsets
__global__ __launch_bounds__(256)
void k_bscan(const unsigned* __restrict__ part, unsigned* __restrict__ off,
             unsigned* __restrict__ bbase) {
    int rel = blockIdx.x, t = threadIdx.x;
    const int BPT = 4;                       // 256*4 >= NB
    int b0 = t * BPT;
    unsigned s = 0;
#pragma unroll
    for (int j = 0; j < BPT; ++j) {
        int b = b0 + j;
        unsigned x = 0;
        if (b < NB)
            for (int c = 0; c < NCHUNK; ++c)
                x += part[((size_t)rel * NCHUNK + c) * NB + b];
        s += x;
    }
    __shared__ unsigned sh[256];
    sh[t] = s;
    __syncthreads();
    for (int o = 1; o < 256; o <<= 1) {
        unsigned u = (t >= o) ? sh[t - o] : 0;
        __syncthreads();
        sh[t] += u;
        __syncthreads();
    }
    unsigned base = sh[t] - s;
#pragma unroll
    for (int j = 0; j < BPT; ++j) {
        int b = b0 + j;
        if (b < NB) {
            bbase[rel * (NB + 1) + b] = base;
            unsigned acc = base;
            for (int c = 0; c < NCHUNK; ++c) {
                size_t o2 = ((size_t)rel * NCHUNK + c) * NB + b;
                off[o2] = acc;
                acc += part[o2];
            }
            base = acc;
        }
    }
    if (t == 255) bbase[rel * (NB + 1) + NB] = sh[255];
}

// scatter (row,col) pairs into row-bucket order
__global__ __launch_bounds__(256)
void k_scatR(const int* __restrict__ edges, const unsigned* __restrict__ off,
             int2* __restrict__ ebuf) {
    int chunk = blockIdx.x, rel = blockIdx.y, t = threadIdx.x;
    const int* rows = edges + (size_t)rel * 2 * EDGES + (size_t)chunk * CHUNKE;
    const int* cols = rows + EDGES;
    __shared__ unsigned cur[NB];
    const unsigned* po = off + ((size_t)rel * NCHUNK + chunk) * NB;
    for (int i = t; i < NB; i += 256) cur[i] = po[i];
    __syncthreads();
    int2* eb = ebuf + (size_t)rel * EDGES;
    for (int e = t; e < CHUNKE; e += 256) {
        int r = rows[e], c = cols[e];
        unsigned pos = atomicAdd(&cur[((unsigned)r) >> 6], 1u);
        eb[pos] = make_int2(r, c);
    }
}

// scatter col values into col-bucket order (for col-degree counting)
__global__ __launch_bounds__(256)
void k_scatC(const int* __restrict__ edges, const unsigned* __restrict__ off,
             int* __restrict__ cbuf) {
    int chunk = blockIdx.x, rel = blockIdx.y, t = threadIdx.x;
    const int* cols = edges + (size_t)rel * 2 * EDGES + EDGES + (size_t)chunk * CHUNKE;
    __shared__ unsigned cur[NB];
    const unsigned* po = off + ((size_t)rel * NCHUNK + chunk) * NB;
    for (int i = t; i < NB; i += 256) cur[i] = po[i];
    __syncthreads();
    int* cb = cbuf + (size_t)rel * EDGES;
    for (int e = t; e < CHUNKE; e += 256) {
        int c = cols[e];
        unsigned pos = atomicAdd(&cur[((unsigned)c) >> 6], 1u);
        cb[pos] = c;
    }
}

// per-bucket row counts -> deg_row
__global__ __launch_bounds__(256)
void k_countR(const int2* __restrict__ ebuf, const unsigned* __restrict__ bbase,
              int* __restrict__ deg_row) {
    int b = blockIdx.x, rel = blockIdx.y, t = threadIdx.x;
    unsigned s = bbase[rel * (NB + 1) + b], e = bbase[rel * (NB + 1) + b + 1];
    __shared__ unsigned cnt[64];
    if (t < 64) cnt[t] = 0;
    __syncthreads();
    const int2* eb = ebuf + (size_t)rel * EDGES;
    for (unsigned i = s + t; i < e; i += 256) atomicAdd(&cnt[eb[i].x & 63], 1u);
    __syncthreads();
    int base = b * 64;
    if (t < 64 && base + t < NODES) deg_row[(size_t)rel * NODES + base + t] = (int)cnt[t];
}

// per-bucket col counts -> deg_col
__global__ __launch_bounds__(256)
void k_countC(const int* __restrict__ cbuf, const unsigned* __restrict__ bbase,
              int* __restrict__ deg_col) {
    int b = blockIdx.x, rel = blockIdx.y, t = threadIdx.x;
    unsigned s = bbase[rel * (NB + 1) + b], e = bbase[rel * (NB + 1) + b + 1];
    __shared__ unsigned cnt[64];
    if (t < 64) cnt[t] = 0;
    __syncthreads();
    const int* cb = cbuf + (size_t)rel * EDGES;
    for (unsigned i = s + t; i < e; i += 256) atomicAdd(&cnt[cb[i] & 63], 1u);
    __syncthreads();
    int base = b * 64;
    if (t < 64 && base + t < NODES) deg_col[(size_t)rel * NODES + base + t] = (int)cnt[t];
}

__global__ void k_dinv(const int* __restrict__ deg_row, const int* __restrict__ deg_col,
                       float* dinv_row, float* dinv_col) {
    int idx = blockIdx.x * blockDim.x + threadIdx.x;
    if (idx >= RELS * NODES) return;
    int dr = deg_row[idx]; if (dr < 1) dr = 1;
    int dc = deg_col[idx]; if (dc < 1) dc = 1;
    dinv_row[idx] = rsqrtf((float)dr);
    dinv_col[idx] = rsqrtf((float)dc);
}

// -------- parallel exclusive scan of deg_row -> row_ptr --------
__global__ __launch_bounds__(256)
void k_scanA(const int* __restrict__ deg, int* __restrict__ tmp, int* __restrict__ btot) {
    int r = blockIdx.y, blk = blockIdx.x, t = threadIdx.x;
    int i0 = blk * SCHUNK + t * 4;
    const int* d = deg + (size_t)r * NODES;
    int4 v = make_int4(0, 0, 0, 0);
    if (i0 + 3 < NODES) v = *(const int4*)(d + i0);
    else if (i0 < NODES) {
        v.x = d[i0];
        if (i0 + 1 < NODES) v.y = d[i0 + 1];
        if (i0 + 2 < NODES) v.z = d[i0 + 2];
    }
    int s = v.x + v.y + v.z + v.w;
    __shared__ int sh[256];
    sh[t] = s;
    __syncthreads();
    for (int off = 1; off < 256; off <<= 1) {
        int u = (t >= off) ? sh[t - off] : 0;
        __syncthreads();
        sh[t] += u;
        __syncthreads();
    }
    int excl = sh[t] - s;
    int4 o;
    o.x = excl; o.y = excl + v.x; o.z = o.y + v.y; o.w = o.z + v.z;
    int* tp = tmp + (size_t)r * NODES;
    if (i0 + 3 < NODES) *(int4*)(tp + i0) = o;
    else if (i0 < NODES) {
        tp[i0] = o.x;
        if (i0 + 1 < NODES) tp[i0 + 1] = o.y;
        if (i0 + 2 < NODES) tp[i0 + 2] = o.z;
    }
    if (t == 255) btot[r * 64 + blk] = sh[255];
}

__global__ void k_scanB(int* __restrict__ btot, int* __restrict__ row_ptr) {
    int r = blockIdx.x;
    if (threadIdx.x != 0) return;
    int acc = 0;
    for (int b = 0; b < NSBLK; ++b) {
        int v = btot[r * 64 + b];
        btot[r * 64 + b] = acc;
        acc += v;
    }
    row_ptr[r * RPS + NODES] = acc;
}

__global__ __launch_bounds__(256)
void k_scanC(const int* __restrict__ tmp, const int* __restrict__ btot,
             int* __restrict__ row_ptr) {
    int r = blockIdx.y, blk = blockIdx.x, t = threadIdx.x;
    int i0 = blk * SCHUNK + t * 4;
    int off = btot[r * 64 + blk];
    const int* tp = tmp + (size_t)r * NODES;
    int* rp = row_ptr + (size_t)r * RPS;
    if (i0 + 3 < NODES) {
        int4 v = *(const int4*)(tp + i0);
        rp[i0] = v.x + off; rp[i0 + 1] = v.y + off;
        rp[i0 + 2] = v.z + off; rp[i0 + 3] = v.w + off;
    } else if (i0 < NODES) {
        for (int j = 0; j < 4 && i0 + j < NODES; ++j)
            rp[i0 + j] = tp[i0 + j] + off;
    }
}

// per-bucket exact CSR fill: 64 LDS cursors, bucket csr range is contiguous (~8 KB)
__global__ __launch_bounds__(256)
void k_place(const int2* __restrict__ ebuf, const unsigned* __restrict__ bbase,
             const int* __restrict__ row_ptr, int* __restrict__ csr_col) {
    int b = blockIdx.x, rel = blockIdx.y, t = threadIdx.x;
    unsigned s = bbase[rel * (NB + 1) + b], e = bbase[rel * (NB + 1) + b + 1];
    __shared__ int cur[64];
    int base = b * 64;
    const int* rp = row_ptr + (size_t)rel * RPS;
    if (t < 64) cur[t] = (base + t < NODES) ? rp[base + t] : 0;
    __syncthreads();
    const int2* eb = ebuf + (size_t)rel * EDGES;
    int* cc = csr_col + (size_t)rel * EDGES;
    for (unsigned i = s + t; i < e; i += 256) {
        int2 ec = eb[i];
        int pos = atomicAdd(&cur[ec.x - base], 1);
        cc[pos] = ec.y;
    }
}

// ---------------- conversions ----------------

// 8 floats per thread -> u16x8 store
__global__ __launch_bounds__(256)
void k_f2bf8(const float* __restrict__ src, unsigned short* __restrict__ dst, int count8) {
    int i = blockIdx.x * 256 + threadIdx.x;
    if (i >= count8) return;
    const float* s = src + (size_t)i * 8;
    float4 a = *(const float4*)s;
    float4 b = *(const float4*)(s + 4);
    u16x8 v;
    v[0] = f2bf(a.x); v[1] = f2bf(a.y); v[2] = f2bf(a.z); v[3] = f2bf(a.w);
    v[4] = f2bf(b.x); v[5] = f2bf(b.y); v[6] = f2bf(b.z); v[7] = f2bf(b.w);
    *(u16x8*)(dst + (size_t)i * 8) = v;
}

__global__ void k_wt(const float* __restrict__ W, unsigned short* __restrict__ Wt) {
    int idx = blockIdx.x * blockDim.x + threadIdx.x;
    if (idx >= RELS * FEAT * FEAT) return;
    int r = idx >> 16;
    int rem = idx & 65535;
    int n = rem >> 8;
    int k = rem & 255;
    Wt[idx] = f2bf(W[(size_t)r * FEAT * FEAT + (size_t)k * FEAT + n]);
}

// ---------------- SPMM: wave per row, all 4 relations fused (grid.y = rel) ----------------
// Round-1 proven body: half-wave interleave, 2 edges in flight per half.
// slice_off selects target agg slice: rel + slice_off (layer1: 0 -> S0..S3, layer2: 1 -> S1..S4).

__global__ __launch_bounds__(256)
void k_spmm(const unsigned short* __restrict__ feat, const int* __restrict__ row_ptr,
            const int* __restrict__ csr_col, const float* __restrict__ dinv_row,
            const float* __restrict__ dinv_col, unsigned short* __restrict__ aggbase,
            int slice_off) {
    int rel = blockIdx.y;
    unsigned short* aggbf = aggbase + (size_t)(rel + slice_off) * (size_t)MPAD * FEAT;
    int wave = (blockIdx.x * blockDim.x + threadIdx.x) >> 6;
    int lane = threadIdx.x & 63;
    if (wave >= NODES) return;
    int row = wave;
    int half = lane >> 5;
    int l32  = lane & 31;
    int start = row_ptr[rel * RPS + row];
    int end   = row_ptr[rel * RPS + row + 1];
    const int* cols = csr_col + (size_t)rel * EDGES;
    const float* dc = dinv_col + rel * NODES;
    const unsigned short* fb = feat + l32 * 8;
    float acc[8] = {0.f, 0.f, 0.f, 0.f, 0.f, 0.f, 0.f, 0.f};
    int j = start + half;
    for (; j + 2 < end; j += 4) {
        int c0 = cols[j];
        int c1 = cols[j + 2];
        float w0 = dc[c0];
        float w1 = dc[c1];
        u16x8 u0 = *(const u16x8*)(fb + (size_t)c0 * FEAT);
        u16x8 u1 = *(const u16x8*)(fb + (size_t)c1 * FEAT);
#pragma unroll
        for (int i = 0; i < 8; ++i) acc[i] += w0 * bf2f(u0[i]);
#pragma unroll
        for (int i = 0; i < 8; ++i) acc[i] += w1 * bf2f(u1[i]);
    }
    if (j < end) {
        int c0 = cols[j];
        float w0 = dc[c0];
        u16x8 u0 = *(const u16x8*)(fb + (size_t)c0 * FEAT);
#pragma unroll
        for (int i = 0; i < 8; ++i) acc[i] += w0 * bf2f(u0[i]);
    }
#pragma unroll
    for (int i = 0; i < 8; ++i) acc[i] += __shfl_down(acc[i], 32, 64);
    if (half == 0) {
        float dr = dinv_row[rel * NODES + row];
        u16x8 o;
#pragma unroll
        for (int i = 0; i < 8; ++i) o[i] = f2bf(acc[i] * dr);
        *(u16x8*)(aggbf + (size_t)row * FEAT + l32 * 8) = o;
    }
}

// ---------------- MFMA GEMM (128x128 tile, BK=64, XOR-swizzled LDS) ----------------
// C/D layout: col = lane&15, row = quad*4 + reg.

__global__ __launch_bounds__(256)
void k_gemm1(const unsigned short* __restrict__ Abase, const unsigned short* __restrict__ Wt,
             unsigned short* __restrict__ h1bf) {
    __shared__ __align__(16) unsigned short As[128 * 64];
    __shared__ __align__(16) unsigned short Bs[128 * 64];
    int tid = threadIdx.x;
    int wave = tid >> 6, lane = tid & 63;
    int quad = lane >> 4, l16 = lane & 15;
    int wm = (wave & 1) * 64, wn = (wave >> 1) * 64;
    int row0 = blockIdx.x * 128, n0 = blockIdx.y * 128;

    f32x4 hacc[4][4];
#pragma unroll
    for (int mi = 0; mi < 4; ++mi)
#pragma unroll
        for (int ni = 0; ni < 4; ++ni)
            hacc[mi][ni] = (f32x4){0.f, 0.f, 0.f, 0.f};

    for (int r = 0; r < RELS; ++r) {
        const unsigned short* A  = Abase + (size_t)r * MPAD * FEAT;
        const unsigned short* Bt = Wt + (size_t)r * FEAT * FEAT;
        f32x4 acc[4][4];
#pragma unroll
        for (int mi = 0; mi < 4; ++mi)
#pragma unroll
            for (int ni = 0; ni < 4; ++ni)
                acc[mi][ni] = (f32x4){0.f, 0.f, 0.f, 0.f};

        for (int k0 = 0; k0 < FEAT; k0 += 64) {
#pragma unroll
            for (int issue = 0; issue < 4; ++issue) {
                int flat = issue * 256 + tid;
                int row = flat >> 3;
                int gr = flat & 7;
                int sg = gr ^ (row & 7);
                *(uint4*)&As[flat * 8] = *(const uint4*)(A + (size_t)(row0 + row) * FEAT + k0 + sg * 8);
                *(uint4*)&Bs[flat * 8] = *(const uint4*)(Bt + (size_t)(n0 + row) * FEAT + k0 + sg * 8);
            }
            __syncthreads();
#pragma unroll
            for (int ks = 0; ks < 2; ++ks) {
                int g = ks * 4 + quad;
                short8 af[4], bfr[4];
#pragma unroll
                for (int mi = 0; mi < 4; ++mi) {
                    int m = wm + mi * 16 + l16;
                    af[mi] = *(const short8*)&As[m * 64 + ((g ^ (m & 7)) << 3)];
                }
#pragma unroll
                for (int ni = 0; ni < 4; ++ni) {
                    int n = wn + ni * 16 + l16;
                    bfr[ni] = *(const short8*)&Bs[n * 64 + ((g ^ (n & 7)) << 3)];
                }
#pragma unroll
                for (int mi = 0; mi < 4; ++mi)
#pragma unroll
                    for (int ni = 0; ni < 4; ++ni)
                        acc[mi][ni] = __builtin_amdgcn_mfma_f32_16x16x32_bf16(af[mi], bfr[ni], acc[mi][ni], 0, 0, 0);
            }
            __syncthreads();
        }
#pragma unroll
        for (int mi = 0; mi < 4; ++mi)
#pragma unroll
            for (int ni = 0; ni < 4; ++ni)
#pragma unroll
                for (int i = 0; i < 4; ++i) {
                    float v = acc[mi][ni][i];
                    hacc[mi][ni][i] += 0.25f * (v > 0.f ? v : 0.f);
                }
    }

#pragma unroll
    for (int mi = 0; mi < 4; ++mi)
#pragma unroll
        for (int ni = 0; ni < 4; ++ni) {
            int col = n0 + wn + ni * 16 + l16;
#pragma unroll
            for (int i = 0; i < 4; ++i) {
                int row = row0 + wm + mi * 16 + quad * 4 + i;
                if (row < NODES) h1bf[(size_t)row * FEAT + col] = f2bf(hacc[mi][ni][i]);
            }
        }
}

__global__ __launch_bounds__(256)
void k_gemm2(const unsigned short* __restrict__ A, const unsigned short* __restrict__ Bt,
             unsigned short* __restrict__ H2) {
    __shared__ __align__(16) unsigned short As[128 * 64];
    __shared__ __align__(16) unsigned short Bs[128 * 64];
    int tid = threadIdx.x;
    int wave = tid >> 6, lane = tid & 63;
    int quad = lane >> 4, l16 = lane & 15;
    int wm = (wave & 1) * 64, wn = (wave >> 1) * 64;
    int row0 = blockIdx.x * 128, n0 = blockIdx.y * 128;

    f32x4 acc[4][4];
#pragma unroll
    for (int mi = 0; mi < 4; ++mi)
#pragma unroll
        for (int ni = 0; ni < 4; ++ni)
            acc[mi][ni] = (f32x4){0.f, 0.f, 0.f, 0.f};

    for (int k0 = 0; k0 < FEAT; k0 += 64) {
#pragma unroll
        for (int issue = 0; issue < 4; ++issue) {
            int flat = issue * 256 + tid;
            int row = flat >> 3;
            int gr = flat & 7;
            int sg = gr ^ (row & 7);
            *(uint4*)&As[flat * 8] = *(const uint4*)(A + (size_t)(row0 + row) * FEAT + k0 + sg * 8);
            *(uint4*)&Bs[flat * 8] = *(const uint4*)(Bt + (size_t)(n0 + row) * FEAT + k0 + sg * 8);
        }
        __syncthreads();
#pragma unroll
        for (int ks = 0; ks < 2; ++ks) {
            int g = ks * 4 + quad;
            short8 af[4], bfr[4];
#pragma unroll
            for (int mi = 0; mi < 4; ++mi) {
                int m = wm + mi * 16 + l16;
                af[mi] = *(const short8*)&As[m * 64 + ((g ^ (m & 7)) << 3)];
            }
#pragma unroll
            for (int ni = 0; ni < 4; ++ni) {
                int n = wn + ni * 16 + l16;
                bfr[ni] = *(const short8*)&Bs[n * 64 + ((g ^ (n & 7)) << 3)];
            }
#pragma unroll
            for (int mi = 0; mi < 4; ++mi)
#pragma unroll
                for (int ni = 0; ni < 4; ++ni)
                    acc[mi][ni] = __builtin_amdgcn_mfma_f32_16x16x32_bf16(af[mi], bfr[ni], acc[mi][ni], 0, 0, 0);
        }
        __syncthreads();
    }

#pragma unroll
    for (int mi = 0; mi < 4; ++mi)
#pragma unroll
        for (int ni = 0; ni < 4; ++ni) {
            int col = n0 + wn + ni * 16 + l16;
#pragma unroll
            for (int i = 0; i < 4; ++i) {
                int row = row0 + wm + mi * 16 + quad * 4 + i;
                if (row < NODES) {
                    float v = acc[mi][ni][i];
                    H2[(size_t)row * FEAT + col] = f2bf(v > 0.f ? v : 0.f);
                }
            }
        }
}

// ---------------- fused attention scores + softmax + combine + output GEMV ----------------
// H2 slices are MPAD*FEAT apart (they live in agg slices S0..S3).

__global__ __launch_bounds__(256)
void k_attn_out(const unsigned short* __restrict__ H2bf, const float* __restrict__ att_q,
                const float* __restrict__ tau_p, const float* __restrict__ W_out,
                const float* __restrict__ b_out, float* __restrict__ alpha_out,
                float* __restrict__ logits) {
    __shared__ float red[4][64 * 17];
    int tid = threadIdx.x;
    int wid = tid >> 6;
    int lane = tid & 63;
    int gwave = blockIdx.x * 4 + wid;
    int nwaves = gridDim.x * 4;

    float4 q = *(const float4*)(att_q + lane * 4);
    float tau = fminf(fmaxf(tau_p[0], 0.5f), 5.0f);
    float itau = 1.0f / tau;
    f32x4 Wr[4][4];
#pragma unroll
    for (int j = 0; j < 4; ++j)
#pragma unroll
        for (int c4 = 0; c4 < 4; ++c4) {
            float4 w = *(const float4*)(W_out + (size_t)(lane * 4 + j) * NCLS + c4 * 4);
            Wr[j][c4] = (f32x4){w.x, w.y, w.z, w.w};
        }
    float bc = b_out[lane & 15];
    float* myred = &red[wid][0];
    int cls = lane & 15;
    int rb = (lane >> 4) * 16;

    int n = gwave;
    if (n >= NODES) return;
    ushort4 u[RELS];
#pragma unroll
    for (int r = 0; r < RELS; ++r)
        u[r] = *(const ushort4*)(H2bf + ((size_t)r * MPAD + n) * FEAT + lane * 4);

    while (n < NODES) {
        int nn = n + nwaves;
        int nc = (nn < NODES) ? nn : n;
        ushort4 un[RELS];
#pragma unroll
        for (int r = 0; r < RELS; ++r)
            un[r] = *(const ushort4*)(H2bf + ((size_t)r * MPAD + nc) * FEAT + lane * 4);

        float h[RELS][4];
#pragma unroll
        for (int r = 0; r < RELS; ++r) {
            h[r][0] = bf2f(u[r].x); h[r][1] = bf2f(u[r].y);
            h[r][2] = bf2f(u[r].z); h[r][3] = bf2f(u[r].w);
        }
        float s[RELS];
#pragma unroll
        for (int r = 0; r < RELS; ++r)
            s[r] = h[r][0] * q.x + h[r][1] * q.y + h[r][2] * q.z + h[r][3] * q.w;
#pragma unroll
        for (int off = 1; off < 64; off <<= 1) {
#pragma unroll
            for (int r = 0; r < RELS; ++r) s[r] += __shfl_xor(s[r], off, 64);
        }
        float m = fmaxf(fmaxf(s[0], s[1]), fmaxf(s[2], s[3]));
        float e[RELS];
        float esum = 0.f;
#pragma unroll
        for (int r = 0; r < RELS; ++r) { e[r] = expf((s[r] - m) * itau); esum += e[r]; }
        float inv = 1.0f / esum;
        float a[RELS];
#pragma unroll
        for (int r = 0; r < RELS; ++r) a[r] = e[r] * inv;
        if (lane == 0)
            *(float4*)(alpha_out + (size_t)n * 4) = make_float4(a[0], a[1], a[2], a[3]);

        float w0 = 0.25f + a[0], w1 = 0.25f + a[1], w2 = 0.25f + a[2], w3 = 0.25f + a[3];
        float h2[4];
#pragma unroll
        for (int j = 0; j < 4; ++j)
            h2[j] = w0 * h[0][j] + w1 * h[1][j] + w2 * h[2][j] + w3 * h[3][j];

        f32x4 acc[4];
#pragma unroll
        for (int c4 = 0; c4 < 4; ++c4)
            acc[c4] = h2[0] * Wr[0][c4] + h2[1] * Wr[1][c4]
                    + h2[2] * Wr[2][c4] + h2[3] * Wr[3][c4];

#pragma unroll
        for (int c4 = 0; c4 < 4; ++c4)
#pragma unroll
            for (int i = 0; i < 4; ++i)
                myred[lane * 17 + c4 * 4 + i] = acc[c4][i];
        asm volatile("s_waitcnt lgkmcnt(0)" ::: "memory");
        float t = 0.f;
#pragma unroll
        for (int k = 0; k < 16; ++k) t += myred[(rb + k) * 17 + cls];
        t += __shfl_xor(t, 16, 64);
        t += __shfl_xor(t, 32, 64);
        if (lane < 16) logits[(size_t)n * NCLS + lane] = t + bc;
        asm volatile("" ::: "memory");

#pragma unroll
        for (int r = 0; r < RELS; ++r) u[r] = un[r];
        n = nn;
    }
}

// ---------------- launcher ----------------

static inline int cdiv(int a, int b) { return (a + b - 1) / b; }

extern "C" void kernel_launch(void* const* d_in, const int* in_sizes, int n_in,
                              void* d_out, int out_size, void* d_ws, size_t ws_size,
                              hipStream_t stream) {
    const float* X     = (const float*)d_in[0];
    const int*   edges = (const int*)d_in[1];
    const float* W1    = (const float*)d_in[2];
    const float* W2    = (const float*)d_in[3];
    const float* att_q = (const float*)d_in[4];
    const float* tau   = (const float*)d_in[5];
    const float* W_out = (const float*)d_in[6];
    const float* b_out = (const float*)d_in[7];

    float* logits = (float*)d_out;
    float* alpha  = logits + (size_t)NODES * NCLS;

    char* p = (char*)d_ws;
    auto carve = [&](size_t bytes) -> char* {
        char* q = p;
        p += (bytes + 255) & ~(size_t)255;
        return q;
    };
    int*   deg_row  = (int*)carve((size_t)RELS * NODES * 4);
    int*   deg_col  = (int*)carve((size_t)RELS * NODES * 4);
    float* dinv_row = (float*)carve((size_t)RELS * NODES * 4);
    float* dinv_col = (float*)carve((size_t)RELS * NODES * 4);
    int*   row_ptr  = (int*)carve((size_t)RELS * RPS * 4 + 256);
    int*   tmp      = (int*)carve((size_t)RELS * NODES * 4);
    int*   btot     = (int*)carve((size_t)RELS * 64 * 4);
    int*   csr_col  = (int*)carve((size_t)RELS * EDGES * 4);
    unsigned short* Xbf  = (unsigned short*)carve((size_t)NODES * FEAT * 2);
    unsigned short* h1bf = (unsigned short*)carve((size_t)NODES * FEAT * 2);
    unsigned short* W1t  = (unsigned short*)carve((size_t)RELS * FEAT * FEAT * 2);
    unsigned short* W2t  = (unsigned short*)carve((size_t)RELS * FEAT * FEAT * 2);
    // BIG region: 5 slices of MPAD*FEAT bf16, phase-aliased:
    //   CSR phase:  ebuf(51.2M) | cbuf(25.6M) | partR/offR/partC/offC(~6.4M) | bbR/bbC
    //   layer 1:    spmm -> S0..S3 (slice_off=0); gemm1 reads S0..S3 -> h1bf
    //   layer 2:    spmm -> S1..S4 (slice_off=1); gemm2_r: S_{r+1} -> H2_r = S_r
    //   attn:       H2 slices contiguous at BIG, stride MPAD*FEAT
    const size_t AGGSE = (size_t)MPAD * FEAT;        // elements per slice
    char* BIG = carve(5 * AGGSE * 2);
    int2*     ebuf = (int2*)BIG;
    int*      cbuf = (int*)(BIG + (size_t)RELS * EDGES * 8);
    char*     q = BIG + (size_t)RELS * EDGES * 12;
    unsigned* partR = (unsigned*)q;               q += (size_t)RELS * NCHUNK * NB * 4;
    unsigned* offR  = (unsigned*)q;               q += (size_t)RELS * NCHUNK * NB * 4;
    unsigned* partC = (unsigned*)q;               q += (size_t)RELS * NCHUNK * NB * 4;
    unsigned* offC  = (unsigned*)q;               q += (size_t)RELS * NCHUNK * NB * 4;
    unsigned* bbR   = (unsigned*)q;               q += (size_t)RELS * (NB + 1) * 4;
    unsigned* bbC   = (unsigned*)q;
    unsigned short* aggbf = (unsigned short*)BIG;
    unsigned short* H2bf  = (unsigned short*)BIG;   // S0..S3 after layer 2

    // CSR build: bucket radix sort (zero global atomics, no memsets)
    {
        dim3 hg(NCHUNK, RELS);
        dim3 bg(NB, RELS);
        k_bhist<<<hg, 256, 0, stream>>>(edges, 0, partR);
        k_bhist<<<hg, 256, 0, stream>>>(edges, EDGES, partC);
        k_bscan<<<RELS, 256, 0, stream>>>(partR, offR, bbR);
        k_bscan<<<RELS, 256, 0, stream>>>(partC, offC, bbC);
        k_scatR<<<hg, 256, 0, stream>>>(edges, offR, ebuf);
        k_scatC<<<hg, 256, 0, stream>>>(edges, offC, cbuf);
        k_countR<<<bg, 256, 0, stream>>>(ebuf, bbR, deg_row);
        k_countC<<<bg, 256, 0, stream>>>(cbuf, bbC, deg_col);
        k_dinv<<<cdiv(RELS * NODES, 256), 256, 0, stream>>>(deg_row, deg_col, dinv_row, dinv_col);
        dim3 sg(NSBLK, RELS);
        k_scanA<<<sg, 256, 0, stream>>>(deg_row, tmp, btot);
        k_scanB<<<RELS, 64, 0, stream>>>(btot, row_ptr);
        k_scanC<<<sg, 256, 0, stream>>>(tmp, btot, row_ptr);
        k_place<<<bg, 256, 0, stream>>>(ebuf, bbR, row_ptr, csr_col);
    }

    // conversions
    k_wt<<<cdiv(RELS * FEAT * FEAT, 256), 256, 0, stream>>>(W1, W1t);
    k_wt<<<cdiv(RELS * FEAT * FEAT, 256), 256, 0, stream>>>(W2, W2t);
    k_f2bf8<<<cdiv(NODES * FEAT / 8, 256), 256, 0, stream>>>(X, Xbf, NODES * FEAT / 8);

    dim3 gemm_grid(MPAD / 128, FEAT / 128);
    dim3 spmm_grid(cdiv(NODES * 64, 256), RELS);

    // Layer 1: one fused SPMM (4 rels) into S0..S3, then fused GEMM -> h1bf
    k_spmm<<<spmm_grid, 256, 0, stream>>>(Xbf, row_ptr, csr_col, dinv_row, dinv_col,
                                          aggbf, 0);
    k_gemm1<<<gemm_grid, 256, 0, stream>>>(aggbf, W1t, h1bf);

    // Layer 2: one fused SPMM (4 rels) into S1..S4, then 4 GEMMs: S_{r+1} -> S_r
    k_spmm<<<spmm_grid, 256, 0, stream>>>(h1bf, row_ptr, csr_col, dinv_row, dinv_col,
                                          aggbf, 1);
    for (int r = 0; r < RELS; ++r)
        k_gemm2<<<gemm_grid, 256, 0, stream>>>(aggbf + (size_t)(r + 1) * AGGSE,
                                               W2t + (size_t)r * FEAT * FEAT,
                                               aggbf + (size_t)r * AGGSE);

    // fused attention + output (single pass over H2)
    k_attn_out<<<1024, 256, 0, stream>>>(H2bf, att_q, tau, W_out, b_out, alpha, logits);
}

// Round 6
// 1457.561 us; speedup vs baseline: 1.5719x; 1.0125x over previous
//
#include <hip/hip_runtime.h>
#include <hip/hip_bf16.h>
#include <stdint.h>

#define NODES 50000
#define RELS  4
#define EDGES 1600000
#define FEAT  256
#define NCLS  16
#define MPAD  50048                 // 391 * 128
#define RPS   50016                 // row_ptr per-relation stride
#define SCHUNK 1024                 // scan elements per block
#define NSBLK  49                   // ceil(50000/1024)
#define NCHUNK 64                   // edge chunks per relation
#define CHUNKE 25000                // EDGES / NCHUNK
#define NB     782                  // node buckets of 64 rows (781*64+16)

typedef __attribute__((ext_vector_type(8))) short short8;
typedef __attribute__((ext_vector_type(8))) unsigned short u16x8;
typedef __attribute__((ext_vector_type(4))) float f32x4;

static __device__ __forceinline__ float bf2f(unsigned short u) {
    return __uint_as_float(((unsigned int)u) << 16);
}
static __device__ __forceinline__ unsigned short f2bf(float f) {
    unsigned int x = __float_as_uint(f);
    unsigned int r = x + 0x7fffu + ((x >> 16) & 1u);
    return (unsigned short)(r >> 16);
}

// ============ CSR build: bucket radix sort, zero global atomics ============

// one edge read pass -> BOTH row and col histograms (value>>6)
__global__ __launch_bounds__(256)
void k_bhist2(const int* __restrict__ edges, unsigned* __restrict__ partR,
              unsigned* __restrict__ partC) {
    int chunk = blockIdx.x, rel = blockIdx.y, t = threadIdx.x;
    const int* rows = edges + (size_t)rel * 2 * EDGES + (size_t)chunk * CHUNKE;
    const int* cols = rows + EDGES;
    __shared__ unsigned hR[NB];
    __shared__ unsigned hC[NB];
    for (int i = t; i < NB; i += 256) { hR[i] = 0; hC[i] = 0; }
    __syncthreads();
    for (int e = t; e < CHUNKE; e += 256) {
        atomicAdd(&hR[((unsigned)rows[e]) >> 6], 1u);
        atomicAdd(&hC[((unsigned)cols[e]) >> 6], 1u);
    }
    __syncthreads();
    unsigned* pR = partR + ((size_t)rel * NCHUNK + chunk) * NB;
    unsigned* pC = partC + ((size_t)rel * NCHUNK + chunk) * NB;
    for (int i = t; i < NB; i += 256) { pR[i] = hR[i]; pC[i] = hC[i]; }
}

// per relation: bucket bases (exclusive scan of totals) + per-(chunk,bucket) offsets
__global__ __launch_bounds__(256)
void k_bscan(const unsigned* __restrict__ part, unsigned* __restrict__ off,
             unsigned* __restrict__ bbase) {
    int rel = blockIdx.x, t = threadIdx.x;
    const int BPT = 4;                       // 256*4 >= NB
    int b0 = t * BPT;
    unsigned s = 0;
#pragma unroll
    for (int j = 0; j < BPT; ++j) {
        int b = b0 + j;
        unsigned x = 0;
        if (b < NB)
            for (int c = 0; c < NCHUNK; ++c)
                x += part[((size_t)rel * NCHUNK + c) * NB + b];
        s += x;
    }
    __shared__ unsigned sh[256];
    sh[t] = s;
    __syncthreads();
    for (int o = 1; o < 256; o <<= 1) {
        unsigned u = (t >= o) ? sh[t - o] : 0;
        __syncthreads();
        sh[t] += u;
        __syncthreads();
    }
    unsigned base = sh[t] - s;
#pragma unroll
    for (int j = 0; j < BPT; ++j) {
        int b = b0 + j;
        if (b < NB) {
            bbase[rel * (NB + 1) + b] = base;
            unsigned acc = base;
            for (int c = 0; c < NCHUNK; ++c) {
                size_t o2 = ((size_t)rel * NCHUNK + c) * NB + b;
                off[o2] = acc;
                acc += part[o2];
            }
            base = acc;
        }
    }
    if (t == 255) bbase[rel * (NB + 1) + NB] = sh[255];
}

// one edge read pass -> scatter (row,col) pairs (row-bucketed) AND cols (col-bucketed)
__global__ __launch_bounds__(256)
void k_scat2(const int* __restrict__ edges, const unsigned* __restrict__ offR,
             const unsigned* __restrict__ offC, int2* __restrict__ ebuf,
             int* __restrict__ cbuf) {
    int chunk = blockIdx.x, rel = blockIdx.y, t = threadIdx.x;
    const int* rows = edges + (size_t)rel * 2 * EDGES + (size_t)chunk * CHUNKE;
    const int* cols = rows + EDGES;
    __shared__ unsigned curR[NB];
    __shared__ unsigned curC[NB];
    const unsigned* pR = offR + ((size_t)rel * NCHUNK + chunk) * NB;
    const unsigned* pC = offC + ((size_t)rel * NCHUNK + chunk) * NB;
    for (int i = t; i < NB; i += 256) { curR[i] = pR[i]; curC[i] = pC[i]; }
    __syncthreads();
    int2* eb = ebuf + (size_t)rel * EDGES;
    int*  cb = cbuf + (size_t)rel * EDGES;
    for (int e = t; e < CHUNKE; e += 256) {
        int r = rows[e], c = cols[e];
        unsigned pr = atomicAdd(&curR[((unsigned)r) >> 6], 1u);
        eb[pr] = make_int2(r, c);
        unsigned pc = atomicAdd(&curC[((unsigned)c) >> 6], 1u);
        cb[pc] = c;
    }
}

// per-bucket row counts -> deg_row
__global__ __launch_bounds__(256)
void k_countR(const int2* __restrict__ ebuf, const unsigned* __restrict__ bbase,
              int* __restrict__ deg_row) {
    int b = blockIdx.x, rel = blockIdx.y, t = threadIdx.x;
    unsigned s = bbase[rel * (NB + 1) + b], e = bbase[rel * (NB + 1) + b + 1];
    __shared__ unsigned cnt[64];
    if (t < 64) cnt[t] = 0;
    __syncthreads();
    const int2* eb = ebuf + (size_t)rel * EDGES;
    for (unsigned i = s + t; i < e; i += 256) atomicAdd(&cnt[eb[i].x & 63], 1u);
    __syncthreads();
    int base = b * 64;
    if (t < 64 && base + t < NODES) deg_row[(size_t)rel * NODES + base + t] = (int)cnt[t];
}

// per-bucket col counts -> deg_col
__global__ __launch_bounds__(256)
void k_countC(const int* __restrict__ cbuf, const unsigned* __restrict__ bbase,
              int* __restrict__ deg_col) {
    int b = blockIdx.x, rel = blockIdx.y, t = threadIdx.x;
    unsigned s = bbase[rel * (NB + 1) + b], e = bbase[rel * (NB + 1) + b + 1];
    __shared__ unsigned cnt[64];
    if (t < 64) cnt[t] = 0;
    __syncthreads();
    const int* cb = cbuf + (size_t)rel * EDGES;
    for (unsigned i = s + t; i < e; i += 256) atomicAdd(&cnt[cb[i] & 63], 1u);
    __syncthreads();
    int base = b * 64;
    if (t < 64 && base + t < NODES) deg_col[(size_t)rel * NODES + base + t] = (int)cnt[t];
}

__global__ void k_dinv(const int* __restrict__ deg_row, const int* __restrict__ deg_col,
                       float* dinv_row, float* dinv_col) {
    int idx = blockIdx.x * blockDim.x + threadIdx.x;
    if (idx >= RELS * NODES) return;
    int dr = deg_row[idx]; if (dr < 1) dr = 1;
    int dc = deg_col[idx]; if (dc < 1) dc = 1;
    dinv_row[idx] = rsqrtf((float)dr);
    dinv_col[idx] = rsqrtf((float)dc);
}

// -------- parallel exclusive scan of deg_row -> row_ptr --------
__global__ __launch_bounds__(256)
void k_scanA(const int* __restrict__ deg, int* __restrict__ tmp, int* __restrict__ btot) {
    int r = blockIdx.y, blk = blockIdx.x, t = threadIdx.x;
    int i0 = blk * SCHUNK + t * 4;
    const int* d = deg + (size_t)r * NODES;
    int4 v = make_int4(0, 0, 0, 0);
    if (i0 + 3 < NODES) v = *(const int4*)(d + i0);
    else if (i0 < NODES) {
        v.x = d[i0];
        if (i0 + 1 < NODES) v.y = d[i0 + 1];
        if (i0 + 2 < NODES) v.z = d[i0 + 2];
    }
    int s = v.x + v.y + v.z + v.w;
    __shared__ int sh[256];
    sh[t] = s;
    __syncthreads();
    for (int off = 1; off < 256; off <<= 1) {
        int u = (t >= off) ? sh[t - off] : 0;
        __syncthreads();
        sh[t] += u;
        __syncthreads();
    }
    int excl = sh[t] - s;
    int4 o;
    o.x = excl; o.y = excl + v.x; o.z = o.y + v.y; o.w = o.z + v.z;
    int* tp = tmp + (size_t)r * NODES;
    if (i0 + 3 < NODES) *(int4*)(tp + i0) = o;
    else if (i0 < NODES) {
        tp[i0] = o.x;
        if (i0 + 1 < NODES) tp[i0 + 1] = o.y;
        if (i0 + 2 < NODES) tp[i0 + 2] = o.z;
    }
    if (t == 255) btot[r * 64 + blk] = sh[255];
}

__global__ void k_scanB(int* __restrict__ btot, int* __restrict__ row_ptr) {
    int r = blockIdx.x;
    if (threadIdx.x != 0) return;
    int acc = 0;
    for (int b = 0; b < NSBLK; ++b) {
        int v = btot[r * 64 + b];
        btot[r * 64 + b] = acc;
        acc += v;
    }
    row_ptr[r * RPS + NODES] = acc;
}

__global__ __launch_bounds__(256)
void k_scanC(const int* __restrict__ tmp, const int* __restrict__ btot,
             int* __restrict__ row_ptr) {
    int r = blockIdx.y, blk = blockIdx.x, t = threadIdx.x;
    int i0 = blk * SCHUNK + t * 4;
    int off = btot[r * 64 + blk];
    const int* tp = tmp + (size_t)r * NODES;
    int* rp = row_ptr + (size_t)r * RPS;
    if (i0 + 3 < NODES) {
        int4 v = *(const int4*)(tp + i0);
        rp[i0] = v.x + off; rp[i0 + 1] = v.y + off;
        rp[i0 + 2] = v.z + off; rp[i0 + 3] = v.w + off;
    } else if (i0 < NODES) {
        for (int j = 0; j < 4 && i0 + j < NODES; ++j)
            rp[i0 + j] = tp[i0 + j] + off;
    }
}

// per-bucket exact CSR fill: 64 LDS cursors, bucket csr range is contiguous (~8 KB)
__global__ __launch_bounds__(256)
void k_place(const int2* __restrict__ ebuf, const unsigned* __restrict__ bbase,
             const int* __restrict__ row_ptr, int* __restrict__ csr_col) {
    int b = blockIdx.x, rel = blockIdx.y, t = threadIdx.x;
    unsigned s = bbase[rel * (NB + 1) + b], e = bbase[rel * (NB + 1) + b + 1];
    __shared__ int cur[64];
    int base = b * 64;
    const int* rp = row_ptr + (size_t)rel * RPS;
    if (t < 64) cur[t] = (base + t < NODES) ? rp[base + t] : 0;
    __syncthreads();
    const int2* eb = ebuf + (size_t)rel * EDGES;
    int* cc = csr_col + (size_t)rel * EDGES;
    for (unsigned i = s + t; i < e; i += 256) {
        int2 ec = eb[i];
        int pos = atomicAdd(&cur[ec.x - base], 1);
        cc[pos] = ec.y;
    }
}

// ---------------- conversions ----------------

// 8 floats per thread -> u16x8 store
__global__ __launch_bounds__(256)
void k_f2bf8(const float* __restrict__ src, unsigned short* __restrict__ dst, int count8) {
    int i = blockIdx.x * 256 + threadIdx.x;
    if (i >= count8) return;
    const float* s = src + (size_t)i * 8;
    float4 a = *(const float4*)s;
    float4 b = *(const float4*)(s + 4);
    u16x8 v;
    v[0] = f2bf(a.x); v[1] = f2bf(a.y); v[2] = f2bf(a.z); v[3] = f2bf(a.w);
    v[4] = f2bf(b.x); v[5] = f2bf(b.y); v[6] = f2bf(b.z); v[7] = f2bf(b.w);
    *(u16x8*)(dst + (size_t)i * 8) = v;
}

// both weight transposes in one launch
__global__ void k_wt2(const float* __restrict__ W1, const float* __restrict__ W2,
                      unsigned short* __restrict__ W1t, unsigned short* __restrict__ W2t) {
    int idx = blockIdx.x * blockDim.x + threadIdx.x;
    const int half = RELS * FEAT * FEAT;
    if (idx >= 2 * half) return;
    const float* W = (idx < half) ? W1 : W2;
    unsigned short* Wt = (idx < half) ? W1t : W2t;
    int id = (idx < half) ? idx : idx - half;
    int r = id >> 16;
    int rem = id & 65535;
    int n = rem >> 8;
    int k = rem & 255;
    Wt[id] = f2bf(W[(size_t)r * FEAT * FEAT + (size_t)k * FEAT + n]);
}

// ---------------- SPMM: wave per row, all 4 relations fused (grid.y = rel) ----------------
// Proven body: half-wave interleave, 2 edges in flight per half.
// slice_off selects target agg slice: rel + slice_off.

__global__ __launch_bounds__(256)
void k_spmm(const unsigned short* __restrict__ feat, const int* __restrict__ row_ptr,
            const int* __restrict__ csr_col, const float* __restrict__ dinv_row,
            const float* __restrict__ dinv_col, unsigned short* __restrict__ aggbase,
            int slice_off) {
    int rel = blockIdx.y;
    unsigned short* aggbf = aggbase + (size_t)(rel + slice_off) * (size_t)MPAD * FEAT;
    int wave = (blockIdx.x * blockDim.x + threadIdx.x) >> 6;
    int lane = threadIdx.x & 63;
    if (wave >= NODES) return;
    int row = wave;
    int half = lane >> 5;
    int l32  = lane & 31;
    int start = row_ptr[rel * RPS + row];
    int end   = row_ptr[rel * RPS + row + 1];
    const int* cols = csr_col + (size_t)rel * EDGES;
    const float* dc = dinv_col + rel * NODES;
    const unsigned short* fb = feat + l32 * 8;
    float acc[8] = {0.f, 0.f, 0.f, 0.f, 0.f, 0.f, 0.f, 0.f};
    int j = start + half;
    for (; j + 2 < end; j += 4) {
        int c0 = cols[j];
        int c1 = cols[j + 2];
        float w0 = dc[c0];
        float w1 = dc[c1];
        u16x8 u0 = *(const u16x8*)(fb + (size_t)c0 * FEAT);
        u16x8 u1 = *(const u16x8*)(fb + (size_t)c1 * FEAT);
#pragma unroll
        for (int i = 0; i < 8; ++i) acc[i] += w0 * bf2f(u0[i]);
#pragma unroll
        for (int i = 0; i < 8; ++i) acc[i] += w1 * bf2f(u1[i]);
    }
    if (j < end) {
        int c0 = cols[j];
        float w0 = dc[c0];
        u16x8 u0 = *(const u16x8*)(fb + (size_t)c0 * FEAT);
#pragma unroll
        for (int i = 0; i < 8; ++i) acc[i] += w0 * bf2f(u0[i]);
    }
#pragma unroll
    for (int i = 0; i < 8; ++i) acc[i] += __shfl_down(acc[i], 32, 64);
    if (half == 0) {
        float dr = dinv_row[rel * NODES + row];
        u16x8 o;
#pragma unroll
        for (int i = 0; i < 8; ++i) o[i] = f2bf(acc[i] * dr);
        *(u16x8*)(aggbf + (size_t)row * FEAT + l32 * 8) = o;
    }
}

// ---------------- MFMA GEMM (128x128 tile, BK=64, XOR-swizzled LDS) ----------------
// C/D layout: col = lane&15, row = quad*4 + reg.

__global__ __launch_bounds__(256)
void k_gemm1(const unsigned short* __restrict__ Abase, const unsigned short* __restrict__ Wt,
             unsigned short* __restrict__ h1bf) {
    __shared__ __align__(16) unsigned short As[128 * 64];
    __shared__ __align__(16) unsigned short Bs[128 * 64];
    int tid = threadIdx.x;
    int wave = tid >> 6, lane = tid & 63;
    int quad = lane >> 4, l16 = lane & 15;
    int wm = (wave & 1) * 64, wn = (wave >> 1) * 64;
    int row0 = blockIdx.x * 128, n0 = blockIdx.y * 128;

    f32x4 hacc[4][4];
#pragma unroll
    for (int mi = 0; mi < 4; ++mi)
#pragma unroll
        for (int ni = 0; ni < 4; ++ni)
            hacc[mi][ni] = (f32x4){0.f, 0.f, 0.f, 0.f};

    for (int r = 0; r < RELS; ++r) {
        const unsigned short* A  = Abase + (size_t)r * MPAD * FEAT;
        const unsigned short* Bt = Wt + (size_t)r * FEAT * FEAT;
        f32x4 acc[4][4];
#pragma unroll
        for (int mi = 0; mi < 4; ++mi)
#pragma unroll
            for (int ni = 0; ni < 4; ++ni)
                acc[mi][ni] = (f32x4){0.f, 0.f, 0.f, 0.f};

        for (int k0 = 0; k0 < FEAT; k0 += 64) {
#pragma unroll
            for (int issue = 0; issue < 4; ++issue) {
                int flat = issue * 256 + tid;
                int row = flat >> 3;
                int gr = flat & 7;
                int sg = gr ^ (row & 7);
                *(uint4*)&As[flat * 8] = *(const uint4*)(A + (size_t)(row0 + row) * FEAT + k0 + sg * 8);
                *(uint4*)&Bs[flat * 8] = *(const uint4*)(Bt + (size_t)(n0 + row) * FEAT + k0 + sg * 8);
            }
            __syncthreads();
#pragma unroll
            for (int ks = 0; ks < 2; ++ks) {
                int g = ks * 4 + quad;
                short8 af[4], bfr[4];
#pragma unroll
                for (int mi = 0; mi < 4; ++mi) {
                    int m = wm + mi * 16 + l16;
                    af[mi] = *(const short8*)&As[m * 64 + ((g ^ (m & 7)) << 3)];
                }
#pragma unroll
                for (int ni = 0; ni < 4; ++ni) {
                    int n = wn + ni * 16 + l16;
                    bfr[ni] = *(const short8*)&Bs[n * 64 + ((g ^ (n & 7)) << 3)];
                }
#pragma unroll
                for (int mi = 0; mi < 4; ++mi)
#pragma unroll
                    for (int ni = 0; ni < 4; ++ni)
                        acc[mi][ni] = __builtin_amdgcn_mfma_f32_16x16x32_bf16(af[mi], bfr[ni], acc[mi][ni], 0, 0, 0);
            }
            __syncthreads();
        }
#pragma unroll
        for (int mi = 0; mi < 4; ++mi)
#pragma unroll
            for (int ni = 0; ni < 4; ++ni)
#pragma unroll
                for (int i = 0; i < 4; ++i) {
                    float v = acc[mi][ni][i];
                    hacc[mi][ni][i] += 0.25f * (v > 0.f ? v : 0.f);
                }
    }

#pragma unroll
    for (int mi = 0; mi < 4; ++mi)
#pragma unroll
        for (int ni = 0; ni < 4; ++ni) {
            int col = n0 + wn + ni * 16 + l16;
#pragma unroll
            for (int i = 0; i < 4; ++i) {
                int row = row0 + wm + mi * 16 + quad * 4 + i;
                if (row < NODES) h1bf[(size_t)row * FEAT + col] = f2bf(hacc[mi][ni][i]);
            }
        }
}

// fused layer-2 GEMM: grid.z = rel; reads S_{r+1}, writes 4 disjoint dead buffers
__global__ __launch_bounds__(256)
void k_gemm2z(const unsigned short* __restrict__ aggbase, const unsigned short* __restrict__ Wtb,
              unsigned short* __restrict__ o0, unsigned short* __restrict__ o1,
              unsigned short* __restrict__ o2, unsigned short* __restrict__ o3) {
    __shared__ __align__(16) unsigned short As[128 * 64];
    __shared__ __align__(16) unsigned short Bs[128 * 64];
    int rz = blockIdx.z;
    const unsigned short* A  = aggbase + (size_t)(rz + 1) * MPAD * FEAT;
    const unsigned short* Bt = Wtb + (size_t)rz * FEAT * FEAT;
    unsigned short* H2 = (rz == 0) ? o0 : (rz == 1) ? o1 : (rz == 2) ? o2 : o3;

    int tid = threadIdx.x;
    int wave = tid >> 6, lane = tid & 63;
    int quad = lane >> 4, l16 = lane & 15;
    int wm = (wave & 1) * 64, wn = (wave >> 1) * 64;
    int row0 = blockIdx.x * 128, n0 = blockIdx.y * 128;

    f32x4 acc[4][4];
#pragma unroll
    for (int mi = 0; mi < 4; ++mi)
#pragma unroll
        for (int ni = 0; ni < 4; ++ni)
            acc[mi][ni] = (f32x4){0.f, 0.f, 0.f, 0.f};

    for (int k0 = 0; k0 < FEAT; k0 += 64) {
#pragma unroll
        for (int issue = 0; issue < 4; ++issue) {
            int flat = issue * 256 + tid;
            int row = flat >> 3;
            int gr = flat & 7;
            int sg = gr ^ (row & 7);
            *(uint4*)&As[flat * 8] = *(const uint4*)(A + (size_t)(row0 + row) * FEAT + k0 + sg * 8);
            *(uint4*)&Bs[flat * 8] = *(const uint4*)(Bt + (size_t)(n0 + row) * FEAT + k0 + sg * 8);
        }
        __syncthreads();
#pragma unroll
        for (int ks = 0; ks < 2; ++ks) {
            int g = ks * 4 + quad;
            short8 af[4], bfr[4];
#pragma unroll
            for (int mi = 0; mi < 4; ++mi) {
                int m = wm + mi * 16 + l16;
                af[mi] = *(const short8*)&As[m * 64 + ((g ^ (m & 7)) << 3)];
            }
#pragma unroll
            for (int ni = 0; ni < 4; ++ni) {
                int n = wn + ni * 16 + l16;
                bfr[ni] = *(const short8*)&Bs[n * 64 + ((g ^ (n & 7)) << 3)];
            }
#pragma unroll
            for (int mi = 0; mi < 4; ++mi)
#pragma unroll
                for (int ni = 0; ni < 4; ++ni)
                    acc[mi][ni] = __builtin_amdgcn_mfma_f32_16x16x32_bf16(af[mi], bfr[ni], acc[mi][ni], 0, 0, 0);
        }
        __syncthreads();
    }

#pragma unroll
    for (int mi = 0; mi < 4; ++mi)
#pragma unroll
        for (int ni = 0; ni < 4; ++ni) {
            int col = n0 + wn + ni * 16 + l16;
#pragma unroll
            for (int i = 0; i < 4; ++i) {
                int row = row0 + wm + mi * 16 + quad * 4 + i;
                if (row < NODES) {
                    float v = acc[mi][ni][i];
                    H2[(size_t)row * FEAT + col] = f2bf(v > 0.f ? v : 0.f);
                }
            }
        }
}

// ---------------- fused attention scores + softmax + combine + output GEMV ----------------
// H2 slices passed as 4 explicit pointers (disjoint buffers).

__global__ __launch_bounds__(256)
void k_attn_out(const unsigned short* __restrict__ p0, const unsigned short* __restrict__ p1,
                const unsigned short* __restrict__ p2, const unsigned short* __restrict__ p3,
                const float* __restrict__ att_q, const float* __restrict__ tau_p,
                const float* __restrict__ W_out, const float* __restrict__ b_out,
                float* __restrict__ alpha_out, float* __restrict__ logits) {
    __shared__ float red[4][64 * 17];
    int tid = threadIdx.x;
    int wid = tid >> 6;
    int lane = tid & 63;
    int gwave = blockIdx.x * 4 + wid;
    int nwaves = gridDim.x * 4;

    const unsigned short* hp[RELS] = {p0, p1, p2, p3};
    float4 q = *(const float4*)(att_q + lane * 4);
    float tau = fminf(fmaxf(tau_p[0], 0.5f), 5.0f);
    float itau = 1.0f / tau;
    f32x4 Wr[4][4];
#pragma unroll
    for (int j = 0; j < 4; ++j)
#pragma unroll
        for (int c4 = 0; c4 < 4; ++c4) {
            float4 w = *(const float4*)(W_out + (size_t)(lane * 4 + j) * NCLS + c4 * 4);
            Wr[j][c4] = (f32x4){w.x, w.y, w.z, w.w};
        }
    float bc = b_out[lane & 15];
    float* myred = &red[wid][0];
    int cls = lane & 15;
    int rb = (lane >> 4) * 16;

    int n = gwave;
    if (n >= NODES) return;
    ushort4 u[RELS];
#pragma unroll
    for (int r = 0; r < RELS; ++r)
        u[r] = *(const ushort4*)(hp[r] + (size_t)n * FEAT + lane * 4);

    while (n < NODES) {
        int nn = n + nwaves;
        int nc = (nn < NODES) ? nn : n;
        ushort4 un[RELS];
#pragma unroll
        for (int r = 0; r < RELS; ++r)
            un[r] = *(const ushort4*)(hp[r] + (size_t)nc * FEAT + lane * 4);

        float h[RELS][4];
#pragma unroll
        for (int r = 0; r < RELS; ++r) {
            h[r][0] = bf2f(u[r].x); h[r][1] = bf2f(u[r].y);
            h[r][2] = bf2f(u[r].z); h[r][3] = bf2f(u[r].w);
        }
        float s[RELS];
#pragma unroll
        for (int r = 0; r < RELS; ++r)
            s[r] = h[r][0] * q.x + h[r][1] * q.y + h[r][2] * q.z + h[r][3] * q.w;
#pragma unroll
        for (int off = 1; off < 64; off <<= 1) {
#pragma unroll
            for (int r = 0; r < RELS; ++r) s[r] += __shfl_xor(s[r], off, 64);
        }
        float m = fmaxf(fmaxf(s[0], s[1]), fmaxf(s[2], s[3]));
        float e[RELS];
        float esum = 0.f;
#pragma unroll
        for (int r = 0; r < RELS; ++r) { e[r] = expf((s[r] - m) * itau); esum += e[r]; }
        float inv = 1.0f / esum;
        float a[RELS];
#pragma unroll
        for (int r = 0; r < RELS; ++r) a[r] = e[r] * inv;
        if (lane == 0)
            *(float4*)(alpha_out + (size_t)n * 4) = make_float4(a[0], a[1], a[2], a[3]);

        float w0 = 0.25f + a[0], w1 = 0.25f + a[1], w2 = 0.25f + a[2], w3 = 0.25f + a[3];
        float h2[4];
#pragma unroll
        for (int j = 0; j < 4; ++j)
            h2[j] = w0 * h[0][j] + w1 * h[1][j] + w2 * h[2][j] + w3 * h[3][j];

        f32x4 acc[4];
#pragma unroll
        for (int c4 = 0; c4 < 4; ++c4)
            acc[c4] = h2[0] * Wr[0][c4] + h2[1] * Wr[1][c4]
                    + h2[2] * Wr[2][c4] + h2[3] * Wr[3][c4];

#pragma unroll
        for (int c4 = 0; c4 < 4; ++c4)
#pragma unroll
            for (int i = 0; i < 4; ++i)
                myred[lane * 17 + c4 * 4 + i] = acc[c4][i];
        asm volatile("s_waitcnt lgkmcnt(0)" ::: "memory");
        float t = 0.f;
#pragma unroll
        for (int k = 0; k < 16; ++k) t += myred[(rb + k) * 17 + cls];
        t += __shfl_xor(t, 16, 64);
        t += __shfl_xor(t, 32, 64);
        if (lane < 16) logits[(size_t)n * NCLS + lane] = t + bc;
        asm volatile("" ::: "memory");

#pragma unroll
        for (int r = 0; r < RELS; ++r) u[r] = un[r];
        n = nn;
    }
}

// ---------------- launcher ----------------

static inline int cdiv(int a, int b) { return (a + b - 1) / b; }

extern "C" void kernel_launch(void* const* d_in, const int* in_sizes, int n_in,
                              void* d_out, int out_size, void* d_ws, size_t ws_size,
                              hipStream_t stream) {
    const float* X     = (const float*)d_in[0];
    const int*   edges = (const int*)d_in[1];
    const float* W1    = (const float*)d_in[2];
    const float* W2    = (const float*)d_in[3];
    const float* att_q = (const float*)d_in[4];
    const float* tau   = (const float*)d_in[5];
    const float* W_out = (const float*)d_in[6];
    const float* b_out = (const float*)d_in[7];

    float* logits = (float*)d_out;
    float* alpha  = logits + (size_t)NODES * NCLS;

    char* p = (char*)d_ws;
    auto carve = [&](size_t bytes) -> char* {
        char* q = p;
        p += (bytes + 255) & ~(size_t)255;
        return q;
    };
    int*   deg_row  = (int*)carve((size_t)RELS * NODES * 4);
    int*   deg_col  = (int*)carve((size_t)RELS * NODES * 4);
    float* dinv_row = (float*)carve((size_t)RELS * NODES * 4);
    float* dinv_col = (float*)carve((size_t)RELS * NODES * 4);
    int*   row_ptr  = (int*)carve((size_t)RELS * RPS * 4 + 256);
    int*   tmp      = (int*)carve((size_t)RELS * NODES * 4);
    int*   btot     = (int*)carve((size_t)RELS * 64 * 4);
    int*   csr_col  = (int*)carve((size_t)RELS * EDGES * 4);     // also H2_3 output (exactly 50000*256*2 B)
    unsigned short* Xbf  = (unsigned short*)carve((size_t)NODES * FEAT * 2);  // also H2_1 output
    unsigned short* h1bf = (unsigned short*)carve((size_t)NODES * FEAT * 2);  // also H2_2 output
    unsigned short* W1t  = (unsigned short*)carve((size_t)RELS * FEAT * FEAT * 2);
    unsigned short* W2t  = (unsigned short*)carve((size_t)RELS * FEAT * FEAT * 2);
    // BIG region: 5 slices of MPAD*FEAT bf16, phase-aliased:
    //   CSR phase:  ebuf(51.2M) | cbuf(25.6M) | partR/offR/partC/offC(~12.8M) | bbR/bbC
    //   layer 1:    spmm -> S0..S3 (slice_off=0); gemm1 reads S0..S3 -> h1bf
    //   layer 2:    spmm -> S1..S4 (slice_off=1); gemm2z reads S1..S4 -> {S0, Xbf, h1bf, csr_col}
    const size_t AGGSE = (size_t)MPAD * FEAT;        // elements per slice
    char* BIG = carve(5 * AGGSE * 2);
    int2*     ebuf = (int2*)BIG;
    int*      cbuf = (int*)(BIG + (size_t)RELS * EDGES * 8);
    char*     q = BIG + (size_t)RELS * EDGES * 12;
    unsigned* partR = (unsigned*)q;               q += (size_t)RELS * NCHUNK * NB * 4;
    unsigned* offR  = (unsigned*)q;               q += (size_t)RELS * NCHUNK * NB * 4;
    unsigned* partC = (unsigned*)q;               q += (size_t)RELS * NCHUNK * NB * 4;
    unsigned* offC  = (unsigned*)q;               q += (size_t)RELS * NCHUNK * NB * 4;
    unsigned* bbR   = (unsigned*)q;               q += (size_t)RELS * (NB + 1) * 4;
    unsigned* bbC   = (unsigned*)q;
    unsigned short* aggbf = (unsigned short*)BIG;
    // H2 destinations (all dead buffers at gemm2z time, disjoint from its inputs S1..S4)
    unsigned short* H2_0 = aggbf;                        // S0
    unsigned short* H2_1 = Xbf;
    unsigned short* H2_2 = h1bf;
    unsigned short* H2_3 = (unsigned short*)csr_col;     // 25,600,000 B == 50000*256*2

    // CSR build: bucket radix sort (zero global atomics, no memsets)
    {
        dim3 hg(NCHUNK, RELS);
        dim3 bg(NB, RELS);
        k_bhist2<<<hg, 256, 0, stream>>>(edges, partR, partC);
        k_bscan<<<RELS, 256, 0, stream>>>(partR, offR, bbR);
        k_bscan<<<RELS, 256, 0, stream>>>(partC, offC, bbC);
        k_scat2<<<hg, 256, 0, stream>>>(edges, offR, offC, ebuf, cbuf);
        k_countR<<<bg, 256, 0, stream>>>(ebuf, bbR, deg_row);
        k_countC<<<bg, 256, 0, stream>>>(cbuf, bbC, deg_col);
        k_dinv<<<cdiv(RELS * NODES, 256), 256, 0, stream>>>(deg_row, deg_col, dinv_row, dinv_col);
        dim3 sg(NSBLK, RELS);
        k_scanA<<<sg, 256, 0, stream>>>(deg_row, tmp, btot);
        k_scanB<<<RELS, 64, 0, stream>>>(btot, row_ptr);
        k_scanC<<<sg, 256, 0, stream>>>(tmp, btot, row_ptr);
        k_place<<<bg, 256, 0, stream>>>(ebuf, bbR, row_ptr, csr_col);
    }

    // conversions
    k_wt2<<<cdiv(2 * RELS * FEAT * FEAT, 256), 256, 0, stream>>>(W1, W2, W1t, W2t);
    k_f2bf8<<<cdiv(NODES * FEAT / 8, 256), 256, 0, stream>>>(X, Xbf, NODES * FEAT / 8);

    dim3 gemm_grid(MPAD / 128, FEAT / 128);
    dim3 gemm2_grid(MPAD / 128, FEAT / 128, RELS);
    dim3 spmm_grid(cdiv(NODES * 64, 256), RELS);

    // Layer 1: one fused SPMM (4 rels) into S0..S3, then fused GEMM -> h1bf
    k_spmm<<<spmm_grid, 256, 0, stream>>>(Xbf, row_ptr, csr_col, dinv_row, dinv_col,
                                          aggbf, 0);
    k_gemm1<<<gemm_grid, 256, 0, stream>>>(aggbf, W1t, h1bf);

    // Layer 2: one fused SPMM (4 rels) into S1..S4, then ONE fused GEMM (grid.z=rel)
    k_spmm<<<spmm_grid, 256, 0, stream>>>(h1bf, row_ptr, csr_col, dinv_row, dinv_col,
                                          aggbf, 1);
    k_gemm2z<<<gemm2_grid, 256, 0, stream>>>(aggbf, W2t, H2_0, H2_1, H2_2, H2_3);

    // fused attention + output (single pass over H2)
    k_attn_out<<<1024, 256, 0, stream>>>(H2_0, H2_1, H2_2, H2_3, att_q, tau,
                                         W_out, b_out, alpha, logits);
}

// Round 7
// 1437.462 us; speedup vs baseline: 1.5939x; 1.0140x over previous
//
#include <hip/hip_runtime.h>
#include <hip/hip_bf16.h>
#include <stdint.h>

#define NODES 50000
#define RELS  4
#define EDGES 1600000
#define FEAT  256
#define NCLS  16
#define MPAD  50048                 // 391 * 128
#define RPS   50016                 // row_ptr per-relation stride
#define NCHUNK 64                   // edge chunks per relation
#define CHUNKE 25000                // EDGES / NCHUNK
#define NB     782                  // node buckets of 64 rows (781*64+16)

typedef __attribute__((ext_vector_type(8))) short short8;
typedef __attribute__((ext_vector_type(8))) unsigned short u16x8;
typedef __attribute__((ext_vector_type(4))) float f32x4;

static __device__ __forceinline__ float bf2f(unsigned short u) {
    return __uint_as_float(((unsigned int)u) << 16);
}
static __device__ __forceinline__ unsigned short f2bf(float f) {
    unsigned int x = __float_as_uint(f);
    unsigned int r = x + 0x7fffu + ((x >> 16) & 1u);
    return (unsigned short)(r >> 16);
}

// ============ CSR build: bucket radix sort, zero global atomics ============
// Key structural fact: after the row-bucket scatter, bucket b's edges occupy
// exactly csr positions [bbR[b], bbR[b+1]) — so per-bucket count+scan+scatter
// reconstructs the exact CSR with NO deg_row array, NO global scan chain.

// one edge read pass -> BOTH row and col histograms (value>>6)
__global__ __launch_bounds__(256)
void k_bhist2(const int* __restrict__ edges, unsigned* __restrict__ partR,
              unsigned* __restrict__ partC) {
    int chunk = blockIdx.x, rel = blockIdx.y, t = threadIdx.x;
    const int* rows = edges + (size_t)rel * 2 * EDGES + (size_t)chunk * CHUNKE;
    const int* cols = rows + EDGES;
    __shared__ unsigned hR[NB];
    __shared__ unsigned hC[NB];
    for (int i = t; i < NB; i += 256) { hR[i] = 0; hC[i] = 0; }
    __syncthreads();
    for (int e = t; e < CHUNKE; e += 256) {
        atomicAdd(&hR[((unsigned)rows[e]) >> 6], 1u);
        atomicAdd(&hC[((unsigned)cols[e]) >> 6], 1u);
    }
    __syncthreads();
    unsigned* pR = partR + ((size_t)rel * NCHUNK + chunk) * NB;
    unsigned* pC = partC + ((size_t)rel * NCHUNK + chunk) * NB;
    for (int i = t; i < NB; i += 256) { pR[i] = hR[i]; pC[i] = hC[i]; }
}

// per relation: bucket bases (exclusive scan of totals) + per-(chunk,bucket) offsets
__global__ __launch_bounds__(256)
void k_bscan(const unsigned* __restrict__ part, unsigned* __restrict__ off,
             unsigned* __restrict__ bbase) {
    int rel = blockIdx.x, t = threadIdx.x;
    const int BPT = 4;                       // 256*4 >= NB
    int b0 = t * BPT;
    unsigned s = 0;
#pragma unroll
    for (int j = 0; j < BPT; ++j) {
        int b = b0 + j;
        unsigned x = 0;
        if (b < NB)
            for (int c = 0; c < NCHUNK; ++c)
                x += part[((size_t)rel * NCHUNK + c) * NB + b];
        s += x;
    }
    __shared__ unsigned sh[256];
    sh[t] = s;
    __syncthreads();
    for (int o = 1; o < 256; o <<= 1) {
        unsigned u = (t >= o) ? sh[t - o] : 0;
        __syncthreads();
        sh[t] += u;
        __syncthreads();
    }
    unsigned base = sh[t] - s;
#pragma unroll
    for (int j = 0; j < BPT; ++j) {
        int b = b0 + j;
        if (b < NB) {
            bbase[rel * (NB + 1) + b] = base;
            unsigned acc = base;
            for (int c = 0; c < NCHUNK; ++c) {
                size_t o2 = ((size_t)rel * NCHUNK + c) * NB + b;
                off[o2] = acc;
                acc += part[o2];
            }
            base = acc;
        }
    }
    if (t == 255) bbase[rel * (NB + 1) + NB] = sh[255];
}

// one edge read pass -> scatter PACKED (row&63,col) (row-bucketed, 4B/edge)
// AND cols (col-bucketed). col < 50000 < 2^16, row&63 < 2^6 -> fits one uint.
__global__ __launch_bounds__(256)
void k_scat2(const int* __restrict__ edges, const unsigned* __restrict__ offR,
             const unsigned* __restrict__ offC, unsigned* __restrict__ ebuf,
             int* __restrict__ cbuf) {
    int chunk = blockIdx.x, rel = blockIdx.y, t = threadIdx.x;
    const int* rows = edges + (size_t)rel * 2 * EDGES + (size_t)chunk * CHUNKE;
    const int* cols = rows + EDGES;
    __shared__ unsigned curR[NB];
    __shared__ unsigned curC[NB];
    const unsigned* pR = offR + ((size_t)rel * NCHUNK + chunk) * NB;
    const unsigned* pC = offC + ((size_t)rel * NCHUNK + chunk) * NB;
    for (int i = t; i < NB; i += 256) { curR[i] = pR[i]; curC[i] = pC[i]; }
    __syncthreads();
    unsigned* eb = ebuf + (size_t)rel * EDGES;
    int*      cb = cbuf + (size_t)rel * EDGES;
    for (int e = t; e < CHUNKE; e += 256) {
        int r = rows[e], c = cols[e];
        unsigned pr = atomicAdd(&curR[((unsigned)r) >> 6], 1u);
        eb[pr] = (((unsigned)(r & 63)) << 16) | (unsigned)c;
        unsigned pc = atomicAdd(&curC[((unsigned)c) >> 6], 1u);
        cb[pc] = c;
    }
}

// per-bucket col counts -> dinv_col directly (no deg_col array, no k_dinv)
__global__ __launch_bounds__(256)
void k_countC(const int* __restrict__ cbuf, const unsigned* __restrict__ bbase,
              float* __restrict__ dinv_col) {
    int b = blockIdx.x, rel = blockIdx.y, t = threadIdx.x;
    unsigned s = bbase[rel * (NB + 1) + b], e = bbase[rel * (NB + 1) + b + 1];
    __shared__ unsigned cnt[64];
    if (t < 64) cnt[t] = 0;
    __syncthreads();
    const int* cb = cbuf + (size_t)rel * EDGES;
    for (unsigned i = s + t; i < e; i += 256) atomicAdd(&cnt[cb[i] & 63], 1u);
    __syncthreads();
    int base = b * 64;
    if (t < 64 && base + t < NODES) {
        int d = (int)cnt[t]; if (d < 1) d = 1;
        dinv_col[(size_t)rel * NODES + base + t] = rsqrtf((float)d);
    }
}

// fused per-bucket count + 64-lane scan + CSR scatter.
// Bucket b's csr range is exactly [bbR[b], bbR[b+1]); row_ptr and dinv_row are
// byproducts. Replaces countR + scanA/B/C + k_dinv(row) + old k_place.
__global__ __launch_bounds__(256)
void k_place2(const unsigned* __restrict__ ebuf, const unsigned* __restrict__ bbase,
              int* __restrict__ csr_col, int* __restrict__ row_ptr,
              float* __restrict__ dinv_row) {
    int b = blockIdx.x, rel = blockIdx.y, t = threadIdx.x;
    unsigned s = bbase[rel * (NB + 1) + b], e = bbase[rel * (NB + 1) + b + 1];
    __shared__ unsigned cnt[64];
    __shared__ int cur[64];
    if (t < 64) cnt[t] = 0;
    __syncthreads();
    const unsigned* eb = ebuf + (size_t)rel * EDGES;
    for (unsigned i = s + t; i < e; i += 256) atomicAdd(&cnt[eb[i] >> 16], 1u);
    __syncthreads();
    if (t < 64) {                     // wave 0 only: 64-lane inclusive shfl scan
        unsigned c = cnt[t];
        unsigned v = c;
#pragma unroll
        for (int off = 1; off < 64; off <<= 1) {
            unsigned n = __shfl_up(v, off, 64);
            if (t >= off) v += n;
        }
        unsigned excl = v - c;
        int base = b * 64;
        cur[t] = (int)(s + excl);
        if (base + t < NODES) {
            row_ptr[rel * RPS + base + t] = (int)(s + excl);
            int d = (int)c; if (d < 1) d = 1;
            dinv_row[(size_t)rel * NODES + base + t] = rsqrtf((float)d);
        }
        if (b == 0 && t == 0) row_ptr[rel * RPS + NODES] = EDGES;
    }
    __syncthreads();
    int* cc = csr_col + (size_t)rel * EDGES;
    for (unsigned i = s + t; i < e; i += 256) {   // bucket range re-read: L2-warm
        unsigned v = eb[i];
        int pos = atomicAdd(&cur[v >> 16], 1);
        cc[pos] = (int)(v & 0xFFFFu);
    }
}

// ---------------- conversions ----------------

// 8 floats per thread -> u16x8 store
__global__ __launch_bounds__(256)
void k_f2bf8(const float* __restrict__ src, unsigned short* __restrict__ dst, int count8) {
    int i = blockIdx.x * 256 + threadIdx.x;
    if (i >= count8) return;
    const float* s = src + (size_t)i * 8;
    float4 a = *(const float4*)s;
    float4 b = *(const float4*)(s + 4);
    u16x8 v;
    v[0] = f2bf(a.x); v[1] = f2bf(a.y); v[2] = f2bf(a.z); v[3] = f2bf(a.w);
    v[4] = f2bf(b.x); v[5] = f2bf(b.y); v[6] = f2bf(b.z); v[7] = f2bf(b.w);
    *(u16x8*)(dst + (size_t)i * 8) = v;
}

// both weight transposes in one launch
__global__ void k_wt2(const float* __restrict__ W1, const float* __restrict__ W2,
                      unsigned short* __restrict__ W1t, unsigned short* __restrict__ W2t) {
    int idx = blockIdx.x * blockDim.x + threadIdx.x;
    const int half = RELS * FEAT * FEAT;
    if (idx >= 2 * half) return;
    const float* W = (idx < half) ? W1 : W2;
    unsigned short* Wt = (idx < half) ? W1t : W2t;
    int id = (idx < half) ? idx : idx - half;
    int r = id >> 16;
    int rem = id & 65535;
    int n = rem >> 8;
    int k = rem & 255;
    Wt[id] = f2bf(W[(size_t)r * FEAT * FEAT + (size_t)k * FEAT + n]);
}

// ---------------- SPMM: wave per row, all 4 relations fused (grid.y = rel) ----------------
// Proven body (stable at ~390 us, beyond-L2 BW ceiling): half-wave interleave,
// 2 edges in flight per half. slice_off selects target agg slice: rel + slice_off.

__global__ __launch_bounds__(256)
void k_spmm(const unsigned short* __restrict__ feat, const int* __restrict__ row_ptr,
            const int* __restrict__ csr_col, const float* __restrict__ dinv_row,
            const float* __restrict__ dinv_col, unsigned short* __restrict__ aggbase,
            int slice_off) {
    int rel = blockIdx.y;
    unsigned short* aggbf = aggbase + (size_t)(rel + slice_off) * (size_t)MPAD * FEAT;
    int wave = (blockIdx.x * blockDim.x + threadIdx.x) >> 6;
    int lane = threadIdx.x & 63;
    if (wave >= NODES) return;
    int row = wave;
    int half = lane >> 5;
    int l32  = lane & 31;
    int start = row_ptr[rel * RPS + row];
    int end   = row_ptr[rel * RPS + row + 1];
    const int* cols = csr_col + (size_t)rel * EDGES;
    const float* dc = dinv_col + rel * NODES;
    const unsigned short* fb = feat + l32 * 8;
    float acc[8] = {0.f, 0.f, 0.f, 0.f, 0.f, 0.f, 0.f, 0.f};
    int j = start + half;
    for (; j + 2 < end; j += 4) {
        int c0 = cols[j];
        int c1 = cols[j + 2];
        float w0 = dc[c0];
        float w1 = dc[c1];
        u16x8 u0 = *(const u16x8*)(fb + (size_t)c0 * FEAT);
        u16x8 u1 = *(const u16x8*)(fb + (size_t)c1 * FEAT);
#pragma unroll
        for (int i = 0; i < 8; ++i) acc[i] += w0 * bf2f(u0[i]);
#pragma unroll
        for (int i = 0; i < 8; ++i) acc[i] += w1 * bf2f(u1[i]);
    }
    if (j < end) {
        int c0 = cols[j];
        float w0 = dc[c0];
        u16x8 u0 = *(const u16x8*)(fb + (size_t)c0 * FEAT);
#pragma unroll
        for (int i = 0; i < 8; ++i) acc[i] += w0 * bf2f(u0[i]);
    }
#pragma unroll
    for (int i = 0; i < 8; ++i) acc[i] += __shfl_down(acc[i], 32, 64);
    if (half == 0) {
        float dr = dinv_row[rel * NODES + row];
        u16x8 o;
#pragma unroll
        for (int i = 0; i < 8; ++i) o[i] = f2bf(acc[i] * dr);
        *(u16x8*)(aggbf + (size_t)row * FEAT + l32 * 8) = o;
    }
}

// ---------------- MFMA GEMM (128x128 tile, BK=64, XOR-swizzled LDS) ----------------
// C/D layout: col = lane&15, row = quad*4 + reg.

__global__ __launch_bounds__(256)
void k_gemm1(const unsigned short* __restrict__ Abase, const unsigned short* __restrict__ Wt,
             unsigned short* __restrict__ h1bf) {
    __shared__ __align__(16) unsigned short As[128 * 64];
    __shared__ __align__(16) unsigned short Bs[128 * 64];
    int tid = threadIdx.x;
    int wave = tid >> 6, lane = tid & 63;
    int quad = lane >> 4, l16 = lane & 15;
    int wm = (wave & 1) * 64, wn = (wave >> 1) * 64;
    int row0 = blockIdx.x * 128, n0 = blockIdx.y * 128;

    f32x4 hacc[4][4];
#pragma unroll
    for (int mi = 0; mi < 4; ++mi)
#pragma unroll
        for (int ni = 0; ni < 4; ++ni)
            hacc[mi][ni] = (f32x4){0.f, 0.f, 0.f, 0.f};

    for (int r = 0; r < RELS; ++r) {
        const unsigned short* A  = Abase + (size_t)r * MPAD * FEAT;
        const unsigned short* Bt = Wt + (size_t)r * FEAT * FEAT;
        f32x4 acc[4][4];
#pragma unroll
        for (int mi = 0; mi < 4; ++mi)
#pragma unroll
            for (int ni = 0; ni < 4; ++ni)
                acc[mi][ni] = (f32x4){0.f, 0.f, 0.f, 0.f};

        for (int k0 = 0; k0 < FEAT; k0 += 64) {
#pragma unroll
            for (int issue = 0; issue < 4; ++issue) {
                int flat = issue * 256 + tid;
                int row = flat >> 3;
                int gr = flat & 7;
                int sg = gr ^ (row & 7);
                *(uint4*)&As[flat * 8] = *(const uint4*)(A + (size_t)(row0 + row) * FEAT + k0 + sg * 8);
                *(uint4*)&Bs[flat * 8] = *(const uint4*)(Bt + (size_t)(n0 + row) * FEAT + k0 + sg * 8);
            }
            __syncthreads();
#pragma unroll
            for (int ks = 0; ks < 2; ++ks) {
                int g = ks * 4 + quad;
                short8 af[4], bfr[4];
#pragma unroll
                for (int mi = 0; mi < 4; ++mi) {
                    int m = wm + mi * 16 + l16;
                    af[mi] = *(const short8*)&As[m * 64 + ((g ^ (m & 7)) << 3)];
                }
#pragma unroll
                for (int ni = 0; ni < 4; ++ni) {
                    int n = wn + ni * 16 + l16;
                    bfr[ni] = *(const short8*)&Bs[n * 64 + ((g ^ (n & 7)) << 3)];
                }
#pragma unroll
                for (int mi = 0; mi < 4; ++mi)
#pragma unroll
                    for (int ni = 0; ni < 4; ++ni)
                        acc[mi][ni] = __builtin_amdgcn_mfma_f32_16x16x32_bf16(af[mi], bfr[ni], acc[mi][ni], 0, 0, 0);
            }
            __syncthreads();
        }
#pragma unroll
        for (int mi = 0; mi < 4; ++mi)
#pragma unroll
            for (int ni = 0; ni < 4; ++ni)
#pragma unroll
                for (int i = 0; i < 4; ++i) {
                    float v = acc[mi][ni][i];
                    hacc[mi][ni][i] += 0.25f * (v > 0.f ? v : 0.f);
                }
    }

#pragma unroll
    for (int mi = 0; mi < 4; ++mi)
#pragma unroll
        for (int ni = 0; ni < 4; ++ni) {
            int col = n0 + wn + ni * 16 + l16;
#pragma unroll
            for (int i = 0; i < 4; ++i) {
                int row = row0 + wm + mi * 16 + quad * 4 + i;
                if (row < NODES) h1bf[(size_t)row * FEAT + col] = f2bf(hacc[mi][ni][i]);
            }
        }
}

// fused layer-2 GEMM: grid.z = rel; reads S_{r+1}, writes 4 disjoint dead buffers
__global__ __launch_bounds__(256)
void k_gemm2z(const unsigned short* __restrict__ aggbase, const unsigned short* __restrict__ Wtb,
              unsigned short* __restrict__ o0, unsigned short* __restrict__ o1,
              unsigned short* __restrict__ o2, unsigned short* __restrict__ o3) {
    __shared__ __align__(16) unsigned short As[128 * 64];
    __shared__ __align__(16) unsigned short Bs[128 * 64];
    int rz = blockIdx.z;
    const unsigned short* A  = aggbase + (size_t)(rz + 1) * MPAD * FEAT;
    const unsigned short* Bt = Wtb + (size_t)rz * FEAT * FEAT;
    unsigned short* H2 = (rz == 0) ? o0 : (rz == 1) ? o1 : (rz == 2) ? o2 : o3;

    int tid = threadIdx.x;
    int wave = tid >> 6, lane = tid & 63;
    int quad = lane >> 4, l16 = lane & 15;
    int wm = (wave & 1) * 64, wn = (wave >> 1) * 64;
    int row0 = blockIdx.x * 128, n0 = blockIdx.y * 128;

    f32x4 acc[4][4];
#pragma unroll
    for (int mi = 0; mi < 4; ++mi)
#pragma unroll
        for (int ni = 0; ni < 4; ++ni)
            acc[mi][ni] = (f32x4){0.f, 0.f, 0.f, 0.f};

    for (int k0 = 0; k0 < FEAT; k0 += 64) {
#pragma unroll
        for (int issue = 0; issue < 4; ++issue) {
            int flat = issue * 256 + tid;
            int row = flat >> 3;
            int gr = flat & 7;
            int sg = gr ^ (row & 7);
            *(uint4*)&As[flat * 8] = *(const uint4*)(A + (size_t)(row0 + row) * FEAT + k0 + sg * 8);
            *(uint4*)&Bs[flat * 8] = *(const uint4*)(Bt + (size_t)(n0 + row) * FEAT + k0 + sg * 8);
        }
        __syncthreads();
#pragma unroll
        for (int ks = 0; ks < 2; ++ks) {
            int g = ks * 4 + quad;
            short8 af[4], bfr[4];
#pragma unroll
            for (int mi = 0; mi < 4; ++mi) {
                int m = wm + mi * 16 + l16;
                af[mi] = *(const short8*)&As[m * 64 + ((g ^ (m & 7)) << 3)];
            }
#pragma unroll
            for (int ni = 0; ni < 4; ++ni) {
                int n = wn + ni * 16 + l16;
                bfr[ni] = *(const short8*)&Bs[n * 64 + ((g ^ (n & 7)) << 3)];
            }
#pragma unroll
            for (int mi = 0; mi < 4; ++mi)
#pragma unroll
                for (int ni = 0; ni < 4; ++ni)
                    acc[mi][ni] = __builtin_amdgcn_mfma_f32_16x16x32_bf16(af[mi], bfr[ni], acc[mi][ni], 0, 0, 0);
        }
        __syncthreads();
    }

#pragma unroll
    for (int mi = 0; mi < 4; ++mi)
#pragma unroll
        for (int ni = 0; ni < 4; ++ni) {
            int col = n0 + wn + ni * 16 + l16;
#pragma unroll
            for (int i = 0; i < 4; ++i) {
                int row = row0 + wm + mi * 16 + quad * 4 + i;
                if (row < NODES) {
                    float v = acc[mi][ni][i];
                    H2[(size_t)row * FEAT + col] = f2bf(v > 0.f ? v : 0.f);
                }
            }
        }
}

// ---------------- fused attention scores + softmax + combine + output GEMV ----------------
// H2 slices passed as 4 explicit pointers (disjoint buffers).

__global__ __launch_bounds__(256)
void k_attn_out(const unsigned short* __restrict__ p0, const unsigned short* __restrict__ p1,
                const unsigned short* __restrict__ p2, const unsigned short* __restrict__ p3,
                const float* __restrict__ att_q, const float* __restrict__ tau_p,
                const float* __restrict__ W_out, const float* __restrict__ b_out,
                float* __restrict__ alpha_out, float* __restrict__ logits) {
    __shared__ float red[4][64 * 17];
    int tid = threadIdx.x;
    int wid = tid >> 6;
    int lane = tid & 63;
    int gwave = blockIdx.x * 4 + wid;
    int nwaves = gridDim.x * 4;

    const unsigned short* hp[RELS] = {p0, p1, p2, p3};
    float4 q = *(const float4*)(att_q + lane * 4);
    float tau = fminf(fmaxf(tau_p[0], 0.5f), 5.0f);
    float itau = 1.0f / tau;
    f32x4 Wr[4][4];
#pragma unroll
    for (int j = 0; j < 4; ++j)
#pragma unroll
        for (int c4 = 0; c4 < 4; ++c4) {
            float4 w = *(const float4*)(W_out + (size_t)(lane * 4 + j) * NCLS + c4 * 4);
            Wr[j][c4] = (f32x4){w.x, w.y, w.z, w.w};
        }
    float bc = b_out[lane & 15];
    float* myred = &red[wid][0];
    int cls = lane & 15;
    int rb = (lane >> 4) * 16;

    int n = gwave;
    if (n >= NODES) return;
    ushort4 u[RELS];
#pragma unroll
    for (int r = 0; r < RELS; ++r)
        u[r] = *(const ushort4*)(hp[r] + (size_t)n * FEAT + lane * 4);

    while (n < NODES) {
        int nn = n + nwaves;
        int nc = (nn < NODES) ? nn : n;
        ushort4 un[RELS];
#pragma unroll
        for (int r = 0; r < RELS; ++r)
            un[r] = *(const ushort4*)(hp[r] + (size_t)nc * FEAT + lane * 4);

        float h[RELS][4];
#pragma unroll
        for (int r = 0; r < RELS; ++r) {
            h[r][0] = bf2f(u[r].x); h[r][1] = bf2f(u[r].y);
            h[r][2] = bf2f(u[r].z); h[r][3] = bf2f(u[r].w);
        }
        float s[RELS];
#pragma unroll
        for (int r = 0; r < RELS; ++r)
            s[r] = h[r][0] * q.x + h[r][1] * q.y + h[r][2] * q.z + h[r][3] * q.w;
#pragma unroll
        for (int off = 1; off < 64; off <<= 1) {
#pragma unroll
            for (int r = 0; r < RELS; ++r) s[r] += __shfl_xor(s[r], off, 64);
        }
        float m = fmaxf(fmaxf(s[0], s[1]), fmaxf(s[2], s[3]));
        float e[RELS];
        float esum = 0.f;
#pragma unroll
        for (int r = 0; r < RELS; ++r) { e[r] = expf((s[r] - m) * itau); esum += e[r]; }
        float inv = 1.0f / esum;
        float a[RELS];
#pragma unroll
        for (int r = 0; r < RELS; ++r) a[r] = e[r] * inv;
        if (lane == 0)
            *(float4*)(alpha_out + (size_t)n * 4) = make_float4(a[0], a[1], a[2], a[3]);

        float w0 = 0.25f + a[0], w1 = 0.25f + a[1], w2 = 0.25f + a[2], w3 = 0.25f + a[3];
        float h2[4];
#pragma unroll
        for (int j = 0; j < 4; ++j)
            h2[j] = w0 * h[0][j] + w1 * h[1][j] + w2 * h[2][j] + w3 * h[3][j];

        f32x4 acc[4];
#pragma unroll
        for (int c4 = 0; c4 < 4; ++c4)
            acc[c4] = h2[0] * Wr[0][c4] + h2[1] * Wr[1][c4]
                    + h2[2] * Wr[2][c4] + h2[3] * Wr[3][c4];

#pragma unroll
        for (int c4 = 0; c4 < 4; ++c4)
#pragma unroll
            for (int i = 0; i < 4; ++i)
                myred[lane * 17 + c4 * 4 + i] = acc[c4][i];
        asm volatile("s_waitcnt lgkmcnt(0)" ::: "memory");
        float t = 0.f;
#pragma unroll
        for (int k = 0; k < 16; ++k) t += myred[(rb + k) * 17 + cls];
        t += __shfl_xor(t, 16, 64);
        t += __shfl_xor(t, 32, 64);
        if (lane < 16) logits[(size_t)n * NCLS + lane] = t + bc;
        asm volatile("" ::: "memory");

#pragma unroll
        for (int r = 0; r < RELS; ++r) u[r] = un[r];
        n = nn;
    }
}

// ---------------- launcher ----------------

static inline int cdiv(int a, int b) { return (a + b - 1) / b; }

extern "C" void kernel_launch(void* const* d_in, const int* in_sizes, int n_in,
                              void* d_out, int out_size, void* d_ws, size_t ws_size,
                              hipStream_t stream) {
    const float* X     = (const float*)d_in[0];
    const int*   edges = (const int*)d_in[1];
    const float* W1    = (const float*)d_in[2];
    const float* W2    = (const float*)d_in[3];
    const float* att_q = (const float*)d_in[4];
    const float* tau   = (const float*)d_in[5];
    const float* W_out = (const float*)d_in[6];
    const float* b_out = (const float*)d_in[7];

    float* logits = (float*)d_out;
    float* alpha  = logits + (size_t)NODES * NCLS;

    char* p = (char*)d_ws;
    auto carve = [&](size_t bytes) -> char* {
        char* q = p;
        p += (bytes + 255) & ~(size_t)255;
        return q;
    };
    float* dinv_row = (float*)carve((size_t)RELS * NODES * 4);
    float* dinv_col = (float*)carve((size_t)RELS * NODES * 4);
    int*   row_ptr  = (int*)carve((size_t)RELS * RPS * 4 + 256);
    int*   csr_col  = (int*)carve((size_t)RELS * EDGES * 4);     // also H2_3 output (exactly 50000*256*2 B)
    unsigned short* Xbf  = (unsigned short*)carve((size_t)NODES * FEAT * 2);  // also H2_1 output
    unsigned short* h1bf = (unsigned short*)carve((size_t)NODES * FEAT * 2);  // also H2_2 output
    unsigned short* W1t  = (unsigned short*)carve((size_t)RELS * FEAT * FEAT * 2);
    unsigned short* W2t  = (unsigned short*)carve((size_t)RELS * FEAT * FEAT * 2);
    // BIG region: 5 slices of MPAD*FEAT bf16, phase-aliased:
    //   CSR phase:  ebuf packed uint (25.6M) | cbuf (25.6M) | partR/offR/partC/offC (~3.2M) | bbR/bbC
    //   layer 1:    spmm -> S0..S3 (slice_off=0); gemm1 reads S0..S3 -> h1bf
    //   layer 2:    spmm -> S1..S4 (slice_off=1); gemm2z reads S1..S4 -> {S0, Xbf, h1bf, csr_col}
    const size_t AGGSE = (size_t)MPAD * FEAT;        // elements per slice
    char* BIG = carve(5 * AGGSE * 2);
    unsigned* ebuf = (unsigned*)BIG;
    int*      cbuf = (int*)(BIG + (size_t)RELS * EDGES * 4);
    char*     q = BIG + (size_t)RELS * EDGES * 8;
    unsigned* partR = (unsigned*)q;               q += (size_t)RELS * NCHUNK * NB * 4;
    unsigned* offR  = (unsigned*)q;               q += (size_t)RELS * NCHUNK * NB * 4;
    unsigned* partC = (unsigned*)q;               q += (size_t)RELS * NCHUNK * NB * 4;
    unsigned* offC  = (unsigned*)q;               q += (size_t)RELS * NCHUNK * NB * 4;
    unsigned* bbR   = (unsigned*)q;               q += (size_t)RELS * (NB + 1) * 4;
    unsigned* bbC   = (unsigned*)q;
    unsigned short* aggbf = (unsigned short*)BIG;
    // H2 destinations (all dead buffers at gemm2z time, disjoint from its inputs S1..S4)
    unsigned short* H2_0 = aggbf;                        // S0
    unsigned short* H2_1 = Xbf;
    unsigned short* H2_2 = h1bf;
    unsigned short* H2_3 = (unsigned short*)csr_col;     // 25,600,000 B == 50000*256*2

    // CSR build: 6 launches (was 12) — bucket sort with fused per-bucket CSR fill
    {
        dim3 hg(NCHUNK, RELS);
        dim3 bg(NB, RELS);
        k_bhist2<<<hg, 256, 0, stream>>>(edges, partR, partC);
        k_bscan<<<RELS, 256, 0, stream>>>(partR, offR, bbR);
        k_bscan<<<RELS, 256, 0, stream>>>(partC, offC, bbC);
        k_scat2<<<hg, 256, 0, stream>>>(edges, offR, offC, ebuf, cbuf);
        k_countC<<<bg, 256, 0, stream>>>(cbuf, bbC, dinv_col);
        k_place2<<<bg, 256, 0, stream>>>(ebuf, bbR, csr_col, row_ptr, dinv_row);
    }

    // conversions
    k_wt2<<<cdiv(2 * RELS * FEAT * FEAT, 256), 256, 0, stream>>>(W1, W2, W1t, W2t);
    k_f2bf8<<<cdiv(NODES * FEAT / 8, 256), 256, 0, stream>>>(X, Xbf, NODES * FEAT / 8);

    dim3 gemm_grid(MPAD / 128, FEAT / 128);
    dim3 gemm2_grid(MPAD / 128, FEAT / 128, RELS);
    dim3 spmm_grid(cdiv(NODES * 64, 256), RELS);

    // Layer 1: one fused SPMM (4 rels) into S0..S3, then fused GEMM -> h1bf
    k_spmm<<<spmm_grid, 256, 0, stream>>>(Xbf, row_ptr, csr_col, dinv_row, dinv_col,
                                          aggbf, 0);
    k_gemm1<<<gemm_grid, 256, 0, stream>>>(aggbf, W1t, h1bf);

    // Layer 2: one fused SPMM (4 rels) into S1..S4, then ONE fused GEMM (grid.z=rel)
    k_spmm<<<spmm_grid, 256, 0, stream>>>(h1bf, row_ptr, csr_col, dinv_row, dinv_col,
                                          aggbf, 1);
    k_gemm2z<<<gemm2_grid, 256, 0, stream>>>(aggbf, W2t, H2_0, H2_1, H2_2, H2_3);

    // fused attention + output (single pass over H2)
    k_attn_out<<<1024, 256, 0, stream>>>(H2_0, H2_1, H2_2, H2_3, att_q, tau,
                                         W_out, b_out, alpha, logits);
}

// Round 8
// 1379.001 us; speedup vs baseline: 1.6615x; 1.0424x over previous
//
#include <hip/hip_runtime.h>
#include <hip/hip_bf16.h>
#include <stdint.h>

#define NODES 50000
#define RELS  4
#define EDGES 1600000
#define FEAT  256
#define NCLS  16
#define MPAD  50048                 // 391 * 128
#define RPS   50016                 // row_ptr per-relation stride
#define NCHUNK 64                   // edge chunks per relation
#define CHUNKE 25000                // EDGES / NCHUNK
#define NB     782                  // node buckets of 64 rows (781*64+16)

typedef __attribute__((ext_vector_type(8))) short short8;
typedef __attribute__((ext_vector_type(8))) unsigned short u16x8;
typedef __attribute__((ext_vector_type(4))) float f32x4;

static __device__ __forceinline__ float bf2f(unsigned short u) {
    return __uint_as_float(((unsigned int)u) << 16);
}
static __device__ __forceinline__ unsigned short f2bf(float f) {
    unsigned int x = __float_as_uint(f);
    unsigned int r = x + 0x7fffu + ((x >> 16) & 1u);
    return (unsigned short)(r >> 16);
}

// ============ CSR build: bucket radix sort, zero global atomics ============
// Bucket b's edges occupy exactly csr positions [bbR[b], bbR[b+1]) after the
// row-bucket scatter -> per-bucket count+scan+scatter reconstructs the CSR.

// one edge read pass -> BOTH row and col histograms (value>>6)
__global__ __launch_bounds__(256)
void k_bhist2(const int* __restrict__ edges, unsigned* __restrict__ partR,
              unsigned* __restrict__ partC) {
    int chunk = blockIdx.x, rel = blockIdx.y, t = threadIdx.x;
    const int* rows = edges + (size_t)rel * 2 * EDGES + (size_t)chunk * CHUNKE;
    const int* cols = rows + EDGES;
    __shared__ unsigned hR[NB];
    __shared__ unsigned hC[NB];
    for (int i = t; i < NB; i += 256) { hR[i] = 0; hC[i] = 0; }
    __syncthreads();
    for (int e = t; e < CHUNKE; e += 256) {
        atomicAdd(&hR[((unsigned)rows[e]) >> 6], 1u);
        atomicAdd(&hC[((unsigned)cols[e]) >> 6], 1u);
    }
    __syncthreads();
    unsigned* pR = partR + ((size_t)rel * NCHUNK + chunk) * NB;
    unsigned* pC = partC + ((size_t)rel * NCHUNK + chunk) * NB;
    for (int i = t; i < NB; i += 256) { pR[i] = hR[i]; pC[i] = hC[i]; }
}

// both sides in one launch: blockIdx.x in [0,4) -> row side, [4,8) -> col side
__global__ __launch_bounds__(256)
void k_bscan(const unsigned* __restrict__ partR, unsigned* __restrict__ offR,
             unsigned* __restrict__ bbR, const unsigned* __restrict__ partC,
             unsigned* __restrict__ offC, unsigned* __restrict__ bbC) {
    int rel = blockIdx.x & 3, t = threadIdx.x;
    const unsigned* part = (blockIdx.x < 4) ? partR : partC;
    unsigned* off   = (blockIdx.x < 4) ? offR : offC;
    unsigned* bbase = (blockIdx.x < 4) ? bbR  : bbC;
    const int BPT = 4;                       // 256*4 >= NB
    int b0 = t * BPT;
    unsigned s = 0;
#pragma unroll
    for (int j = 0; j < BPT; ++j) {
        int b = b0 + j;
        unsigned x = 0;
        if (b < NB)
            for (int c = 0; c < NCHUNK; ++c)
                x += part[((size_t)rel * NCHUNK + c) * NB + b];
        s += x;
    }
    __shared__ unsigned sh[256];
    sh[t] = s;
    __syncthreads();
    for (int o = 1; o < 256; o <<= 1) {
        unsigned u = (t >= o) ? sh[t - o] : 0;
        __syncthreads();
        sh[t] += u;
        __syncthreads();
    }
    unsigned base = sh[t] - s;
#pragma unroll
    for (int j = 0; j < BPT; ++j) {
        int b = b0 + j;
        if (b < NB) {
            bbase[rel * (NB + 1) + b] = base;
            unsigned acc = base;
            for (int c = 0; c < NCHUNK; ++c) {
                size_t o2 = ((size_t)rel * NCHUNK + c) * NB + b;
                off[o2] = acc;
                acc += part[o2];
            }
            base = acc;
        }
    }
    if (t == 255) bbase[rel * (NB + 1) + NB] = sh[255];
}

// one edge read pass -> scatter PACKED (row&63,col) (row-bucketed, 4B/edge)
// AND col&63 as BYTES (col-bucketed, 1B/edge — only the low 6 bits are needed).
__global__ __launch_bounds__(256)
void k_scat2(const int* __restrict__ edges, const unsigned* __restrict__ offR,
             const unsigned* __restrict__ offC, unsigned* __restrict__ ebuf,
             unsigned char* __restrict__ cbuf) {
    int chunk = blockIdx.x, rel = blockIdx.y, t = threadIdx.x;
    const int* rows = edges + (size_t)rel * 2 * EDGES + (size_t)chunk * CHUNKE;
    const int* cols = rows + EDGES;
    __shared__ unsigned curR[NB];
    __shared__ unsigned curC[NB];
    const unsigned* pR = offR + ((size_t)rel * NCHUNK + chunk) * NB;
    const unsigned* pC = offC + ((size_t)rel * NCHUNK + chunk) * NB;
    for (int i = t; i < NB; i += 256) { curR[i] = pR[i]; curC[i] = pC[i]; }
    __syncthreads();
    unsigned*      eb = ebuf + (size_t)rel * EDGES;
    unsigned char* cb = cbuf + (size_t)rel * EDGES;
    for (int e = t; e < CHUNKE; e += 256) {
        int r = rows[e], c = cols[e];
        unsigned pr = atomicAdd(&curR[((unsigned)r) >> 6], 1u);
        eb[pr] = (((unsigned)(r & 63)) << 16) | (unsigned)c;
        unsigned pc = atomicAdd(&curC[((unsigned)c) >> 6], 1u);
        cb[pc] = (unsigned char)(c & 63);
    }
}

// fused per-bucket finish: col-degree count (from byte cbuf) -> dinv_col,
// AND row count + 64-lane scan + CSR scatter -> csr_col, row_ptr, dinv_row.
__global__ __launch_bounds__(256)
void k_finish(const unsigned* __restrict__ ebuf, const unsigned char* __restrict__ cbuf,
              const unsigned* __restrict__ bbR, const unsigned* __restrict__ bbC,
              int* __restrict__ csr_col, int* __restrict__ row_ptr,
              float* __restrict__ dinv_row, float* __restrict__ dinv_col) {
    int b = blockIdx.x, rel = blockIdx.y, t = threadIdx.x;
    unsigned sR = bbR[rel * (NB + 1) + b], eR = bbR[rel * (NB + 1) + b + 1];
    unsigned sC = bbC[rel * (NB + 1) + b], eC = bbC[rel * (NB + 1) + b + 1];
    __shared__ unsigned rcnt[64];
    __shared__ unsigned ccnt[64];
    __shared__ int cur[64];
    if (t < 64) { rcnt[t] = 0; ccnt[t] = 0; }
    __syncthreads();
    const unsigned*      eb = ebuf + (size_t)rel * EDGES;
    const unsigned char* cb = cbuf + (size_t)rel * EDGES;
    for (unsigned i = sR + t; i < eR; i += 256) atomicAdd(&rcnt[eb[i] >> 16], 1u);
    for (unsigned i = sC + t; i < eC; i += 256) atomicAdd(&ccnt[cb[i]], 1u);
    __syncthreads();
    int base = b * 64;
    if (t < 64) {                     // wave 0 only: 64-lane inclusive shfl scan
        unsigned c = rcnt[t];
        unsigned v = c;
#pragma unroll
        for (int off = 1; off < 64; off <<= 1) {
            unsigned n = __shfl_up(v, off, 64);
            if (t >= off) v += n;
        }
        unsigned excl = v - c;
        cur[t] = (int)(sR + excl);
        if (base + t < NODES) {
            row_ptr[rel * RPS + base + t] = (int)(sR + excl);
            int d = (int)c; if (d < 1) d = 1;
            dinv_row[(size_t)rel * NODES + base + t] = rsqrtf((float)d);
        }
        if (b == 0 && t == 0) row_ptr[rel * RPS + NODES] = EDGES;
    } else if (t >= 64 && t < 128) {
        int tt = t - 64;
        if (base + tt < NODES) {
            int d = (int)ccnt[tt]; if (d < 1) d = 1;
            dinv_col[(size_t)rel * NODES + base + tt] = rsqrtf((float)d);
        }
    }
    __syncthreads();
    int* cc = csr_col + (size_t)rel * EDGES;
    for (unsigned i = sR + t; i < eR; i += 256) {   // bucket range re-read: L2-warm
        unsigned v = eb[i];
        int pos = atomicAdd(&cur[v >> 16], 1);
        cc[pos] = (int)(v & 0xFFFFu);
    }
}

// ---------------- conversions (one launch: weights + X) ----------------

#define WELEMS (2 * RELS * FEAT * FEAT)          // 524288 weight elements
#define XGROUPS (NODES * FEAT / 8)               // 1.6M groups of 8 floats

__global__ __launch_bounds__(256)
void k_conv(const float* __restrict__ W1, const float* __restrict__ W2,
            unsigned short* __restrict__ W1t, unsigned short* __restrict__ W2t,
            const float* __restrict__ X, unsigned short* __restrict__ Xbf) {
    int gid = blockIdx.x * 256 + threadIdx.x;
    if (gid < WELEMS) {
        const int half = RELS * FEAT * FEAT;
        const float* W = (gid < half) ? W1 : W2;
        unsigned short* Wt = (gid < half) ? W1t : W2t;
        int id = (gid < half) ? gid : gid - half;
        int r = id >> 16;
        int rem = id & 65535;
        int n = rem >> 8;
        int k = rem & 255;
        Wt[id] = f2bf(W[(size_t)r * FEAT * FEAT + (size_t)k * FEAT + n]);
        return;
    }
    int i = gid - WELEMS;
    if (i >= XGROUPS) return;
    const float* s = X + (size_t)i * 8;
    float4 a = *(const float4*)s;
    float4 b = *(const float4*)(s + 4);
    u16x8 v;
    v[0] = f2bf(a.x); v[1] = f2bf(a.y); v[2] = f2bf(a.z); v[3] = f2bf(a.w);
    v[4] = f2bf(b.x); v[5] = f2bf(b.y); v[6] = f2bf(b.z); v[7] = f2bf(b.w);
    *(u16x8*)(Xbf + (size_t)i * 8) = v;
}

// ---------------- SPMM: wave per row, all 4 relations fused (grid.y = rel) ----------------
// Proven body (stable at ~390 us, beyond-L2 BW ceiling): half-wave interleave,
// 2 edges in flight per half. slice_off selects target agg slice: rel + slice_off.

__global__ __launch_bounds__(256)
void k_spmm(const unsigned short* __restrict__ feat, const int* __restrict__ row_ptr,
            const int* __restrict__ csr_col, const float* __restrict__ dinv_row,
            const float* __restrict__ dinv_col, unsigned short* __restrict__ aggbase,
            int slice_off) {
    int rel = blockIdx.y;
    unsigned short* aggbf = aggbase + (size_t)(rel + slice_off) * (size_t)MPAD * FEAT;
    int wave = (blockIdx.x * blockDim.x + threadIdx.x) >> 6;
    int lane = threadIdx.x & 63;
    if (wave >= NODES) return;
    int row = wave;
    int half = lane >> 5;
    int l32  = lane & 31;
    int start = row_ptr[rel * RPS + row];
    int end   = row_ptr[rel * RPS + row + 1];
    const int* cols = csr_col + (size_t)rel * EDGES;
    const float* dc = dinv_col + rel * NODES;
    const unsigned short* fb = feat + l32 * 8;
    float acc[8] = {0.f, 0.f, 0.f, 0.f, 0.f, 0.f, 0.f, 0.f};
    int j = start + half;
    for (; j + 2 < end; j += 4) {
        int c0 = cols[j];
        int c1 = cols[j + 2];
        float w0 = dc[c0];
        float w1 = dc[c1];
        u16x8 u0 = *(const u16x8*)(fb + (size_t)c0 * FEAT);
        u16x8 u1 = *(const u16x8*)(fb + (size_t)c1 * FEAT);
#pragma unroll
        for (int i = 0; i < 8; ++i) acc[i] += w0 * bf2f(u0[i]);
#pragma unroll
        for (int i = 0; i < 8; ++i) acc[i] += w1 * bf2f(u1[i]);
    }
    if (j < end) {
        int c0 = cols[j];
        float w0 = dc[c0];
        u16x8 u0 = *(const u16x8*)(fb + (size_t)c0 * FEAT);
#pragma unroll
        for (int i = 0; i < 8; ++i) acc[i] += w0 * bf2f(u0[i]);
    }
#pragma unroll
    for (int i = 0; i < 8; ++i) acc[i] += __shfl_down(acc[i], 32, 64);
    if (half == 0) {
        float dr = dinv_row[rel * NODES + row];
        u16x8 o;
#pragma unroll
        for (int i = 0; i < 8; ++i) o[i] = f2bf(acc[i] * dr);
        *(u16x8*)(aggbf + (size_t)row * FEAT + l32 * 8) = o;
    }
}

// ---------------- MFMA GEMM (128x128 tile, BK=64, XOR-swizzled LDS) ----------------
// C/D layout: col = lane&15, row = quad*4 + reg.

__global__ __launch_bounds__(256)
void k_gemm1(const unsigned short* __restrict__ Abase, const unsigned short* __restrict__ Wt,
             unsigned short* __restrict__ h1bf) {
    __shared__ __align__(16) unsigned short As[128 * 64];
    __shared__ __align__(16) unsigned short Bs[128 * 64];
    int tid = threadIdx.x;
    int wave = tid >> 6, lane = tid & 63;
    int quad = lane >> 4, l16 = lane & 15;
    int wm = (wave & 1) * 64, wn = (wave >> 1) * 64;
    int row0 = blockIdx.x * 128, n0 = blockIdx.y * 128;

    f32x4 hacc[4][4];
#pragma unroll
    for (int mi = 0; mi < 4; ++mi)
#pragma unroll
        for (int ni = 0; ni < 4; ++ni)
            hacc[mi][ni] = (f32x4){0.f, 0.f, 0.f, 0.f};

    for (int r = 0; r < RELS; ++r) {
        const unsigned short* A  = Abase + (size_t)r * MPAD * FEAT;
        const unsigned short* Bt = Wt + (size_t)r * FEAT * FEAT;
        f32x4 acc[4][4];
#pragma unroll
        for (int mi = 0; mi < 4; ++mi)
#pragma unroll
            for (int ni = 0; ni < 4; ++ni)
                acc[mi][ni] = (f32x4){0.f, 0.f, 0.f, 0.f};

        for (int k0 = 0; k0 < FEAT; k0 += 64) {
#pragma unroll
            for (int issue = 0; issue < 4; ++issue) {
                int flat = issue * 256 + tid;
                int row = flat >> 3;
                int gr = flat & 7;
                int sg = gr ^ (row & 7);
                *(uint4*)&As[flat * 8] = *(const uint4*)(A + (size_t)(row0 + row) * FEAT + k0 + sg * 8);
                *(uint4*)&Bs[flat * 8] = *(const uint4*)(Bt + (size_t)(n0 + row) * FEAT + k0 + sg * 8);
            }
            __syncthreads();
#pragma unroll
            for (int ks = 0; ks < 2; ++ks) {
                int g = ks * 4 + quad;
                short8 af[4], bfr[4];
#pragma unroll
                for (int mi = 0; mi < 4; ++mi) {
                    int m = wm + mi * 16 + l16;
                    af[mi] = *(const short8*)&As[m * 64 + ((g ^ (m & 7)) << 3)];
                }
#pragma unroll
                for (int ni = 0; ni < 4; ++ni) {
                    int n = wn + ni * 16 + l16;
                    bfr[ni] = *(const short8*)&Bs[n * 64 + ((g ^ (n & 7)) << 3)];
                }
#pragma unroll
                for (int mi = 0; mi < 4; ++mi)
#pragma unroll
                    for (int ni = 0; ni < 4; ++ni)
                        acc[mi][ni] = __builtin_amdgcn_mfma_f32_16x16x32_bf16(af[mi], bfr[ni], acc[mi][ni], 0, 0, 0);
            }
            __syncthreads();
        }
#pragma unroll
        for (int mi = 0; mi < 4; ++mi)
#pragma unroll
            for (int ni = 0; ni < 4; ++ni)
#pragma unroll
                for (int i = 0; i < 4; ++i) {
                    float v = acc[mi][ni][i];
                    hacc[mi][ni][i] += 0.25f * (v > 0.f ? v : 0.f);
                }
    }

#pragma unroll
    for (int mi = 0; mi < 4; ++mi)
#pragma unroll
        for (int ni = 0; ni < 4; ++ni) {
            int col = n0 + wn + ni * 16 + l16;
#pragma unroll
            for (int i = 0; i < 4; ++i) {
                int row = row0 + wm + mi * 16 + quad * 4 + i;
                if (row < NODES) h1bf[(size_t)row * FEAT + col] = f2bf(hacc[mi][ni][i]);
            }
        }
}

// fused layer-2 GEMM: grid.z = rel; reads S_{r+1}, writes 4 disjoint dead buffers
__global__ __launch_bounds__(256)
void k_gemm2z(const unsigned short* __restrict__ aggbase, const unsigned short* __restrict__ Wtb,
              unsigned short* __restrict__ o0, unsigned short* __restrict__ o1,
              unsigned short* __restrict__ o2, unsigned short* __restrict__ o3) {
    __shared__ __align__(16) unsigned short As[128 * 64];
    __shared__ __align__(16) unsigned short Bs[128 * 64];
    int rz = blockIdx.z;
    const unsigned short* A  = aggbase + (size_t)(rz + 1) * MPAD * FEAT;
    const unsigned short* Bt = Wtb + (size_t)rz * FEAT * FEAT;
    unsigned short* H2 = (rz == 0) ? o0 : (rz == 1) ? o1 : (rz == 2) ? o2 : o3;

    int tid = threadIdx.x;
    int wave = tid >> 6, lane = tid & 63;
    int quad = lane >> 4, l16 = lane & 15;
    int wm = (wave & 1) * 64, wn = (wave >> 1) * 64;
    int row0 = blockIdx.x * 128, n0 = blockIdx.y * 128;

    f32x4 acc[4][4];
#pragma unroll
    for (int mi = 0; mi < 4; ++mi)
#pragma unroll
        for (int ni = 0; ni < 4; ++ni)
            acc[mi][ni] = (f32x4){0.f, 0.f, 0.f, 0.f};

    for (int k0 = 0; k0 < FEAT; k0 += 64) {
#pragma unroll
        for (int issue = 0; issue < 4; ++issue) {
            int flat = issue * 256 + tid;
            int row = flat >> 3;
            int gr = flat & 7;
            int sg = gr ^ (row & 7);
            *(uint4*)&As[flat * 8] = *(const uint4*)(A + (size_t)(row0 + row) * FEAT + k0 + sg * 8);
            *(uint4*)&Bs[flat * 8] = *(const uint4*)(Bt + (size_t)(n0 + row) * FEAT + k0 + sg * 8);
        }
        __syncthreads();
#pragma unroll
        for (int ks = 0; ks < 2; ++ks) {
            int g = ks * 4 + quad;
            short8 af[4], bfr[4];
#pragma unroll
            for (int mi = 0; mi < 4; ++mi) {
                int m = wm + mi * 16 + l16;
                af[mi] = *(const short8*)&As[m * 64 + ((g ^ (m & 7)) << 3)];
            }
#pragma unroll
            for (int ni = 0; ni < 4; ++ni) {
                int n = wn + ni * 16 + l16;
                bfr[ni] = *(const short8*)&Bs[n * 64 + ((g ^ (n & 7)) << 3)];
            }
#pragma unroll
            for (int mi = 0; mi < 4; ++mi)
#pragma unroll
                for (int ni = 0; ni < 4; ++ni)
                    acc[mi][ni] = __builtin_amdgcn_mfma_f32_16x16x32_bf16(af[mi], bfr[ni], acc[mi][ni], 0, 0, 0);
        }
        __syncthreads();
    }

#pragma unroll
    for (int mi = 0; mi < 4; ++mi)
#pragma unroll
        for (int ni = 0; ni < 4; ++ni) {
            int col = n0 + wn + ni * 16 + l16;
#pragma unroll
            for (int i = 0; i < 4; ++i) {
                int row = row0 + wm + mi * 16 + quad * 4 + i;
                if (row < NODES) {
                    float v = acc[mi][ni][i];
                    H2[(size_t)row * FEAT + col] = f2bf(v > 0.f ? v : 0.f);
                }
            }
        }
}

// ---------------- fused attention scores + softmax + combine + output GEMV ----------------
// H2 slices passed as 4 explicit pointers (disjoint buffers).

__global__ __launch_bounds__(256)
void k_attn_out(const unsigned short* __restrict__ p0, const unsigned short* __restrict__ p1,
                const unsigned short* __restrict__ p2, const unsigned short* __restrict__ p3,
                const float* __restrict__ att_q, const float* __restrict__ tau_p,
                const float* __restrict__ W_out, const float* __restrict__ b_out,
                float* __restrict__ alpha_out, float* __restrict__ logits) {
    __shared__ float red[4][64 * 17];
    int tid = threadIdx.x;
    int wid = tid >> 6;
    int lane = tid & 63;
    int gwave = blockIdx.x * 4 + wid;
    int nwaves = gridDim.x * 4;

    const unsigned short* hp[RELS] = {p0, p1, p2, p3};
    float4 q = *(const float4*)(att_q + lane * 4);
    float tau = fminf(fmaxf(tau_p[0], 0.5f), 5.0f);
    float itau = 1.0f / tau;
    f32x4 Wr[4][4];
#pragma unroll
    for (int j = 0; j < 4; ++j)
#pragma unroll
        for (int c4 = 0; c4 < 4; ++c4) {
            float4 w = *(const float4*)(W_out + (size_t)(lane * 4 + j) * NCLS + c4 * 4);
            Wr[j][c4] = (f32x4){w.x, w.y, w.z, w.w};
        }
    float bc = b_out[lane & 15];
    float* myred = &red[wid][0];
    int cls = lane & 15;
    int rb = (lane >> 4) * 16;

    int n = gwave;
    if (n >= NODES) return;
    ushort4 u[RELS];
#pragma unroll
    for (int r = 0; r < RELS; ++r)
        u[r] = *(const ushort4*)(hp[r] + (size_t)n * FEAT + lane * 4);

    while (n < NODES) {
        int nn = n + nwaves;
        int nc = (nn < NODES) ? nn : n;
        ushort4 un[RELS];
#pragma unroll
        for (int r = 0; r < RELS; ++r)
            un[r] = *(const ushort4*)(hp[r] + (size_t)nc * FEAT + lane * 4);

        float h[RELS][4];
#pragma unroll
        for (int r = 0; r < RELS; ++r) {
            h[r][0] = bf2f(u[r].x); h[r][1] = bf2f(u[r].y);
            h[r][2] = bf2f(u[r].z); h[r][3] = bf2f(u[r].w);
        }
        float s[RELS];
#pragma unroll
        for (int r = 0; r < RELS; ++r)
            s[r] = h[r][0] * q.x + h[r][1] * q.y + h[r][2] * q.z + h[r][3] * q.w;
#pragma unroll
        for (int off = 1; off < 64; off <<= 1) {
#pragma unroll
            for (int r = 0; r < RELS; ++r) s[r] += __shfl_xor(s[r], off, 64);
        }
        float m = fmaxf(fmaxf(s[0], s[1]), fmaxf(s[2], s[3]));
        float e[RELS];
        float esum = 0.f;
#pragma unroll
        for (int r = 0; r < RELS; ++r) { e[r] = expf((s[r] - m) * itau); esum += e[r]; }
        float inv = 1.0f / esum;
        float a[RELS];
#pragma unroll
        for (int r = 0; r < RELS; ++r) a[r] = e[r] * inv;
        if (lane == 0)
            *(float4*)(alpha_out + (size_t)n * 4) = make_float4(a[0], a[1], a[2], a[3]);

        float w0 = 0.25f + a[0], w1 = 0.25f + a[1], w2 = 0.25f + a[2], w3 = 0.25f + a[3];
        float h2[4];
#pragma unroll
        for (int j = 0; j < 4; ++j)
            h2[j] = w0 * h[0][j] + w1 * h[1][j] + w2 * h[2][j] + w3 * h[3][j];

        f32x4 acc[4];
#pragma unroll
        for (int c4 = 0; c4 < 4; ++c4)
            acc[c4] = h2[0] * Wr[0][c4] + h2[1] * Wr[1][c4]
                    + h2[2] * Wr[2][c4] + h2[3] * Wr[3][c4];

#pragma unroll
        for (int c4 = 0; c4 < 4; ++c4)
#pragma unroll
            for (int i = 0; i < 4; ++i)
                myred[lane * 17 + c4 * 4 + i] = acc[c4][i];
        asm volatile("s_waitcnt lgkmcnt(0)" ::: "memory");
        float t = 0.f;
#pragma unroll
        for (int k = 0; k < 16; ++k) t += myred[(rb + k) * 17 + cls];
        t += __shfl_xor(t, 16, 64);
        t += __shfl_xor(t, 32, 64);
        if (lane < 16) logits[(size_t)n * NCLS + lane] = t + bc;
        asm volatile("" ::: "memory");

#pragma unroll
        for (int r = 0; r < RELS; ++r) u[r] = un[r];
        n = nn;
    }
}

// ---------------- launcher ----------------

static inline int cdiv(int a, int b) { return (a + b - 1) / b; }

extern "C" void kernel_launch(void* const* d_in, const int* in_sizes, int n_in,
                              void* d_out, int out_size, void* d_ws, size_t ws_size,
                              hipStream_t stream) {
    const float* X     = (const float*)d_in[0];
    const int*   edges = (const int*)d_in[1];
    const float* W1    = (const float*)d_in[2];
    const float* W2    = (const float*)d_in[3];
    const float* att_q = (const float*)d_in[4];
    const float* tau   = (const float*)d_in[5];
    const float* W_out = (const float*)d_in[6];
    const float* b_out = (const float*)d_in[7];

    float* logits = (float*)d_out;
    float* alpha  = logits + (size_t)NODES * NCLS;

    char* p = (char*)d_ws;
    auto carve = [&](size_t bytes) -> char* {
        char* q = p;
        p += (bytes + 255) & ~(size_t)255;
        return q;
    };
    float* dinv_row = (float*)carve((size_t)RELS * NODES * 4);
    float* dinv_col = (float*)carve((size_t)RELS * NODES * 4);
    int*   row_ptr  = (int*)carve((size_t)RELS * RPS * 4 + 256);
    int*   csr_col  = (int*)carve((size_t)RELS * EDGES * 4);     // also H2_3 output (exactly 50000*256*2 B)
    unsigned short* Xbf  = (unsigned short*)carve((size_t)NODES * FEAT * 2);  // also H2_1 output
    unsigned short* h1bf = (unsigned short*)carve((size_t)NODES * FEAT * 2);  // also H2_2 output
    unsigned short* W1t  = (unsigned short*)carve((size_t)RELS * FEAT * FEAT * 2);
    unsigned short* W2t  = (unsigned short*)carve((size_t)RELS * FEAT * FEAT * 2);
    // BIG region: 5 slices of MPAD*FEAT bf16, phase-aliased:
    //   CSR phase:  ebuf packed uint (25.6M) | cbuf bytes (6.4M) | partR/offR/partC/offC (~3.2M) | bbR/bbC
    //   layer 1:    spmm -> S0..S3 (slice_off=0); gemm1 reads S0..S3 -> h1bf
    //   layer 2:    spmm -> S1..S4 (slice_off=1); gemm2z reads S1..S4 -> {S0, Xbf, h1bf, csr_col}
    const size_t AGGSE = (size_t)MPAD * FEAT;        // elements per slice
    char* BIG = carve(5 * AGGSE * 2);
    unsigned*      ebuf = (unsigned*)BIG;
    unsigned char* cbuf = (unsigned char*)(BIG + (size_t)RELS * EDGES * 4);
    char*     q = BIG + (size_t)RELS * EDGES * 5;
    q = (char*)(((uintptr_t)q + 255) & ~(uintptr_t)255);
    unsigned* partR = (unsigned*)q;               q += (size_t)RELS * NCHUNK * NB * 4;
    unsigned* offR  = (unsigned*)q;               q += (size_t)RELS * NCHUNK * NB * 4;
    unsigned* partC = (unsigned*)q;               q += (size_t)RELS * NCHUNK * NB * 4;
    unsigned* offC  = (unsigned*)q;               q += (size_t)RELS * NCHUNK * NB * 4;
    unsigned* bbR   = (unsigned*)q;               q += (size_t)RELS * (NB + 1) * 4;
    unsigned* bbC   = (unsigned*)q;
    unsigned short* aggbf = (unsigned short*)BIG;
    // H2 destinations (all dead buffers at gemm2z time, disjoint from its inputs S1..S4)
    unsigned short* H2_0 = aggbf;                        // S0
    unsigned short* H2_1 = Xbf;
    unsigned short* H2_2 = h1bf;
    unsigned short* H2_3 = (unsigned short*)csr_col;     // 25,600,000 B == 50000*256*2

    // CSR build: 4 launches — bucket sort with fused per-bucket finish
    {
        dim3 hg(NCHUNK, RELS);
        dim3 bg(NB, RELS);
        k_bhist2<<<hg, 256, 0, stream>>>(edges, partR, partC);
        k_bscan<<<8, 256, 0, stream>>>(partR, offR, bbR, partC, offC, bbC);
        k_scat2<<<hg, 256, 0, stream>>>(edges, offR, offC, ebuf, cbuf);
        k_finish<<<bg, 256, 0, stream>>>(ebuf, cbuf, bbR, bbC, csr_col, row_ptr,
                                         dinv_row, dinv_col);
    }

    // conversions (one launch: W1,W2 transpose + X -> bf16)
    k_conv<<<cdiv(WELEMS + XGROUPS, 256), 256, 0, stream>>>(W1, W2, W1t, W2t, X, Xbf);

    dim3 gemm_grid(MPAD / 128, FEAT / 128);
    dim3 gemm2_grid(MPAD / 128, FEAT / 128, RELS);
    dim3 spmm_grid(cdiv(NODES * 64, 256), RELS);

    // Layer 1: one fused SPMM (4 rels) into S0..S3, then fused GEMM -> h1bf
    k_spmm<<<spmm_grid, 256, 0, stream>>>(Xbf, row_ptr, csr_col, dinv_row, dinv_col,
                                          aggbf, 0);
    k_gemm1<<<gemm_grid, 256, 0, stream>>>(aggbf, W1t, h1bf);

    // Layer 2: one fused SPMM (4 rels) into S1..S4, then ONE fused GEMM (grid.z=rel)
    k_spmm<<<spmm_grid, 256, 0, stream>>>(h1bf, row_ptr, csr_col, dinv_row, dinv_col,
                                          aggbf, 1);
    k_gemm2z<<<gemm2_grid, 256, 0, stream>>>(aggbf, W2t, H2_0, H2_1, H2_2, H2_3);

    // fused attention + output (single pass over H2)
    k_attn_out<<<1024, 256, 0, stream>>>(H2_0, H2_1, H2_2, H2_3, att_q, tau,
                                         W_out, b_out, alpha, logits);
}

// Round 9
// 1356.522 us; speedup vs baseline: 1.6890x; 1.0166x over previous
//
#include <hip/hip_runtime.h>
#include <hip/hip_bf16.h>
#include <stdint.h>

#define NODES 50000
#define RELS  4
#define EDGES 1600000
#define FEAT  256
#define NCLS  16
#define MPAD  50048                 // 391 * 128
#define RPS   50016                 // row_ptr per-relation stride
#define NCHUNK 128                  // edge chunks per relation (2 blocks/CU)
#define CHUNKE 12500                // EDGES / NCHUNK
#define NB     782                  // node buckets of 64 rows (781*64+16)

#define WELEMS (2 * RELS * FEAT * FEAT)          // 524288 weight elements
#define XGROUPS (NODES * FEAT / 8)               // 1.6M groups of 8 floats
#define CONVB  2075                              // ceil((WELEMS+XGROUPS)/256/RELS)

typedef __attribute__((ext_vector_type(8))) short short8;
typedef __attribute__((ext_vector_type(8))) unsigned short u16x8;
typedef __attribute__((ext_vector_type(4))) float f32x4;

static __device__ __forceinline__ float bf2f(unsigned short u) {
    return __uint_as_float(((unsigned int)u) << 16);
}
static __device__ __forceinline__ unsigned short f2bf(float f) {
    unsigned int x = __float_as_uint(f);
    unsigned int r = x + 0x7fffu + ((x >> 16) & 1u);
    return (unsigned short)(r >> 16);
}

// async global->LDS 16B transfer: wave-uniform LDS base + lane*16 (linear dest),
// per-lane global source (carries the XOR pre-swizzle). Layout identical to the
// previous reg-staged path; only the transport changes (no VGPR round-trip).
#define GLOAD_LDS16(gsrc, ldst)                                                          \
    __builtin_amdgcn_global_load_lds(                                                    \
        (const __attribute__((address_space(1))) unsigned int*)(gsrc),                   \
        (__attribute__((address_space(3))) unsigned int*)(ldst), 16, 0, 0)

// ============ CSR build: bucket radix sort, zero global atomics ============
// Bucket b's edges occupy exactly csr positions [bbR[b], bbR[b+1]) after the
// row-bucket scatter -> per-bucket count+scan+scatter reconstructs the CSR.

// blocks [0,NCHUNK): one edge read pass -> BOTH row and col histograms (value>>6)
// blocks [NCHUNK,..): independent conversion work (W1/W2 transpose + X->bf16),
// fused here so its streaming traffic hides under the atomic-bound histogram.
__global__ __launch_bounds__(256)
void k_bhist2(const int* __restrict__ edges, unsigned* __restrict__ partR,
              unsigned* __restrict__ partC,
              const float* __restrict__ W1, const float* __restrict__ W2,
              unsigned short* __restrict__ W1t, unsigned short* __restrict__ W2t,
              const float* __restrict__ X, unsigned short* __restrict__ Xbf) {
    __shared__ unsigned hR[NB];
    __shared__ unsigned hC[NB];
    int t = threadIdx.x;
    if (blockIdx.x >= NCHUNK) {
        // ---- conversion branch ----
        int cid = (blockIdx.x - NCHUNK) * RELS + blockIdx.y;
        int gid = cid * 256 + t;
        if (gid < WELEMS) {
            const int half = RELS * FEAT * FEAT;
            const float* W = (gid < half) ? W1 : W2;
            unsigned short* Wt = (gid < half) ? W1t : W2t;
            int id = (gid < half) ? gid : gid - half;
            int r = id >> 16;
            int rem = id & 65535;
            int n = rem >> 8;
            int k = rem & 255;
            Wt[id] = f2bf(W[(size_t)r * FEAT * FEAT + (size_t)k * FEAT + n]);
            return;
        }
        int i = gid - WELEMS;
        if (i >= XGROUPS) return;
        const float* s = X + (size_t)i * 8;
        float4 a = *(const float4*)s;
        float4 b = *(const float4*)(s + 4);
        u16x8 v;
        v[0] = f2bf(a.x); v[1] = f2bf(a.y); v[2] = f2bf(a.z); v[3] = f2bf(a.w);
        v[4] = f2bf(b.x); v[5] = f2bf(b.y); v[6] = f2bf(b.z); v[7] = f2bf(b.w);
        *(u16x8*)(Xbf + (size_t)i * 8) = v;
        return;
    }
    // ---- histogram branch ----
    int chunk = blockIdx.x, rel = blockIdx.y;
    const int* rows = edges + (size_t)rel * 2 * EDGES + (size_t)chunk * CHUNKE;
    const int* cols = rows + EDGES;
    for (int i = t; i < NB; i += 256) { hR[i] = 0; hC[i] = 0; }
    __syncthreads();
    for (int e = t; e < CHUNKE; e += 256) {
        atomicAdd(&hR[((unsigned)rows[e]) >> 6], 1u);
        atomicAdd(&hC[((unsigned)cols[e]) >> 6], 1u);
    }
    __syncthreads();
    unsigned* pR = partR + ((size_t)rel * NCHUNK + chunk) * NB;
    unsigned* pC = partC + ((size_t)rel * NCHUNK + chunk) * NB;
    for (int i = t; i < NB; i += 256) { pR[i] = hR[i]; pC[i] = hC[i]; }
}

// both sides in one launch: blockIdx.x in [0,4) -> row side, [4,8) -> col side
__global__ __launch_bounds__(256)
void k_bscan(const unsigned* __restrict__ partR, unsigned* __restrict__ offR,
             unsigned* __restrict__ bbR, const unsigned* __restrict__ partC,
             unsigned* __restrict__ offC, unsigned* __restrict__ bbC) {
    int rel = blockIdx.x & 3, t = threadIdx.x;
    const unsigned* part = (blockIdx.x < 4) ? partR : partC;
    unsigned* off   = (blockIdx.x < 4) ? offR : offC;
    unsigned* bbase = (blockIdx.x < 4) ? bbR  : bbC;
    const int BPT = 4;                       // 256*4 >= NB
    int b0 = t * BPT;
    unsigned s = 0;
#pragma unroll
    for (int j = 0; j < BPT; ++j) {
        int b = b0 + j;
        unsigned x = 0;
        if (b < NB)
            for (int c = 0; c < NCHUNK; ++c)
                x += part[((size_t)rel * NCHUNK + c) * NB + b];
        s += x;
    }
    __shared__ unsigned sh[256];
    sh[t] = s;
    __syncthreads();
    for (int o = 1; o < 256; o <<= 1) {
        unsigned u = (t >= o) ? sh[t - o] : 0;
        __syncthreads();
        sh[t] += u;
        __syncthreads();
    }
    unsigned base = sh[t] - s;
#pragma unroll
    for (int j = 0; j < BPT; ++j) {
        int b = b0 + j;
        if (b < NB) {
            bbase[rel * (NB + 1) + b] = base;
            unsigned acc = base;
            for (int c = 0; c < NCHUNK; ++c) {
                size_t o2 = ((size_t)rel * NCHUNK + c) * NB + b;
                off[o2] = acc;
                acc += part[o2];
            }
            base = acc;
        }
    }
    if (t == 255) bbase[rel * (NB + 1) + NB] = sh[255];
}

// one edge read pass -> scatter PACKED (row&63,col) (row-bucketed, 4B/edge)
// AND col&63 as BYTES (col-bucketed, 1B/edge — only the low 6 bits are needed).
__global__ __launch_bounds__(256)
void k_scat2(const int* __restrict__ edges, const unsigned* __restrict__ offR,
             const unsigned* __restrict__ offC, unsigned* __restrict__ ebuf,
             unsigned char* __restrict__ cbuf) {
    int chunk = blockIdx.x, rel = blockIdx.y, t = threadIdx.x;
    const int* rows = edges + (size_t)rel * 2 * EDGES + (size_t)chunk * CHUNKE;
    const int* cols = rows + EDGES;
    __shared__ unsigned curR[NB];
    __shared__ unsigned curC[NB];
    const unsigned* pR = offR + ((size_t)rel * NCHUNK + chunk) * NB;
    const unsigned* pC = offC + ((size_t)rel * NCHUNK + chunk) * NB;
    for (int i = t; i < NB; i += 256) { curR[i] = pR[i]; curC[i] = pC[i]; }
    __syncthreads();
    unsigned*      eb = ebuf + (size_t)rel * EDGES;
    unsigned char* cb = cbuf + (size_t)rel * EDGES;
    for (int e = t; e < CHUNKE; e += 256) {
        int r = rows[e], c = cols[e];
        unsigned pr = atomicAdd(&curR[((unsigned)r) >> 6], 1u);
        eb[pr] = (((unsigned)(r & 63)) << 16) | (unsigned)c;
        unsigned pc = atomicAdd(&curC[((unsigned)c) >> 6], 1u);
        cb[pc] = (unsigned char)(c & 63);
    }
}

// fused per-bucket finish: col-degree count (from byte cbuf) -> dinv_col,
// AND row count + 64-lane scan + CSR scatter -> csr_col, row_ptr, dinv_row.
__global__ __launch_bounds__(256)
void k_finish(const unsigned* __restrict__ ebuf, const unsigned char* __restrict__ cbuf,
              const unsigned* __restrict__ bbR, const unsigned* __restrict__ bbC,
              int* __restrict__ csr_col, int* __restrict__ row_ptr,
              float* __restrict__ dinv_row, float* __restrict__ dinv_col) {
    int b = blockIdx.x, rel = blockIdx.y, t = threadIdx.x;
    unsigned sR = bbR[rel * (NB + 1) + b], eR = bbR[rel * (NB + 1) + b + 1];
    unsigned sC = bbC[rel * (NB + 1) + b], eC = bbC[rel * (NB + 1) + b + 1];
    __shared__ unsigned rcnt[64];
    __shared__ unsigned ccnt[64];
    __shared__ int cur[64];
    if (t < 64) { rcnt[t] = 0; ccnt[t] = 0; }
    __syncthreads();
    const unsigned*      eb = ebuf + (size_t)rel * EDGES;
    const unsigned char* cb = cbuf + (size_t)rel * EDGES;
    for (unsigned i = sR + t; i < eR; i += 256) atomicAdd(&rcnt[eb[i] >> 16], 1u);
    for (unsigned i = sC + t; i < eC; i += 256) atomicAdd(&ccnt[cb[i]], 1u);
    __syncthreads();
    int base = b * 64;
    if (t < 64) {                     // wave 0 only: 64-lane inclusive shfl scan
        unsigned c = rcnt[t];
        unsigned v = c;
#pragma unroll
        for (int off = 1; off < 64; off <<= 1) {
            unsigned n = __shfl_up(v, off, 64);
            if (t >= off) v += n;
        }
        unsigned excl = v - c;
        cur[t] = (int)(sR + excl);
        if (base + t < NODES) {
            row_ptr[rel * RPS + base + t] = (int)(sR + excl);
            int d = (int)c; if (d < 1) d = 1;
            dinv_row[(size_t)rel * NODES + base + t] = rsqrtf((float)d);
        }
        if (b == 0 && t == 0) row_ptr[rel * RPS + NODES] = EDGES;
    } else if (t >= 64 && t < 128) {
        int tt = t - 64;
        if (base + tt < NODES) {
            int d = (int)ccnt[tt]; if (d < 1) d = 1;
            dinv_col[(size_t)rel * NODES + base + tt] = rsqrtf((float)d);
        }
    }
    __syncthreads();
    int* cc = csr_col + (size_t)rel * EDGES;
    for (unsigned i = sR + t; i < eR; i += 256) {   // bucket range re-read: L2-warm
        unsigned v = eb[i];
        int pos = atomicAdd(&cur[v >> 16], 1);
        cc[pos] = (int)(v & 0xFFFFu);
    }
}

// ---------------- SPMM: wave per row, all 4 relations fused (grid.y = rel) ----------------
// Proven body (stable at ~390 us, beyond-L2 BW ceiling): half-wave interleave,
// 2 edges in flight per half. slice_off selects target agg slice: rel + slice_off.

__global__ __launch_bounds__(256)
void k_spmm(const unsigned short* __restrict__ feat, const int* __restrict__ row_ptr,
            const int* __restrict__ csr_col, const float* __restrict__ dinv_row,
            const float* __restrict__ dinv_col, unsigned short* __restrict__ aggbase,
            int slice_off) {
    int rel = blockIdx.y;
    unsigned short* aggbf = aggbase + (size_t)(rel + slice_off) * (size_t)MPAD * FEAT;
    int wave = (blockIdx.x * blockDim.x + threadIdx.x) >> 6;
    int lane = threadIdx.x & 63;
    if (wave >= NODES) return;
    int row = wave;
    int half = lane >> 5;
    int l32  = lane & 31;
    int start = row_ptr[rel * RPS + row];
    int end   = row_ptr[rel * RPS + row + 1];
    const int* cols = csr_col + (size_t)rel * EDGES;
    const float* dc = dinv_col + rel * NODES;
    const unsigned short* fb = feat + l32 * 8;
    float acc[8] = {0.f, 0.f, 0.f, 0.f, 0.f, 0.f, 0.f, 0.f};
    int j = start + half;
    for (; j + 2 < end; j += 4) {
        int c0 = cols[j];
        int c1 = cols[j + 2];
        float w0 = dc[c0];
        float w1 = dc[c1];
        u16x8 u0 = *(const u16x8*)(fb + (size_t)c0 * FEAT);
        u16x8 u1 = *(const u16x8*)(fb + (size_t)c1 * FEAT);
#pragma unroll
        for (int i = 0; i < 8; ++i) acc[i] += w0 * bf2f(u0[i]);
#pragma unroll
        for (int i = 0; i < 8; ++i) acc[i] += w1 * bf2f(u1[i]);
    }
    if (j < end) {
        int c0 = cols[j];
        float w0 = dc[c0];
        u16x8 u0 = *(const u16x8*)(fb + (size_t)c0 * FEAT);
#pragma unroll
        for (int i = 0; i < 8; ++i) acc[i] += w0 * bf2f(u0[i]);
    }
#pragma unroll
    for (int i = 0; i < 8; ++i) acc[i] += __shfl_down(acc[i], 32, 64);
    if (half == 0) {
        float dr = dinv_row[rel * NODES + row];
        u16x8 o;
#pragma unroll
        for (int i = 0; i < 8; ++i) o[i] = f2bf(acc[i] * dr);
        *(u16x8*)(aggbf + (size_t)row * FEAT + l32 * 8) = o;
    }
}

// ---------------- MFMA GEMM (128x128 tile, BK=64, XOR-swizzled LDS) ----------------
// Staging via global_load_lds width-16 (async, no VGPR round-trip): linear LDS
// dest + source-side XOR pre-swizzle + same XOR on read (identical layout to
// the previous reg-staged path). C/D layout: col = lane&15, row = quad*4 + reg.

__global__ __launch_bounds__(256)
void k_gemm1(const unsigned short* __restrict__ Abase, const unsigned short* __restrict__ Wt,
             unsigned short* __restrict__ h1bf) {
    __shared__ __align__(16) unsigned short As[128 * 64];
    __shared__ __align__(16) unsigned short Bs[128 * 64];
    int tid = threadIdx.x;
    int wave = tid >> 6, lane = tid & 63;
    int quad = lane >> 4, l16 = lane & 15;
    int wm = (wave & 1) * 64, wn = (wave >> 1) * 64;
    int row0 = blockIdx.x * 128, n0 = blockIdx.y * 128;

    f32x4 hacc[4][4];
#pragma unroll
    for (int mi = 0; mi < 4; ++mi)
#pragma unroll
        for (int ni = 0; ni < 4; ++ni)
            hacc[mi][ni] = (f32x4){0.f, 0.f, 0.f, 0.f};

    for (int r = 0; r < RELS; ++r) {
        const unsigned short* A  = Abase + (size_t)r * MPAD * FEAT;
        const unsigned short* Bt = Wt + (size_t)r * FEAT * FEAT;
        f32x4 acc[4][4];
#pragma unroll
        for (int mi = 0; mi < 4; ++mi)
#pragma unroll
            for (int ni = 0; ni < 4; ++ni)
                acc[mi][ni] = (f32x4){0.f, 0.f, 0.f, 0.f};

        for (int k0 = 0; k0 < FEAT; k0 += 64) {
#pragma unroll
            for (int issue = 0; issue < 4; ++issue) {
                int flat = issue * 256 + tid;
                int row = flat >> 3;
                int gr = flat & 7;
                int sg = gr ^ (row & 7);
                GLOAD_LDS16(A + (size_t)(row0 + row) * FEAT + k0 + sg * 8, &As[flat * 8]);
                GLOAD_LDS16(Bt + (size_t)(n0 + row) * FEAT + k0 + sg * 8, &Bs[flat * 8]);
            }
            __syncthreads();
#pragma unroll
            for (int ks = 0; ks < 2; ++ks) {
                int g = ks * 4 + quad;
                short8 af[4], bfr[4];
#pragma unroll
                for (int mi = 0; mi < 4; ++mi) {
                    int m = wm + mi * 16 + l16;
                    af[mi] = *(const short8*)&As[m * 64 + ((g ^ (m & 7)) << 3)];
                }
#pragma unroll
                for (int ni = 0; ni < 4; ++ni) {
                    int n = wn + ni * 16 + l16;
                    bfr[ni] = *(const short8*)&Bs[n * 64 + ((g ^ (n & 7)) << 3)];
                }
#pragma unroll
                for (int mi = 0; mi < 4; ++mi)
#pragma unroll
                    for (int ni = 0; ni < 4; ++ni)
                        acc[mi][ni] = __builtin_amdgcn_mfma_f32_16x16x32_bf16(af[mi], bfr[ni], acc[mi][ni], 0, 0, 0);
            }
            __syncthreads();
        }
#pragma unroll
        for (int mi = 0; mi < 4; ++mi)
#pragma unroll
            for (int ni = 0; ni < 4; ++ni)
#pragma unroll
                for (int i = 0; i < 4; ++i) {
                    float v = acc[mi][ni][i];
                    hacc[mi][ni][i] += 0.25f * (v > 0.f ? v : 0.f);
                }
    }

#pragma unroll
    for (int mi = 0; mi < 4; ++mi)
#pragma unroll
        for (int ni = 0; ni < 4; ++ni) {
            int col = n0 + wn + ni * 16 + l16;
#pragma unroll
            for (int i = 0; i < 4; ++i) {
                int row = row0 + wm + mi * 16 + quad * 4 + i;
                if (row < NODES) h1bf[(size_t)row * FEAT + col] = f2bf(hacc[mi][ni][i]);
            }
        }
}

// fused layer-2 GEMM: grid.z = rel; reads S_{r+1}, writes 4 disjoint dead buffers
__global__ __launch_bounds__(256)
void k_gemm2z(const unsigned short* __restrict__ aggbase, const unsigned short* __restrict__ Wtb,
              unsigned short* __restrict__ o0, unsigned short* __restrict__ o1,
              unsigned short* __restrict__ o2, unsigned short* __restrict__ o3) {
    __shared__ __align__(16) unsigned short As[128 * 64];
    __shared__ __align__(16) unsigned short Bs[128 * 64];
    int rz = blockIdx.z;
    const unsigned short* A  = aggbase + (size_t)(rz + 1) * MPAD * FEAT;
    const unsigned short* Bt = Wtb + (size_t)rz * FEAT * FEAT;
    unsigned short* H2 = (rz == 0) ? o0 : (rz == 1) ? o1 : (rz == 2) ? o2 : o3;

    int tid = threadIdx.x;
    int wave = tid >> 6, lane = tid & 63;
    int quad = lane >> 4, l16 = lane & 15;
    int wm = (wave & 1) * 64, wn = (wave >> 1) * 64;
    int row0 = blockIdx.x * 128, n0 = blockIdx.y * 128;

    f32x4 acc[4][4];
#pragma unroll
    for (int mi = 0; mi < 4; ++mi)
#pragma unroll
        for (int ni = 0; ni < 4; ++ni)
            acc[mi][ni] = (f32x4){0.f, 0.f, 0.f, 0.f};

    for (int k0 = 0; k0 < FEAT; k0 += 64) {
#pragma unroll
        for (int issue = 0; issue < 4; ++issue) {
            int flat = issue * 256 + tid;
            int row = flat >> 3;
            int gr = flat & 7;
            int sg = gr ^ (row & 7);
            GLOAD_LDS16(A + (size_t)(row0 + row) * FEAT + k0 + sg * 8, &As[flat * 8]);
            GLOAD_LDS16(Bt + (size_t)(n0 + row) * FEAT + k0 + sg * 8, &Bs[flat * 8]);
        }
        __syncthreads();
#pragma unroll
        for (int ks = 0; ks < 2; ++ks) {
            int g = ks * 4 + quad;
            short8 af[4], bfr[4];
#pragma unroll
            for (int mi = 0; mi < 4; ++mi) {
                int m = wm + mi * 16 + l16;
                af[mi] = *(const short8*)&As[m * 64 + ((g ^ (m & 7)) << 3)];
            }
#pragma unroll
            for (int ni = 0; ni < 4; ++ni) {
                int n = wn + ni * 16 + l16;
                bfr[ni] = *(const short8*)&Bs[n * 64 + ((g ^ (n & 7)) << 3)];
            }
#pragma unroll
            for (int mi = 0; mi < 4; ++mi)
#pragma unroll
                for (int ni = 0; ni < 4; ++ni)
                    acc[mi][ni] = __builtin_amdgcn_mfma_f32_16x16x32_bf16(af[mi], bfr[ni], acc[mi][ni], 0, 0, 0);
        }
        __syncthreads();
    }

#pragma unroll
    for (int mi = 0; mi < 4; ++mi)
#pragma unroll
        for (int ni = 0; ni < 4; ++ni) {
            int col = n0 + wn + ni * 16 + l16;
#pragma unroll
            for (int i = 0; i < 4; ++i) {
                int row = row0 + wm + mi * 16 + quad * 4 + i;
                if (row < NODES) {
                    float v = acc[mi][ni][i];
                    H2[(size_t)row * FEAT + col] = f2bf(v > 0.f ? v : 0.f);
                }
            }
        }
}

// ---------------- fused attention scores + softmax + combine + output GEMV ----------------
// H2 slices passed as 4 explicit pointers (disjoint buffers).

__global__ __launch_bounds__(256)
void k_attn_out(const unsigned short* __restrict__ p0, const unsigned short* __restrict__ p1,
                const unsigned short* __restrict__ p2, const unsigned short* __restrict__ p3,
                const float* __restrict__ att_q, const float* __restrict__ tau_p,
                const float* __restrict__ W_out, const float* __restrict__ b_out,
                float* __restrict__ alpha_out, float* __restrict__ logits) {
    __shared__ float red[4][64 * 17];
    int tid = threadIdx.x;
    int wid = tid >> 6;
    int lane = tid & 63;
    int gwave = blockIdx.x * 4 + wid;
    int nwaves = gridDim.x * 4;

    const unsigned short* hp[RELS] = {p0, p1, p2, p3};
    float4 q = *(const float4*)(att_q + lane * 4);
    float tau = fminf(fmaxf(tau_p[0], 0.5f), 5.0f);
    float itau = 1.0f / tau;
    f32x4 Wr[4][4];
#pragma unroll
    for (int j = 0; j < 4; ++j)
#pragma unroll
        for (int c4 = 0; c4 < 4; ++c4) {
            float4 w = *(const float4*)(W_out + (size_t)(lane * 4 + j) * NCLS + c4 * 4);
            Wr[j][c4] = (f32x4){w.x, w.y, w.z, w.w};
        }
    float bc = b_out[lane & 15];
    float* myred = &red[wid][0];
    int cls = lane & 15;
    int rb = (lane >> 4) * 16;

    int n = gwave;
    if (n >= NODES) return;
    ushort4 u[RELS];
#pragma unroll
    for (int r = 0; r < RELS; ++r)
        u[r] = *(const ushort4*)(hp[r] + (size_t)n * FEAT + lane * 4);

    while (n < NODES) {
        int nn = n + nwaves;
        int nc = (nn < NODES) ? nn : n;
        ushort4 un[RELS];
#pragma unroll
        for (int r = 0; r < RELS; ++r)
            un[r] = *(const ushort4*)(hp[r] + (size_t)nc * FEAT + lane * 4);

        float h[RELS][4];
#pragma unroll
        for (int r = 0; r < RELS; ++r) {
            h[r][0] = bf2f(u[r].x); h[r][1] = bf2f(u[r].y);
            h[r][2] = bf2f(u[r].z); h[r][3] = bf2f(u[r].w);
        }
        float s[RELS];
#pragma unroll
        for (int r = 0; r < RELS; ++r)
            s[r] = h[r][0] * q.x + h[r][1] * q.y + h[r][2] * q.z + h[r][3] * q.w;
#pragma unroll
        for (int off = 1; off < 64; off <<= 1) {
#pragma unroll
            for (int r = 0; r < RELS; ++r) s[r] += __shfl_xor(s[r], off, 64);
        }
        float m = fmaxf(fmaxf(s[0], s[1]), fmaxf(s[2], s[3]));
        float e[RELS];
        float esum = 0.f;
#pragma unroll
        for (int r = 0; r < RELS; ++r) { e[r] = expf((s[r] - m) * itau); esum += e[r]; }
        float inv = 1.0f / esum;
        float a[RELS];
#pragma unroll
        for (int r = 0; r < RELS; ++r) a[r] = e[r] * inv;
        if (lane == 0)
            *(float4*)(alpha_out + (size_t)n * 4) = make_float4(a[0], a[1], a[2], a[3]);

        float w0 = 0.25f + a[0], w1 = 0.25f + a[1], w2 = 0.25f + a[2], w3 = 0.25f + a[3];
        float h2[4];
#pragma unroll
        for (int j = 0; j < 4; ++j)
            h2[j] = w0 * h[0][j] + w1 * h[1][j] + w2 * h[2][j] + w3 * h[3][j];

        f32x4 acc[4];
#pragma unroll
        for (int c4 = 0; c4 < 4; ++c4)
            acc[c4] = h2[0] * Wr[0][c4] + h2[1] * Wr[1][c4]
                    + h2[2] * Wr[2][c4] + h2[3] * Wr[3][c4];

#pragma unroll
        for (int c4 = 0; c4 < 4; ++c4)
#pragma unroll
            for (int i = 0; i < 4; ++i)
                myred[lane * 17 + c4 * 4 + i] = acc[c4][i];
        asm volatile("s_waitcnt lgkmcnt(0)" ::: "memory");
        float t = 0.f;
#pragma unroll
        for (int k = 0; k < 16; ++k) t += myred[(rb + k) * 17 + cls];
        t += __shfl_xor(t, 16, 64);
        t += __shfl_xor(t, 32, 64);
        if (lane < 16) logits[(size_t)n * NCLS + lane] = t + bc;
        asm volatile("" ::: "memory");

#pragma unroll
        for (int r = 0; r < RELS; ++r) u[r] = un[r];
        n = nn;
    }
}

// ---------------- launcher ----------------

static inline int cdiv(int a, int b) { return (a + b - 1) / b; }

extern "C" void kernel_launch(void* const* d_in, const int* in_sizes, int n_in,
                              void* d_out, int out_size, void* d_ws, size_t ws_size,
                              hipStream_t stream) {
    const float* X     = (const float*)d_in[0];
    const int*   edges = (const int*)d_in[1];
    const float* W1    = (const float*)d_in[2];
    const float* W2    = (const float*)d_in[3];
    const float* att_q = (const float*)d_in[4];
    const float* tau   = (const float*)d_in[5];
    const float* W_out = (const float*)d_in[6];
    const float* b_out = (const float*)d_in[7];

    float* logits = (float*)d_out;
    float* alpha  = logits + (size_t)NODES * NCLS;

    char* p = (char*)d_ws;
    auto carve = [&](size_t bytes) -> char* {
        char* q = p;
        p += (bytes + 255) & ~(size_t)255;
        return q;
    };
    float* dinv_row = (float*)carve((size_t)RELS * NODES * 4);
    float* dinv_col = (float*)carve((size_t)RELS * NODES * 4);
    int*   row_ptr  = (int*)carve((size_t)RELS * RPS * 4 + 256);
    int*   csr_col  = (int*)carve((size_t)RELS * EDGES * 4);     // also H2_3 output (exactly 50000*256*2 B)
    unsigned short* Xbf  = (unsigned short*)carve((size_t)NODES * FEAT * 2);  // also H2_1 output
    unsigned short* h1bf = (unsigned short*)carve((size_t)NODES * FEAT * 2);  // also H2_2 output
    unsigned short* W1t  = (unsigned short*)carve((size_t)RELS * FEAT * FEAT * 2);
    unsigned short* W2t  = (unsigned short*)carve((size_t)RELS * FEAT * FEAT * 2);
    // BIG region: 5 slices of MPAD*FEAT bf16, phase-aliased:
    //   CSR phase:  ebuf packed uint (25.6M) | cbuf bytes (6.4M) | partR/offR/partC/offC (~6.4M) | bbR/bbC
    //   layer 1:    spmm -> S0..S3 (slice_off=0); gemm1 reads S0..S3 -> h1bf
    //   layer 2:    spmm -> S1..S4 (slice_off=1); gemm2z reads S1..S4 -> {S0, Xbf, h1bf, csr_col}
    const size_t AGGSE = (size_t)MPAD * FEAT;        // elements per slice
    char* BIG = carve(5 * AGGSE * 2);
    unsigned*      ebuf = (unsigned*)BIG;
    unsigned char* cbuf = (unsigned char*)(BIG + (size_t)RELS * EDGES * 4);
    char*     q = BIG + (size_t)RELS * EDGES * 5;
    q = (char*)(((uintptr_t)q + 255) & ~(uintptr_t)255);
    unsigned* partR = (unsigned*)q;               q += (size_t)RELS * NCHUNK * NB * 4;
    unsigned* offR  = (unsigned*)q;               q += (size_t)RELS * NCHUNK * NB * 4;
    unsigned* partC = (unsigned*)q;               q += (size_t)RELS * NCHUNK * NB * 4;
    unsigned* offC  = (unsigned*)q;               q += (size_t)RELS * NCHUNK * NB * 4;
    unsigned* bbR   = (unsigned*)q;               q += (size_t)RELS * (NB + 1) * 4;
    unsigned* bbC   = (unsigned*)q;
    unsigned short* aggbf = (unsigned short*)BIG;
    // H2 destinations (all dead buffers at gemm2z time, disjoint from its inputs S1..S4)
    unsigned short* H2_0 = aggbf;                        // S0
    unsigned short* H2_1 = Xbf;
    unsigned short* H2_2 = h1bf;
    unsigned short* H2_3 = (unsigned short*)csr_col;     // 25,600,000 B == 50000*256*2

    // CSR build: 4 launches — bucket sort with fused per-bucket finish.
    // Conversions (W transpose + X->bf16) ride along in k_bhist2's extra blocks.
    {
        dim3 hg(NCHUNK + CONVB, RELS);
        dim3 sg(NCHUNK, RELS);
        dim3 bg(NB, RELS);
        k_bhist2<<<hg, 256, 0, stream>>>(edges, partR, partC, W1, W2, W1t, W2t, X, Xbf);
        k_bscan<<<8, 256, 0, stream>>>(partR, offR, bbR, partC, offC, bbC);
        k_scat2<<<sg, 256, 0, stream>>>(edges, offR, offC, ebuf, cbuf);
        k_finish<<<bg, 256, 0, stream>>>(ebuf, cbuf, bbR, bbC, csr_col, row_ptr,
                                         dinv_row, dinv_col);
    }

    dim3 gemm_grid(MPAD / 128, FEAT / 128);
    dim3 gemm2_grid(MPAD / 128, FEAT / 128, RELS);
    dim3 spmm_grid(cdiv(NODES * 64, 256), RELS);

    // Layer 1: one fused SPMM (4 rels) into S0..S3, then fused GEMM -> h1bf
    k_spmm<<<spmm_grid, 256, 0, stream>>>(Xbf, row_ptr, csr_col, dinv_row, dinv_col,
                                          aggbf, 0);
    k_gemm1<<<gemm_grid, 256, 0, stream>>>(aggbf, W1t, h1bf);

    // Layer 2: one fused SPMM (4 rels) into S1..S4, then ONE fused GEMM (grid.z=rel)
    k_spmm<<<spmm_grid, 256, 0, stream>>>(h1bf, row_ptr, csr_col, dinv_row, dinv_col,
                                          aggbf, 1);
    k_gemm2z<<<gemm2_grid, 256, 0, stream>>>(aggbf, W2t, H2_0, H2_1, H2_2, H2_3);

    // fused attention + output (single pass over H2)
    k_attn_out<<<1024, 256, 0, stream>>>(H2_0, H2_1, H2_2, H2_3, att_q, tau,
                                         W_out, b_out, alpha, logits);
}